// Round 6
// baseline (597.019 us; speedup 1.0000x reference)
//
#include <hip/hip_runtime.h>

// ---------------- helpers ----------------

__device__ __forceinline__ float wredsum(float v) {
#pragma unroll
    for (int o = 32; o; o >>= 1) v += __shfl_xor(v, o);
    return v;
}

// SGPR row load: 16 x s_load_dwordx4 + tied waitcnt (data-tie orders use after wait)
typedef unsigned int u4v __attribute__((ext_vector_type(4)));

#define DECL_ROW u4v L0,L1,L2,L3,L4,L5,L6,L7,L8,L9,L10,L11,L12,L13,L14,L15

#define SLOAD_ROW(rowptr) do { \
    asm volatile("s_load_dwordx4 %0, %1, 0x00" : "=s"(L0)  : "s"(rowptr)); \
    asm volatile("s_load_dwordx4 %0, %1, 0x10" : "=s"(L1)  : "s"(rowptr)); \
    asm volatile("s_load_dwordx4 %0, %1, 0x20" : "=s"(L2)  : "s"(rowptr)); \
    asm volatile("s_load_dwordx4 %0, %1, 0x30" : "=s"(L3)  : "s"(rowptr)); \
    asm volatile("s_load_dwordx4 %0, %1, 0x40" : "=s"(L4)  : "s"(rowptr)); \
    asm volatile("s_load_dwordx4 %0, %1, 0x50" : "=s"(L5)  : "s"(rowptr)); \
    asm volatile("s_load_dwordx4 %0, %1, 0x60" : "=s"(L6)  : "s"(rowptr)); \
    asm volatile("s_load_dwordx4 %0, %1, 0x70" : "=s"(L7)  : "s"(rowptr)); \
    asm volatile("s_load_dwordx4 %0, %1, 0x80" : "=s"(L8)  : "s"(rowptr)); \
    asm volatile("s_load_dwordx4 %0, %1, 0x90" : "=s"(L9)  : "s"(rowptr)); \
    asm volatile("s_load_dwordx4 %0, %1, 0xa0" : "=s"(L10) : "s"(rowptr)); \
    asm volatile("s_load_dwordx4 %0, %1, 0xb0" : "=s"(L11) : "s"(rowptr)); \
    asm volatile("s_load_dwordx4 %0, %1, 0xc0" : "=s"(L12) : "s"(rowptr)); \
    asm volatile("s_load_dwordx4 %0, %1, 0xd0" : "=s"(L13) : "s"(rowptr)); \
    asm volatile("s_load_dwordx4 %0, %1, 0xe0" : "=s"(L14) : "s"(rowptr)); \
    asm volatile("s_load_dwordx4 %0, %1, 0xf0" : "=s"(L15) : "s"(rowptr)); \
    asm volatile("s_waitcnt lgkmcnt(0)" \
        : "+s"(L0),"+s"(L1),"+s"(L2),"+s"(L3),"+s"(L4),"+s"(L5),"+s"(L6),"+s"(L7), \
          "+s"(L8),"+s"(L9),"+s"(L10),"+s"(L11),"+s"(L12),"+s"(L13),"+s"(L14),"+s"(L15)); \
} while (0)

#define MVE(Lk, W, b) \
    a0 = fmaf(__uint_as_float(Lk.x), W[b+0], a0); \
    a1 = fmaf(__uint_as_float(Lk.y), W[b+1], a1); \
    a2 = fmaf(__uint_as_float(Lk.z), W[b+2], a2); \
    a3 = fmaf(__uint_as_float(Lk.w), W[b+3], a3);

#define MV64(W, OUT) do { \
    float a0=0.f, a1=0.f, a2=0.f, a3=0.f; \
    MVE(L0,W,0)  MVE(L1,W,4)  MVE(L2,W,8)   MVE(L3,W,12) \
    MVE(L4,W,16) MVE(L5,W,20) MVE(L6,W,24)  MVE(L7,W,28) \
    MVE(L8,W,32) MVE(L9,W,36) MVE(L10,W,40) MVE(L11,W,44) \
    MVE(L12,W,48) MVE(L13,W,52) MVE(L14,W,56) MVE(L15,W,60) \
    OUT = (a0+a1) + (a2+a3); \
} while (0)

// ================= bucketed CSR build =================

__global__ __launch_bounds__(256) void k_bhist_e(
    const int2* __restrict__ e, int* __restrict__ gcnt, int E, int nb)
{
    __shared__ int c[400];
    for (int i = threadIdx.x; i < nb; i += 256) c[i] = 0;
    __syncthreads();
    for (int idx = blockIdx.x*256 + threadIdx.x; idx < E; idx += gridDim.x*256)
        atomicAdd(&c[e[idx].y >> 8], 1);
    __syncthreads();
    for (int i = threadIdx.x; i < nb; i += 256) if (c[i]) atomicAdd(&gcnt[i], c[i]);
}

__global__ __launch_bounds__(256) void k_bhist_l(
    const int* __restrict__ lab, int* __restrict__ gcnt, int n, int nb)
{
    __shared__ int c[400];
    for (int i = threadIdx.x; i < nb; i += 256) c[i] = 0;
    __syncthreads();
    for (int idx = blockIdx.x*256 + threadIdx.x; idx < n; idx += gridDim.x*256)
        atomicAdd(&c[lab[idx] >> 8], 1);
    __syncthreads();
    for (int i = threadIdx.x; i < nb; i += 256) if (c[i]) atomicAdd(&gcnt[i], c[i]);
}

__global__ __launch_bounds__(512) void k_bscan3(
    const int* c0, int* b0, int* u0, int nb0, int t0,
    const int* c1, int* b1, int* u1, int nb1, int t1,
    const int* c2, int* b2, int* u2, int nb2, int t2)
{
    const int* cnt; int* base; int* cur; int nb; int tot;
    if (blockIdx.x == 0) { cnt=c0; base=b0; cur=u0; nb=nb0; tot=t0; }
    else if (blockIdx.x == 1) { cnt=c1; base=b1; cur=u1; nb=nb1; tot=t1; }
    else { cnt=c2; base=b2; cur=u2; nb=nb2; tot=t2; }
    __shared__ int sc[512];
    int t = threadIdx.x;
    int v = (t < nb) ? cnt[t] : 0;
    sc[t] = v; __syncthreads();
    for (int o = 1; o < 512; o <<= 1) {
        int a = (t >= o) ? sc[t-o] : 0;
        __syncthreads();
        sc[t] += a;
        __syncthreads();
    }
    if (t < nb) { int ex = sc[t] - v; base[t] = ex; cur[t] = ex; }
    if (t == nb) base[nb] = tot;
}

#define BKT 512
#define EPT 8
__global__ __launch_bounds__(BKT) void k_bucket_e(
    const int2* __restrict__ e, int* __restrict__ cur,
    int2* __restrict__ ebuf, int E, int nb)
{
    __shared__ int cnt[400];
    __shared__ int chunk[400];
    int t = threadIdx.x;
    int base = blockIdx.x * (BKT*EPT);
    for (int i = t; i < nb; i += BKT) cnt[i] = 0;
    __syncthreads();
    int2 ed[EPT]; int rk[EPT];
#pragma unroll
    for (int k = 0; k < EPT; ++k) {
        int idx = base + k*BKT + t;
        if (idx < E) { ed[k] = e[idx]; rk[k] = atomicAdd(&cnt[ed[k].y >> 8], 1); }
        else rk[k] = -1;
    }
    __syncthreads();
    for (int i = t; i < nb; i += BKT) { int c = cnt[i]; if (c) chunk[i] = atomicAdd(&cur[i], c); }
    __syncthreads();
#pragma unroll
    for (int k = 0; k < EPT; ++k)
        if (rk[k] >= 0) ebuf[chunk[ed[k].y >> 8] + rk[k]] = ed[k];
}

__global__ __launch_bounds__(BKT) void k_bucket_l(
    const int* __restrict__ lab, int* __restrict__ cur,
    int2* __restrict__ ebuf, int n, int nb)
{
    __shared__ int cnt[400];
    __shared__ int chunk[400];
    int t = threadIdx.x;
    int base = blockIdx.x * (BKT*EPT);
    for (int i = t; i < nb; i += BKT) cnt[i] = 0;
    __syncthreads();
    int2 ed[EPT]; int rk[EPT];
#pragma unroll
    for (int k = 0; k < EPT; ++k) {
        int idx = base + k*BKT + t;
        if (idx < n) { ed[k] = make_int2(idx, lab[idx]); rk[k] = atomicAdd(&cnt[ed[k].y >> 8], 1); }
        else rk[k] = -1;
    }
    __syncthreads();
    for (int i = t; i < nb; i += BKT) { int c = cnt[i]; if (c) chunk[i] = atomicAdd(&cur[i], c); }
    __syncthreads();
#pragma unroll
    for (int k = 0; k < EPT; ++k)
        if (rk[k] >= 0) ebuf[chunk[ed[k].y >> 8] + rk[k]] = ed[k];
}

__global__ __launch_bounds__(512) void k_final(
    const int2* __restrict__ ebuf, const int* __restrict__ base_,
    int* __restrict__ rs, int* __restrict__ srcs, int ndst, int etot, int nb)
{
    __shared__ int h[256];
    __shared__ int sc[256];
    int b = blockIdx.x, t = threadIdx.x;
    int base = base_[b];
    int cnt  = base_[b+1] - base;
    int d0 = b << 8;
    if (t < 256) h[t] = 0;
    __syncthreads();
    for (int i = t; i < cnt; i += 512) atomicAdd(&h[ebuf[base+i].y - d0], 1);
    __syncthreads();
    int v = (t < 256) ? h[t] : 0;
    if (t < 256) sc[t] = v;
    __syncthreads();
    for (int o = 1; o < 256; o <<= 1) {
        int a = (t < 256 && t >= o) ? sc[t-o] : 0;
        __syncthreads();
        if (t < 256) sc[t] += a;
        __syncthreads();
    }
    if (t < 256) {
        int gpos = base + sc[t] - v;
        if (d0 + t < ndst) rs[d0+t] = gpos;
        h[t] = gpos;
    }
    if (b == nb-1 && t == 0) rs[ndst] = etot;
    __syncthreads();
    for (int i = t; i < cnt; i += 512) {
        int2 ed = ebuf[base+i];
        int pos = atomicAdd(&h[ed.y - d0], 1);
        srcs[pos] = ed.x;
    }
}

// ================= compute kernels =================

// rel = points - centers[labels]; x1 = relu([features, rel] @ feW + feb)  (2 nodes/wave)
__global__ __launch_bounds__(256) void k_feat(
    const float* __restrict__ feat, const float* __restrict__ pts,
    const float* __restrict__ ctr, const int* __restrict__ lab,
    const float* __restrict__ W, const float* __restrict__ b,
    float* __restrict__ rel, float* __restrict__ x1, int n)
{
    int lane = threadIdx.x & 63;
    int wid  = blockIdx.x * (blockDim.x >> 6) + (threadIdx.x >> 6);
    int nw   = gridDim.x * (blockDim.x >> 6);
    float bl = b[lane];
    float w0 = W[0*64+lane], w1 = W[1*64+lane], w2 = W[2*64+lane], w3 = W[3*64+lane];
    float w4 = W[4*64+lane], w5 = W[5*64+lane], w6 = W[6*64+lane];
    for (int i0 = wid*2; i0 < n; i0 += nw*2) {
        int iA = __builtin_amdgcn_readfirstlane(i0);
        int iB = iA + 1;
        int lA = lab[iA], lB = lab[iB];
        float pA0 = pts[iA*3+0], pA1 = pts[iA*3+1], pA2 = pts[iA*3+2];
        float pB0 = pts[iB*3+0], pB1 = pts[iB*3+1], pB2 = pts[iB*3+2];
        float rA0 = pA0 - ctr[lA*3+0], rA1 = pA1 - ctr[lA*3+1], rA2 = pA2 - ctr[lA*3+2];
        float rB0 = pB0 - ctr[lB*3+0], rB1 = pB1 - ctr[lB*3+1], rB2 = pB2 - ctr[lB*3+2];
        if (lane == 0)      { rel[iA*3+0]=rA0; rel[iA*3+1]=rA1; rel[iA*3+2]=rA2; }
        else if (lane == 1) { rel[iB*3+0]=rB0; rel[iB*3+1]=rB1; rel[iB*3+2]=rB2; }
        float aA = bl, aB = bl;
        aA = fmaf(feat[iA*4+0], w0, aA); aB = fmaf(feat[iB*4+0], w0, aB);
        aA = fmaf(feat[iA*4+1], w1, aA); aB = fmaf(feat[iB*4+1], w1, aB);
        aA = fmaf(feat[iA*4+2], w2, aA); aB = fmaf(feat[iB*4+2], w2, aB);
        aA = fmaf(feat[iA*4+3], w3, aA); aB = fmaf(feat[iB*4+3], w3, aB);
        aA = fmaf(rA0, w4, aA); aB = fmaf(rB0, w4, aB);
        aA = fmaf(rA1, w5, aA); aB = fmaf(rB1, w5, aB);
        aA = fmaf(rA2, w6, aA); aB = fmaf(rB2, w6, aB);
        x1[(size_t)iA*64+lane] = fmaxf(aA, 0.f);
        x1[(size_t)iB*64+lane] = fmaxf(aB, 0.f);
    }
}

// GNN pre: delta = tanh(x@Wh+bh); p = x@Wf[3:67] + pos@Wf[0:3]; q = (delta-pos)@Wf[0:3]+bf
__global__ __launch_bounds__(256) void k_pre(
    const float* __restrict__ x, const float* __restrict__ pos,
    const float* __restrict__ Wh, const float* __restrict__ bh,
    const float* __restrict__ Wf, const float* __restrict__ bf,
    float* __restrict__ p, float* __restrict__ q, int n)
{
    int lane = threadIdx.x & 63;
    int wid  = blockIdx.x * (blockDim.x >> 6) + (threadIdx.x >> 6);
    int nw   = gridDim.x * (blockDim.x >> 6);
    float wf[64];
#pragma unroll
    for (int j = 0; j < 64; ++j) wf[j] = Wf[(3+j)*64 + lane];
    float w0 = Wf[0*64+lane], w1 = Wf[1*64+lane], w2 = Wf[2*64+lane];
    float bfl = bf[lane];
    float wh0 = Wh[lane*3+0], wh1 = Wh[lane*3+1], wh2 = Wh[lane*3+2];
    float bh0 = bh[0], bh1 = bh[1], bh2 = bh[2];
    for (int i = wid; i < n; i += nw) {
        int iu = __builtin_amdgcn_readfirstlane(i);
        const float* row = x + (size_t)iu*64;
        DECL_ROW;
        SLOAD_ROW(row);
        float xv = row[lane];
        float d0 = xv*wh0, d1 = xv*wh1, d2 = xv*wh2;
#pragma unroll
        for (int o = 32; o; o >>= 1) {
            d0 += __shfl_xor(d0,o); d1 += __shfl_xor(d1,o); d2 += __shfl_xor(d2,o);
        }
        d0 = tanhf(d0+bh0); d1 = tanhf(d1+bh1); d2 = tanhf(d2+bh2);
        float p0 = pos[iu*3+0], p1 = pos[iu*3+1], p2 = pos[iu*3+2];
        float mv;
        MV64(wf, mv);
        size_t o = (size_t)iu*64 + lane;
        p[o] = mv + p0*w0 + p1*w1 + p2*w2;
        q[o] = (d0-p0)*w0 + (d1-p1)*w1 + (d2-p2)*w2 + bfl;
    }
}

// CSR gather-max fused with relu(max+q) in place into q; 2 dests/wave, 4 streams.
__global__ __launch_bounds__(256) void k_seg_max_gnn(
    const int* __restrict__ rs, const int* __restrict__ srcs,
    const float* __restrict__ p, float* __restrict__ q, int n)
{
    int lane = threadIdx.x & 63;
    int wid  = blockIdx.x * (blockDim.x >> 6) + (threadIdx.x >> 6);
    int nw   = gridDim.x * (blockDim.x >> 6);
    for (int d0 = wid*2; d0 < n; d0 += nw*2) {
        int dA = __builtin_amdgcn_readfirstlane(d0);
        int begA = rs[dA], endA = rs[dA+1], endB = rs[dA+2];
        int ca = begA, cb = endA;
        float aA0=-1e30f, aA1=-1e30f, aB0=-1e30f, aB1=-1e30f;
        while (ca+2 <= endA && cb+2 <= endB) {
            int s0=srcs[ca], s1=srcs[ca+1], s2=srcs[cb], s3=srcs[cb+1];
            aA0 = fmaxf(aA0, p[(size_t)s0*64+lane]);
            aA1 = fmaxf(aA1, p[(size_t)s1*64+lane]);
            aB0 = fmaxf(aB0, p[(size_t)s2*64+lane]);
            aB1 = fmaxf(aB1, p[(size_t)s3*64+lane]);
            ca += 2; cb += 2;
        }
        while (ca+2 <= endA) {
            int s0=srcs[ca], s1=srcs[ca+1];
            aA0 = fmaxf(aA0, p[(size_t)s0*64+lane]);
            aA1 = fmaxf(aA1, p[(size_t)s1*64+lane]);
            ca += 2;
        }
        while (cb+2 <= endB) {
            int s2=srcs[cb], s3=srcs[cb+1];
            aB0 = fmaxf(aB0, p[(size_t)s2*64+lane]);
            aB1 = fmaxf(aB1, p[(size_t)s3*64+lane]);
            cb += 2;
        }
        if (ca < endA) aA0 = fmaxf(aA0, p[(size_t)srcs[ca]*64+lane]);
        if (cb < endB) aB0 = fmaxf(aB0, p[(size_t)srcs[cb]*64+lane]);
        float accA = fmaxf(aA0, aA1), accB = fmaxf(aB0, aB1);
        size_t oA = (size_t)dA*64 + lane, oB = oA + 64;
        q[oA] = fmaxf(accA + q[oA], 0.f);
        q[oB] = fmaxf(accB + q[oB], 0.f);
    }
}

// plain segmax (inputs >= 0, empty -> 0): c[d] = max over CSR of h[src]
__global__ __launch_bounds__(256) void k_seg_max_plain(
    const int* __restrict__ rs, const int* __restrict__ srcs,
    const float* __restrict__ h, float* __restrict__ out, int n)
{
    int lane = threadIdx.x & 63;
    int wid  = blockIdx.x * (blockDim.x >> 6) + (threadIdx.x >> 6);
    int nw   = gridDim.x * (blockDim.x >> 6);
    for (int d0 = wid*2; d0 < n; d0 += nw*2) {
        int dA = __builtin_amdgcn_readfirstlane(d0);
        int begA = rs[dA], endA = rs[dA+1], endB = rs[dA+2];
        int ca = begA, cb = endA;
        float aA0=-1e30f, aA1=-1e30f, aB0=-1e30f, aB1=-1e30f;
        while (ca+2 <= endA && cb+2 <= endB) {
            int s0=srcs[ca], s1=srcs[ca+1], s2=srcs[cb], s3=srcs[cb+1];
            aA0 = fmaxf(aA0, h[(size_t)s0*64+lane]);
            aA1 = fmaxf(aA1, h[(size_t)s1*64+lane]);
            aB0 = fmaxf(aB0, h[(size_t)s2*64+lane]);
            aB1 = fmaxf(aB1, h[(size_t)s3*64+lane]);
            ca += 2; cb += 2;
        }
        while (ca+2 <= endA) {
            int s0=srcs[ca], s1=srcs[ca+1];
            aA0 = fmaxf(aA0, h[(size_t)s0*64+lane]);
            aA1 = fmaxf(aA1, h[(size_t)s1*64+lane]);
            ca += 2;
        }
        while (cb+2 <= endB) {
            int s2=srcs[cb], s3=srcs[cb+1];
            aB0 = fmaxf(aB0, h[(size_t)s2*64+lane]);
            aB1 = fmaxf(aB1, h[(size_t)s3*64+lane]);
            cb += 2;
        }
        if (ca < endA) aA0 = fmaxf(aA0, h[(size_t)srcs[ca]*64+lane]);
        if (cb < endB) aB0 = fmaxf(aB0, h[(size_t)srcs[cb]*64+lane]);
        out[(size_t)dA*64+lane] = fmaxf(fmaxf(aA0,aA1), 0.f);
        out[(size_t)dA*64+64+lane] = fmaxf(fmaxf(aB0,aB1), 0.f);
    }
}

// out = relu(agg@Wg + bg) + res1 [+ res2]
__global__ __launch_bounds__(256) void k_post(
    const float* __restrict__ agg, const float* __restrict__ Wg,
    const float* __restrict__ bg, const float* __restrict__ res1,
    const float* __restrict__ res2, float* __restrict__ out, int n)
{
    int lane = threadIdx.x & 63;
    int wid  = blockIdx.x * (blockDim.x >> 6) + (threadIdx.x >> 6);
    int nw   = gridDim.x * (blockDim.x >> 6);
    float wg[64];
#pragma unroll
    for (int j = 0; j < 64; ++j) wg[j] = Wg[j*64 + lane];
    float bgl = bg[lane];
    for (int i = wid; i < n; i += nw) {
        int iu = __builtin_amdgcn_readfirstlane(i);
        const float* row = agg + (size_t)iu*64;
        DECL_ROW;
        SLOAD_ROW(row);
        size_t o = (size_t)iu*64 + lane;
        float res1v = res1[o];
        float res2v = res2 ? res2[o] : 0.f;
        float mv;
        MV64(wg, mv);
        out[o] = fmaxf(mv + bgl, 0.f) + res1v + res2v;
    }
}

// h = relu([x, rel] @ W + b)   (x row uniform; rel per node)
__global__ __launch_bounds__(256) void k_mlp67(
    const float* __restrict__ x, const float* __restrict__ rel,
    const float* __restrict__ W, const float* __restrict__ b,
    float* __restrict__ h, int n)
{
    int lane = threadIdx.x & 63;
    int wid  = blockIdx.x * (blockDim.x >> 6) + (threadIdx.x >> 6);
    int nw   = gridDim.x * (blockDim.x >> 6);
    float wm[64];
#pragma unroll
    for (int j = 0; j < 64; ++j) wm[j] = W[j*64 + lane];
    float w64 = W[64*64+lane], w65 = W[65*64+lane], w66 = W[66*64+lane];
    float bl = b[lane];
    for (int i = wid; i < n; i += nw) {
        int iu = __builtin_amdgcn_readfirstlane(i);
        const float* row = x + (size_t)iu*64;
        DECL_ROW;
        SLOAD_ROW(row);
        float rv0 = rel[iu*3+0], rv1 = rel[iu*3+1], rv2 = rel[iu*3+2];
        float mv;
        MV64(wm, mv);
        h[(size_t)iu*64+lane] = fmaxf(mv + bl + rv0*w64 + rv1*w65 + rv2*w66, 0.f);
    }
}

// x5 = relu([c4[lab], rel] @ W + b)   (gathered uniform row)
__global__ __launch_bounds__(256) void k_l2m(
    const float* __restrict__ c4, const int* __restrict__ lab,
    const float* __restrict__ rel,
    const float* __restrict__ W, const float* __restrict__ b,
    float* __restrict__ x5, int n)
{
    int lane = threadIdx.x & 63;
    int wid  = blockIdx.x * (blockDim.x >> 6) + (threadIdx.x >> 6);
    int nw   = gridDim.x * (blockDim.x >> 6);
    float wm[64];
#pragma unroll
    for (int j = 0; j < 64; ++j) wm[j] = W[j*64 + lane];
    float w64 = W[64*64+lane], w65 = W[65*64+lane], w66 = W[66*64+lane];
    float bl = b[lane];
    for (int i = wid; i < n; i += nw) {
        int iu = __builtin_amdgcn_readfirstlane(i);
        int l = lab[iu];
        const float* row = c4 + (size_t)l*64;
        DECL_ROW;
        SLOAD_ROW(row);
        float rv0 = rel[iu*3+0], rv1 = rel[iu*3+1], rv2 = rel[iu*3+2];
        float mv;
        MV64(wm, mv);
        x5[(size_t)iu*64+lane] = fmaxf(mv + bl + rv0*w64 + rv1*w65 + rv2*w66, 0.f);
    }
}

// t = relu(fin@W1+b1); out = t@W2 + b2
__global__ __launch_bounds__(256) void k_cls(
    const float* __restrict__ fin,
    const float* __restrict__ W1, const float* __restrict__ b1,
    const float* __restrict__ W2, const float* __restrict__ b2,
    float* __restrict__ out, int n)
{
    int lane = threadIdx.x & 63;
    int wid  = blockIdx.x * (blockDim.x >> 6) + (threadIdx.x >> 6);
    int nw   = gridDim.x * (blockDim.x >> 6);
    float w1c[64];
#pragma unroll
    for (int j = 0; j < 64; ++j) w1c[j] = W1[j*64 + lane];
    float w2c0 = W2[lane*4+0], w2c1 = W2[lane*4+1], w2c2 = W2[lane*4+2], w2c3 = W2[lane*4+3];
    float b1l = b1[lane];
    float b20 = b2[0], b21 = b2[1], b22 = b2[2], b23 = b2[3];
    for (int i = wid; i < n; i += nw) {
        int iu = __builtin_amdgcn_readfirstlane(i);
        const float* row = fin + (size_t)iu*64;
        DECL_ROW;
        SLOAD_ROW(row);
        float mv;
        MV64(w1c, mv);
        float t = fmaxf(mv + b1l, 0.f);
        float o0 = wredsum(t * w2c0);
        float o1 = wredsum(t * w2c1);
        float o2 = wredsum(t * w2c2);
        float o3 = wredsum(t * w2c3);
        if (lane == 0)
            *(float4*)(out + (size_t)iu*4) = make_float4(o0+b20, o1+b21, o2+b22, o3+b23);
    }
}

// ---------------- launch ----------------

extern "C" void kernel_launch(void* const* d_in, const int* in_sizes, int n_in,
                              void* d_out, int out_size, void* d_ws, size_t ws_size,
                              hipStream_t stream)
{
    const int N = 100000, M = 10000, E0 = 1600000, E1 = 320000;
    const int NB0 = (N + 255) / 256;   // 391
    const int NB1 = (M + 255) / 256;   // 40
    const int NBL = (M + 255) / 256;   // 40

    const float* feat = (const float*)d_in[0];
    const float* pts  = (const float*)d_in[1];
    const float* ctr  = (const float*)d_in[2];
    const int*   lab  = (const int*)d_in[3];
    const int2*  e0   = (const int2*)d_in[4];
    const int2*  e1   = (const int2*)d_in[5];
    const float* feW  = (const float*)d_in[6];
    const float* feb  = (const float*)d_in[7];
    const float* Wh   = (const float*)d_in[8];
    const float* bh   = (const float*)d_in[9];
    const float* Wf   = (const float*)d_in[10];
    const float* bf   = (const float*)d_in[11];
    const float* Wg   = (const float*)d_in[12];
    const float* bg   = (const float*)d_in[13];
    const float* m2lW = (const float*)d_in[14];
    const float* m2lb = (const float*)d_in[15];
    const float* l2mW = (const float*)d_in[16];
    const float* l2mb = (const float*)d_in[17];
    const float* cW1  = (const float*)d_in[18];
    const float* cb1  = (const float*)d_in[19];
    const float* cW2  = (const float*)d_in[20];
    const float* cb2  = (const float*)d_in[21];
    float* out = (float*)d_out;

    char* ws = (char*)d_ws;
    size_t off = 0;
    auto alloc = [&](size_t bytes) -> char* {
        char* r = ws + off; off += (bytes + 255) & ~(size_t)255; return r;
    };
    float* rel   = (float*)alloc((size_t)N*3*4);
    float* x1    = (float*)alloc((size_t)N*64*4);   // x1, later x5
    float* x2    = (float*)alloc((size_t)N*64*4);   // hosts ebufs pre-compute
    float* p     = (float*)alloc((size_t)N*64*4);   // p0 / h / p2 / fin
    float* q     = (float*)alloc((size_t)N*64*4);   // q0/agg0, [p1|q1], q2/agg2
    float* c     = (float*)alloc((size_t)M*64*4);
    float* c4    = (float*)alloc((size_t)M*64*4);
    int* rs0     = (int*)alloc((size_t)(N+2)*4);
    int* srcs0   = (int*)alloc((size_t)E0*4);
    int* rs1     = (int*)alloc((size_t)(M+2)*4);
    int* srcs1   = (int*)alloc((size_t)E1*4);
    int* rsL     = (int*)alloc((size_t)(M+2)*4);
    int* srcsL   = (int*)alloc((size_t)N*4);
    int* cnt0    = (int*)alloc((size_t)NB0*4);
    int* cnt1    = (int*)alloc((size_t)NB1*4);
    int* cntL    = (int*)alloc((size_t)NBL*4);
    int* base0   = (int*)alloc((size_t)(NB0+1)*4);
    int* base1   = (int*)alloc((size_t)(NB1+1)*4);
    int* baseL   = (int*)alloc((size_t)(NBL+1)*4);
    int* cur0    = (int*)alloc((size_t)NB0*4);
    int* cur1    = (int*)alloc((size_t)NB1*4);
    int* curL    = (int*)alloc((size_t)NBL*4);
    (void)ws_size; (void)in_sizes; (void)n_in; (void)out_size;

    int2* ebuf0 = (int2*)x2;
    int2* ebuf1 = ebuf0 + E0;
    int2* ebufL = ebuf1 + E1;

    dim3 blk(256);
    const int gN = 1024;   // N matvec kernels: 4096 waves, ~25 nodes each
    const int gM = 256;
    const int gSeg = 2048;

    // ---- CSR builds ----
    hipMemsetAsync(cnt0, 0, (size_t)NB0*4, stream);
    hipMemsetAsync(cnt1, 0, (size_t)NB1*4, stream);
    hipMemsetAsync(cntL, 0, (size_t)NBL*4, stream);
    k_bhist_e<<<1024, blk, 0, stream>>>(e0, cnt0, E0, NB0);
    k_bhist_e<<<512,  blk, 0, stream>>>(e1, cnt1, E1, NB1);
    k_bhist_l<<<512,  blk, 0, stream>>>(lab, cntL, N, NBL);
    k_bscan3<<<3, 512, 0, stream>>>(cnt0, base0, cur0, NB0, E0,
                                    cnt1, base1, cur1, NB1, E1,
                                    cntL, baseL, curL, NBL, N);
    k_bucket_e<<<(E0 + BKT*EPT - 1)/(BKT*EPT), BKT, 0, stream>>>(e0, cur0, ebuf0, E0, NB0);
    k_bucket_e<<<(E1 + BKT*EPT - 1)/(BKT*EPT), BKT, 0, stream>>>(e1, cur1, ebuf1, E1, NB1);
    k_bucket_l<<<(N  + BKT*EPT - 1)/(BKT*EPT), BKT, 0, stream>>>(lab, curL, ebufL, N, NBL);
    k_final<<<NB0, 512, 0, stream>>>(ebuf0, base0, rs0, srcs0, N, E0, NB0);
    k_final<<<NB1, 512, 0, stream>>>(ebuf1, base1, rs1, srcs1, M, E1, NB1);
    k_final<<<NBL, 512, 0, stream>>>(ebufL, baseL, rsL, srcsL, M, N, NBL);

    // ---- feature encoder ----
    k_feat<<<2048, blk, 0, stream>>>(feat, pts, ctr, lab, feW, feb, rel, x1, N);

    // ---- GNN layer 0 ----
    k_pre<<<gN, blk, 0, stream>>>(x1, pts, Wh+0*64*3, bh+0*3, Wf+0*67*64, bf+0*64, p, q, N);
    k_seg_max_gnn<<<gSeg, blk, 0, stream>>>(rs0, srcs0, p, q, N);
    k_post<<<gN, blk, 0, stream>>>(q, Wg+0*64*64, bg+0*64, x1, nullptr, x2, N);

    // ---- m2l + label segmax ----
    k_mlp67<<<gN, blk, 0, stream>>>(x2, rel, m2lW, m2lb, p, N);        // h -> p
    k_seg_max_plain<<<640, blk, 0, stream>>>(rsL, srcsL, p, c, M);

    // ---- GNN layer 1 (clusters) ----
    float* p1 = q;
    float* q1 = q + (size_t)M*64;
    k_pre<<<gM, blk, 0, stream>>>(c, ctr, Wh+1*64*3, bh+1*3, Wf+1*67*64, bf+1*64, p1, q1, M);
    k_seg_max_gnn<<<640, blk, 0, stream>>>(rs1, srcs1, p1, q1, M);
    k_post<<<gM, blk, 0, stream>>>(q1, Wg+1*64*64, bg+1*64, c, nullptr, c4, M);

    // ---- l2m -> x5 (x1 buffer) ----
    k_l2m<<<gN, blk, 0, stream>>>(c4, lab, rel, l2mW, l2mb, x1, N);

    // ---- GNN layer 2 + classifier ----
    k_pre<<<gN, blk, 0, stream>>>(x1, pts, Wh+2*64*3, bh+2*3, Wf+2*67*64, bf+2*64, p, q, N);
    k_seg_max_gnn<<<gSeg, blk, 0, stream>>>(rs0, srcs0, p, q, N);
    k_post<<<gN, blk, 0, stream>>>(q, Wg+2*64*64, bg+2*64, x1, x2, p, N);   // fin -> p
    k_cls<<<gN, blk, 0, stream>>>(p, cW1, cb1, cW2, cb2, out, N);
}

// Round 7
// 544.900 us; speedup vs baseline: 1.0957x; 1.0957x over previous
//
#include <hip/hip_runtime.h>

// ---------------- helpers ----------------

__device__ __forceinline__ float wredsum(float v) {
#pragma unroll
    for (int o = 32; o; o >>= 1) v += __shfl_xor(v, o);
    return v;
}

// lane-broadcast via v_readlane (const lane in unrolled loops) -> SGPR operand fma
__device__ __forceinline__ float bcast(float v, int l) {
    return __int_as_float(__builtin_amdgcn_readlane(__float_as_int(v), l));
}

// ================= bucketed CSR build =================
// Bucket = dest >> 8 (256 dests per bucket).

__global__ __launch_bounds__(256) void k_bhist_e(
    const int2* __restrict__ e, int* __restrict__ gcnt, int E, int nb)
{
    __shared__ int c[400];
    for (int i = threadIdx.x; i < nb; i += 256) c[i] = 0;
    __syncthreads();
    for (int idx = blockIdx.x*256 + threadIdx.x; idx < E; idx += gridDim.x*256)
        atomicAdd(&c[e[idx].y >> 8], 1);
    __syncthreads();
    for (int i = threadIdx.x; i < nb; i += 256) if (c[i]) atomicAdd(&gcnt[i], c[i]);
}

__global__ __launch_bounds__(256) void k_bhist_l(
    const int* __restrict__ lab, int* __restrict__ gcnt, int n, int nb)
{
    __shared__ int c[400];
    for (int i = threadIdx.x; i < nb; i += 256) c[i] = 0;
    __syncthreads();
    for (int idx = blockIdx.x*256 + threadIdx.x; idx < n; idx += gridDim.x*256)
        atomicAdd(&c[lab[idx] >> 8], 1);
    __syncthreads();
    for (int i = threadIdx.x; i < nb; i += 256) if (c[i]) atomicAdd(&gcnt[i], c[i]);
}

__global__ __launch_bounds__(512) void k_bscan3(
    const int* c0, int* b0, int* u0, int nb0, int t0,
    const int* c1, int* b1, int* u1, int nb1, int t1,
    const int* c2, int* b2, int* u2, int nb2, int t2)
{
    const int* cnt; int* base; int* cur; int nb; int tot;
    if (blockIdx.x == 0) { cnt=c0; base=b0; cur=u0; nb=nb0; tot=t0; }
    else if (blockIdx.x == 1) { cnt=c1; base=b1; cur=u1; nb=nb1; tot=t1; }
    else { cnt=c2; base=b2; cur=u2; nb=nb2; tot=t2; }
    __shared__ int sc[512];
    int t = threadIdx.x;
    int v = (t < nb) ? cnt[t] : 0;
    sc[t] = v; __syncthreads();
    for (int o = 1; o < 512; o <<= 1) {
        int a = (t >= o) ? sc[t-o] : 0;
        __syncthreads();
        sc[t] += a;
        __syncthreads();
    }
    if (t < nb) { int ex = sc[t] - v; base[t] = ex; cur[t] = ex; }
    if (t == nb) base[nb] = tot;
}

#define BKT 512
#define EPT 8
__global__ __launch_bounds__(BKT) void k_bucket_e(
    const int2* __restrict__ e, int* __restrict__ cur,
    int2* __restrict__ ebuf, int E, int nb)
{
    __shared__ int cnt[400];
    __shared__ int chunk[400];
    int t = threadIdx.x;
    int base = blockIdx.x * (BKT*EPT);
    for (int i = t; i < nb; i += BKT) cnt[i] = 0;
    __syncthreads();
    int2 ed[EPT]; int rk[EPT];
#pragma unroll
    for (int k = 0; k < EPT; ++k) {
        int idx = base + k*BKT + t;
        if (idx < E) { ed[k] = e[idx]; rk[k] = atomicAdd(&cnt[ed[k].y >> 8], 1); }
        else rk[k] = -1;
    }
    __syncthreads();
    for (int i = t; i < nb; i += BKT) { int c = cnt[i]; if (c) chunk[i] = atomicAdd(&cur[i], c); }
    __syncthreads();
#pragma unroll
    for (int k = 0; k < EPT; ++k)
        if (rk[k] >= 0) ebuf[chunk[ed[k].y >> 8] + rk[k]] = ed[k];
}

__global__ __launch_bounds__(BKT) void k_bucket_l(
    const int* __restrict__ lab, int* __restrict__ cur,
    int2* __restrict__ ebuf, int n, int nb)
{
    __shared__ int cnt[400];
    __shared__ int chunk[400];
    int t = threadIdx.x;
    int base = blockIdx.x * (BKT*EPT);
    for (int i = t; i < nb; i += BKT) cnt[i] = 0;
    __syncthreads();
    int2 ed[EPT]; int rk[EPT];
#pragma unroll
    for (int k = 0; k < EPT; ++k) {
        int idx = base + k*BKT + t;
        if (idx < n) { ed[k] = make_int2(idx, lab[idx]); rk[k] = atomicAdd(&cnt[ed[k].y >> 8], 1); }
        else rk[k] = -1;
    }
    __syncthreads();
    for (int i = t; i < nb; i += BKT) { int c = cnt[i]; if (c) chunk[i] = atomicAdd(&cur[i], c); }
    __syncthreads();
#pragma unroll
    for (int k = 0; k < EPT; ++k)
        if (rk[k] >= 0) ebuf[chunk[ed[k].y >> 8] + rk[k]] = ed[k];
}

__global__ __launch_bounds__(512) void k_final(
    const int2* __restrict__ ebuf, const int* __restrict__ base_,
    int* __restrict__ rs, int* __restrict__ srcs, int ndst, int etot, int nb)
{
    __shared__ int h[256];
    __shared__ int sc[256];
    int b = blockIdx.x, t = threadIdx.x;
    int base = base_[b];
    int cnt  = base_[b+1] - base;
    int d0 = b << 8;
    if (t < 256) h[t] = 0;
    __syncthreads();
    for (int i = t; i < cnt; i += 512) atomicAdd(&h[ebuf[base+i].y - d0], 1);
    __syncthreads();
    int v = (t < 256) ? h[t] : 0;
    if (t < 256) sc[t] = v;
    __syncthreads();
    for (int o = 1; o < 256; o <<= 1) {
        int a = (t < 256 && t >= o) ? sc[t-o] : 0;
        __syncthreads();
        if (t < 256) sc[t] += a;
        __syncthreads();
    }
    if (t < 256) {
        int gpos = base + sc[t] - v;
        if (d0 + t < ndst) rs[d0+t] = gpos;
        h[t] = gpos;
    }
    if (b == nb-1 && t == 0) rs[ndst] = etot;
    __syncthreads();
    for (int i = t; i < cnt; i += 512) {
        int2 ed = ebuf[base+i];
        int pos = atomicAdd(&h[ed.y - d0], 1);
        srcs[pos] = ed.x;
    }
}

// ================= compute kernels =================
// 2 nodes per wave-iteration, readlane broadcast matvecs, even/odd split accs.

// rel, x1 = relu([feat, rel]@feW + feb); fused gnn_pre layer0 -> p, q
__global__ __launch_bounds__(256) void k_feat_pre0(
    const float* __restrict__ feat, const float* __restrict__ pts,
    const float* __restrict__ ctr, const int* __restrict__ lab,
    const float* __restrict__ Wfe, const float* __restrict__ bfe,
    const float* __restrict__ Wh, const float* __restrict__ bh,
    const float* __restrict__ Wf, const float* __restrict__ bf,
    float* __restrict__ rel, float* __restrict__ x1,
    float* __restrict__ p, float* __restrict__ q, int n)
{
    int lane = threadIdx.x & 63;
    int wid  = blockIdx.x * (blockDim.x >> 6) + (threadIdx.x >> 6);
    int nw   = gridDim.x * (blockDim.x >> 6);
    float fe0 = Wfe[0*64+lane], fe1 = Wfe[1*64+lane], fe2 = Wfe[2*64+lane], fe3 = Wfe[3*64+lane];
    float fe4 = Wfe[4*64+lane], fe5 = Wfe[5*64+lane], fe6 = Wfe[6*64+lane];
    float bfe_l = bfe[lane];
    float wcol[64];
#pragma unroll
    for (int j = 0; j < 64; ++j) wcol[j] = Wf[(3+j)*64 + lane];
    float w0 = Wf[0*64+lane], w1 = Wf[1*64+lane], w2 = Wf[2*64+lane];
    float bfl = bf[lane];
    float wh0 = Wh[lane*3+0], wh1 = Wh[lane*3+1], wh2 = Wh[lane*3+2];
    float bh0 = bh[0], bh1 = bh[1], bh2 = bh[2];
    for (int i0 = wid*2; i0 < n; i0 += nw*2) {
        int iA = __builtin_amdgcn_readfirstlane(i0);
        int iB = iA + 1;
        int lA = lab[iA], lB = lab[iB];
        float pA0 = pts[iA*3+0], pA1 = pts[iA*3+1], pA2 = pts[iA*3+2];
        float pB0 = pts[iB*3+0], pB1 = pts[iB*3+1], pB2 = pts[iB*3+2];
        float rA0 = pA0 - ctr[lA*3+0], rA1 = pA1 - ctr[lA*3+1], rA2 = pA2 - ctr[lA*3+2];
        float rB0 = pB0 - ctr[lB*3+0], rB1 = pB1 - ctr[lB*3+1], rB2 = pB2 - ctr[lB*3+2];
        if (lane == 0)      { rel[iA*3+0]=rA0; rel[iA*3+1]=rA1; rel[iA*3+2]=rA2; }
        else if (lane == 1) { rel[iB*3+0]=rB0; rel[iB*3+1]=rB1; rel[iB*3+2]=rB2; }
        float aA = bfe_l, aB = bfe_l;
        aA = fmaf(feat[iA*4+0], fe0, aA); aB = fmaf(feat[iB*4+0], fe0, aB);
        aA = fmaf(feat[iA*4+1], fe1, aA); aB = fmaf(feat[iB*4+1], fe1, aB);
        aA = fmaf(feat[iA*4+2], fe2, aA); aB = fmaf(feat[iB*4+2], fe2, aB);
        aA = fmaf(feat[iA*4+3], fe3, aA); aB = fmaf(feat[iB*4+3], fe3, aB);
        aA = fmaf(rA0, fe4, aA); aB = fmaf(rB0, fe4, aB);
        aA = fmaf(rA1, fe5, aA); aB = fmaf(rB1, fe5, aB);
        aA = fmaf(rA2, fe6, aA); aB = fmaf(rB2, fe6, aB);
        float xvA = fmaxf(aA, 0.f), xvB = fmaxf(aB, 0.f);
        x1[(size_t)iA*64+lane] = xvA;
        x1[(size_t)iB*64+lane] = xvB;
        float d0A = xvA*wh0, d1A = xvA*wh1, d2A = xvA*wh2;
        float d0B = xvB*wh0, d1B = xvB*wh1, d2B = xvB*wh2;
#pragma unroll
        for (int o = 32; o; o >>= 1) {
            d0A += __shfl_xor(d0A,o); d1A += __shfl_xor(d1A,o); d2A += __shfl_xor(d2A,o);
            d0B += __shfl_xor(d0B,o); d1B += __shfl_xor(d1B,o); d2B += __shfl_xor(d2B,o);
        }
        d0A = tanhf(d0A+bh0); d1A = tanhf(d1A+bh1); d2A = tanhf(d2A+bh2);
        d0B = tanhf(d0B+bh0); d1B = tanhf(d1B+bh1); d2B = tanhf(d2B+bh2);
        float s0A=0.f, s1A=0.f, s0B=0.f, s1B=0.f;
#pragma unroll
        for (int j = 0; j < 64; j += 2) {
            s0A = fmaf(bcast(xvA,j),   wcol[j],   s0A);
            s1A = fmaf(bcast(xvA,j+1), wcol[j+1], s1A);
            s0B = fmaf(bcast(xvB,j),   wcol[j],   s0B);
            s1B = fmaf(bcast(xvB,j+1), wcol[j+1], s1B);
        }
        p[(size_t)iA*64+lane] = s0A+s1A + pA0*w0 + pA1*w1 + pA2*w2;
        p[(size_t)iB*64+lane] = s0B+s1B + pB0*w0 + pB1*w1 + pB2*w2;
        q[(size_t)iA*64+lane] = (d0A-pA0)*w0 + (d1A-pA1)*w1 + (d2A-pA2)*w2 + bfl;
        q[(size_t)iB*64+lane] = (d0B-pB0)*w0 + (d1B-pB1)*w1 + (d2B-pB2)*w2 + bfl;
    }
}

// CSR gather-max fused with relu(max+q) in place into q; 2 dests/wave, 4 streams.
__global__ __launch_bounds__(256) void k_seg_max_gnn(
    const int* __restrict__ rs, const int* __restrict__ srcs,
    const float* __restrict__ p, float* __restrict__ q, int n)
{
    int lane = threadIdx.x & 63;
    int wid  = blockIdx.x * (blockDim.x >> 6) + (threadIdx.x >> 6);
    int nw   = gridDim.x * (blockDim.x >> 6);
    for (int d0 = wid*2; d0 < n; d0 += nw*2) {
        int dA = __builtin_amdgcn_readfirstlane(d0);
        int begA = rs[dA], endA = rs[dA+1], endB = rs[dA+2];
        int ca = begA, cb = endA;
        float aA0=-1e30f, aA1=-1e30f, aB0=-1e30f, aB1=-1e30f;
        while (ca+2 <= endA && cb+2 <= endB) {
            int s0=srcs[ca], s1=srcs[ca+1], s2=srcs[cb], s3=srcs[cb+1];
            aA0 = fmaxf(aA0, p[(size_t)s0*64+lane]);
            aA1 = fmaxf(aA1, p[(size_t)s1*64+lane]);
            aB0 = fmaxf(aB0, p[(size_t)s2*64+lane]);
            aB1 = fmaxf(aB1, p[(size_t)s3*64+lane]);
            ca += 2; cb += 2;
        }
        while (ca+2 <= endA) {
            int s0=srcs[ca], s1=srcs[ca+1];
            aA0 = fmaxf(aA0, p[(size_t)s0*64+lane]);
            aA1 = fmaxf(aA1, p[(size_t)s1*64+lane]);
            ca += 2;
        }
        while (cb+2 <= endB) {
            int s2=srcs[cb], s3=srcs[cb+1];
            aB0 = fmaxf(aB0, p[(size_t)s2*64+lane]);
            aB1 = fmaxf(aB1, p[(size_t)s3*64+lane]);
            cb += 2;
        }
        if (ca < endA) aA0 = fmaxf(aA0, p[(size_t)srcs[ca]*64+lane]);
        if (cb < endB) aB0 = fmaxf(aB0, p[(size_t)srcs[cb]*64+lane]);
        float accA = fmaxf(aA0, aA1), accB = fmaxf(aB0, aB1);
        size_t oA = (size_t)dA*64 + lane, oB = oA + 64;
        q[oA] = fmaxf(accA + q[oA], 0.f);
        q[oB] = fmaxf(accB + q[oB], 0.f);
    }
}

// x2 = relu(agg@Wg+bg)+x1; h = relu([x2,rel]@Wm+bm)   (2 weight arrays -> (256,1))
__global__ __launch_bounds__(256, 1) void k_post_m2l(
    const float* __restrict__ agg, const float* __restrict__ Wg,
    const float* __restrict__ bg, const float* __restrict__ x1,
    const float* __restrict__ rel,
    const float* __restrict__ Wm, const float* __restrict__ bm,
    float* __restrict__ x2, float* __restrict__ h, int n)
{
    int lane = threadIdx.x & 63;
    int wid  = blockIdx.x * (blockDim.x >> 6) + (threadIdx.x >> 6);
    int nw   = gridDim.x * (blockDim.x >> 6);
    float wg[64], wm[64];
#pragma unroll
    for (int j = 0; j < 64; ++j) { wg[j] = Wg[j*64 + lane]; wm[j] = Wm[j*64 + lane]; }
    float wm64 = Wm[64*64+lane], wm65 = Wm[65*64+lane], wm66 = Wm[66*64+lane];
    float bgl = bg[lane], bml = bm[lane];
    for (int i0 = wid*2; i0 < n; i0 += nw*2) {
        int iA = __builtin_amdgcn_readfirstlane(i0);
        int iB = iA + 1;
        size_t oA = (size_t)iA*64 + lane, oB = oA + 64;
        float avA = agg[oA], avB = agg[oB];
        float s0A=0.f, s1A=0.f, s0B=0.f, s1B=0.f;
#pragma unroll
        for (int j = 0; j < 64; j += 2) {
            s0A = fmaf(bcast(avA,j),   wg[j],   s0A);
            s1A = fmaf(bcast(avA,j+1), wg[j+1], s1A);
            s0B = fmaf(bcast(avB,j),   wg[j],   s0B);
            s1B = fmaf(bcast(avB,j+1), wg[j+1], s1B);
        }
        float x2A = fmaxf(s0A+s1A + bgl, 0.f) + x1[oA];
        float x2B = fmaxf(s0B+s1B + bgl, 0.f) + x1[oB];
        x2[oA] = x2A; x2[oB] = x2B;
        float t0A=0.f, t1A=0.f, t0B=0.f, t1B=0.f;
#pragma unroll
        for (int j = 0; j < 64; j += 2) {
            t0A = fmaf(bcast(x2A,j),   wm[j],   t0A);
            t1A = fmaf(bcast(x2A,j+1), wm[j+1], t1A);
            t0B = fmaf(bcast(x2B,j),   wm[j],   t0B);
            t1B = fmaf(bcast(x2B,j+1), wm[j+1], t1B);
        }
        float hA = t0A+t1A + bml + rel[iA*3+0]*wm64 + rel[iA*3+1]*wm65 + rel[iA*3+2]*wm66;
        float hB = t0B+t1B + bml + rel[iB*3+0]*wm64 + rel[iB*3+1]*wm65 + rel[iB*3+2]*wm66;
        h[oA] = fmaxf(hA, 0.f);
        h[oB] = fmaxf(hB, 0.f);
    }
}

// c = segmax(h by labels); fused gnn_pre layer1 -> pa, qa   (M nodes, 2/wave)
__global__ __launch_bounds__(256) void k_seglab_pre1(
    const int* __restrict__ rsL, const int* __restrict__ srcsL,
    const float* __restrict__ h, const float* __restrict__ pos,
    const float* __restrict__ Wh, const float* __restrict__ bh,
    const float* __restrict__ Wf, const float* __restrict__ bf,
    float* __restrict__ c, float* __restrict__ pa, float* __restrict__ qa, int m)
{
    int lane = threadIdx.x & 63;
    int wid  = blockIdx.x * (blockDim.x >> 6) + (threadIdx.x >> 6);
    int nw   = gridDim.x * (blockDim.x >> 6);
    float wcol[64];
#pragma unroll
    for (int j = 0; j < 64; ++j) wcol[j] = Wf[(3+j)*64 + lane];
    float w0 = Wf[0*64+lane], w1 = Wf[1*64+lane], w2 = Wf[2*64+lane];
    float bfl = bf[lane];
    float wh0 = Wh[lane*3+0], wh1 = Wh[lane*3+1], wh2 = Wh[lane*3+2];
    float bh0 = bh[0], bh1 = bh[1], bh2 = bh[2];
    for (int d0 = wid*2; d0 < m; d0 += nw*2) {
        int dA = __builtin_amdgcn_readfirstlane(d0);
        int dB = dA + 1;
        int begA = rsL[dA], endA = rsL[dA+1], endB = rsL[dA+2];
        int ca = begA, cb = endA;
        float aA0=-1e30f, aA1=-1e30f, aB0=-1e30f, aB1=-1e30f;
        while (ca+2 <= endA && cb+2 <= endB) {
            int s0=srcsL[ca], s1=srcsL[ca+1], s2=srcsL[cb], s3=srcsL[cb+1];
            aA0 = fmaxf(aA0, h[(size_t)s0*64+lane]);
            aA1 = fmaxf(aA1, h[(size_t)s1*64+lane]);
            aB0 = fmaxf(aB0, h[(size_t)s2*64+lane]);
            aB1 = fmaxf(aB1, h[(size_t)s3*64+lane]);
            ca += 2; cb += 2;
        }
        while (ca+2 <= endA) {
            int s0=srcsL[ca], s1=srcsL[ca+1];
            aA0 = fmaxf(aA0, h[(size_t)s0*64+lane]);
            aA1 = fmaxf(aA1, h[(size_t)s1*64+lane]);
            ca += 2;
        }
        while (cb+2 <= endB) {
            int s2=srcsL[cb], s3=srcsL[cb+1];
            aB0 = fmaxf(aB0, h[(size_t)s2*64+lane]);
            aB1 = fmaxf(aB1, h[(size_t)s3*64+lane]);
            cb += 2;
        }
        if (ca < endA) aA0 = fmaxf(aA0, h[(size_t)srcsL[ca]*64+lane]);
        if (cb < endB) aB0 = fmaxf(aB0, h[(size_t)srcsL[cb]*64+lane]);
        float cvA = fmaxf(fmaxf(aA0,aA1), 0.f);
        float cvB = fmaxf(fmaxf(aB0,aB1), 0.f);
        c[(size_t)dA*64+lane] = cvA;
        c[(size_t)dB*64+lane] = cvB;
        float d0A = cvA*wh0, d1A = cvA*wh1, d2A = cvA*wh2;
        float d0B = cvB*wh0, d1B = cvB*wh1, d2B = cvB*wh2;
#pragma unroll
        for (int o = 32; o; o >>= 1) {
            d0A += __shfl_xor(d0A,o); d1A += __shfl_xor(d1A,o); d2A += __shfl_xor(d2A,o);
            d0B += __shfl_xor(d0B,o); d1B += __shfl_xor(d1B,o); d2B += __shfl_xor(d2B,o);
        }
        d0A = tanhf(d0A+bh0); d1A = tanhf(d1A+bh1); d2A = tanhf(d2A+bh2);
        d0B = tanhf(d0B+bh0); d1B = tanhf(d1B+bh1); d2B = tanhf(d2B+bh2);
        float pA0 = pos[dA*3+0], pA1 = pos[dA*3+1], pA2 = pos[dA*3+2];
        float pB0 = pos[dB*3+0], pB1 = pos[dB*3+1], pB2 = pos[dB*3+2];
        float s0A=0.f, s1A=0.f, s0B=0.f, s1B=0.f;
#pragma unroll
        for (int j = 0; j < 64; j += 2) {
            s0A = fmaf(bcast(cvA,j),   wcol[j],   s0A);
            s1A = fmaf(bcast(cvA,j+1), wcol[j+1], s1A);
            s0B = fmaf(bcast(cvB,j),   wcol[j],   s0B);
            s1B = fmaf(bcast(cvB,j+1), wcol[j+1], s1B);
        }
        pa[(size_t)dA*64+lane] = s0A+s1A + pA0*w0 + pA1*w1 + pA2*w2;
        pa[(size_t)dB*64+lane] = s0B+s1B + pB0*w0 + pB1*w1 + pB2*w2;
        qa[(size_t)dA*64+lane] = (d0A-pA0)*w0 + (d1A-pA1)*w1 + (d2A-pA2)*w2 + bfl;
        qa[(size_t)dB*64+lane] = (d0B-pB0)*w0 + (d1B-pB1)*w1 + (d2B-pB2)*w2 + bfl;
    }
}

// out = relu(agg@Wg + bg) + xres   (1 weight array)
__global__ __launch_bounds__(256) void k_gnn_post(
    const float* __restrict__ agg, const float* __restrict__ Wg,
    const float* __restrict__ bg, const float* __restrict__ xres,
    float* __restrict__ out, int n)
{
    int lane = threadIdx.x & 63;
    int wid  = blockIdx.x * (blockDim.x >> 6) + (threadIdx.x >> 6);
    int nw   = gridDim.x * (blockDim.x >> 6);
    float wcol[64];
#pragma unroll
    for (int j = 0; j < 64; ++j) wcol[j] = Wg[j*64 + lane];
    float bgl = bg[lane];
    for (int i0 = wid*2; i0 < n; i0 += nw*2) {
        int iA = __builtin_amdgcn_readfirstlane(i0);
        size_t oA = (size_t)iA*64 + lane, oB = oA + 64;
        float avA = agg[oA], avB = agg[oB];
        float s0A=0.f, s1A=0.f, s0B=0.f, s1B=0.f;
#pragma unroll
        for (int j = 0; j < 64; j += 2) {
            s0A = fmaf(bcast(avA,j),   wcol[j],   s0A);
            s1A = fmaf(bcast(avA,j+1), wcol[j+1], s1A);
            s0B = fmaf(bcast(avB,j),   wcol[j],   s0B);
            s1B = fmaf(bcast(avB,j+1), wcol[j+1], s1B);
        }
        out[oA] = fmaxf(s0A+s1A + bgl, 0.f) + xres[oA];
        out[oB] = fmaxf(s0B+s1B + bgl, 0.f) + xres[oB];
    }
}

// x5 = relu([c4[lab], rel]@Wm+bm); fused gnn_pre layer2 -> p, q  (2 arrays -> (256,1))
__global__ __launch_bounds__(256, 1) void k_l2m_pre2(
    const float* __restrict__ c4, const int* __restrict__ lab,
    const float* __restrict__ rel, const float* __restrict__ pts,
    const float* __restrict__ Wm, const float* __restrict__ bm,
    const float* __restrict__ Wh, const float* __restrict__ bh,
    const float* __restrict__ Wf, const float* __restrict__ bf,
    float* __restrict__ x5, float* __restrict__ p, float* __restrict__ q, int n)
{
    int lane = threadIdx.x & 63;
    int wid  = blockIdx.x * (blockDim.x >> 6) + (threadIdx.x >> 6);
    int nw   = gridDim.x * (blockDim.x >> 6);
    float wm[64], wf[64];
#pragma unroll
    for (int j = 0; j < 64; ++j) { wm[j] = Wm[j*64 + lane]; wf[j] = Wf[(3+j)*64 + lane]; }
    float wm64 = Wm[64*64+lane], wm65 = Wm[65*64+lane], wm66 = Wm[66*64+lane];
    float w0 = Wf[0*64+lane], w1 = Wf[1*64+lane], w2 = Wf[2*64+lane];
    float bml = bm[lane], bfl = bf[lane];
    float wh0 = Wh[lane*3+0], wh1 = Wh[lane*3+1], wh2 = Wh[lane*3+2];
    float bh0 = bh[0], bh1 = bh[1], bh2 = bh[2];
    for (int i0 = wid*2; i0 < n; i0 += nw*2) {
        int iA = __builtin_amdgcn_readfirstlane(i0);
        int iB = iA + 1;
        int lA = lab[iA], lB = lab[iB];
        float cvA = c4[(size_t)lA*64 + lane];
        float cvB = c4[(size_t)lB*64 + lane];
        float s0A=0.f, s1A=0.f, s0B=0.f, s1B=0.f;
#pragma unroll
        for (int j = 0; j < 64; j += 2) {
            s0A = fmaf(bcast(cvA,j),   wm[j],   s0A);
            s1A = fmaf(bcast(cvA,j+1), wm[j+1], s1A);
            s0B = fmaf(bcast(cvB,j),   wm[j],   s0B);
            s1B = fmaf(bcast(cvB,j+1), wm[j+1], s1B);
        }
        float hA = s0A+s1A + bml + rel[iA*3+0]*wm64 + rel[iA*3+1]*wm65 + rel[iA*3+2]*wm66;
        float hB = s0B+s1B + bml + rel[iB*3+0]*wm64 + rel[iB*3+1]*wm65 + rel[iB*3+2]*wm66;
        float xvA = fmaxf(hA, 0.f), xvB = fmaxf(hB, 0.f);
        size_t oA = (size_t)iA*64 + lane, oB = oA + 64;
        x5[oA] = xvA; x5[oB] = xvB;
        float d0A = xvA*wh0, d1A = xvA*wh1, d2A = xvA*wh2;
        float d0B = xvB*wh0, d1B = xvB*wh1, d2B = xvB*wh2;
#pragma unroll
        for (int o = 32; o; o >>= 1) {
            d0A += __shfl_xor(d0A,o); d1A += __shfl_xor(d1A,o); d2A += __shfl_xor(d2A,o);
            d0B += __shfl_xor(d0B,o); d1B += __shfl_xor(d1B,o); d2B += __shfl_xor(d2B,o);
        }
        d0A = tanhf(d0A+bh0); d1A = tanhf(d1A+bh1); d2A = tanhf(d2A+bh2);
        d0B = tanhf(d0B+bh0); d1B = tanhf(d1B+bh1); d2B = tanhf(d2B+bh2);
        float pA0 = pts[iA*3+0], pA1 = pts[iA*3+1], pA2 = pts[iA*3+2];
        float pB0 = pts[iB*3+0], pB1 = pts[iB*3+1], pB2 = pts[iB*3+2];
        float t0A=0.f, t1A=0.f, t0B=0.f, t1B=0.f;
#pragma unroll
        for (int j = 0; j < 64; j += 2) {
            t0A = fmaf(bcast(xvA,j),   wf[j],   t0A);
            t1A = fmaf(bcast(xvA,j+1), wf[j+1], t1A);
            t0B = fmaf(bcast(xvB,j),   wf[j],   t0B);
            t1B = fmaf(bcast(xvB,j+1), wf[j+1], t1B);
        }
        p[oA] = t0A+t1A + pA0*w0 + pA1*w1 + pA2*w2;
        p[oB] = t0B+t1B + pB0*w0 + pB1*w1 + pB2*w2;
        q[oA] = (d0A-pA0)*w0 + (d1A-pA1)*w1 + (d2A-pA2)*w2 + bfl;
        q[oB] = (d0B-pB0)*w0 + (d1B-pB1)*w1 + (d2B-pB2)*w2 + bfl;
    }
}

// x6 = relu(agg@Wg+bg)+x5; fin = x6+x2; t = relu(fin@W1+b1); out = t@W2+b2 (2 arrays -> (256,1))
__global__ __launch_bounds__(256, 1) void k_gnn_post_final(
    const float* __restrict__ agg, const float* __restrict__ Wg,
    const float* __restrict__ bg,
    const float* __restrict__ x5, const float* __restrict__ x2,
    const float* __restrict__ W1, const float* __restrict__ b1,
    const float* __restrict__ W2, const float* __restrict__ b2,
    float* __restrict__ out, int n)
{
    int lane = threadIdx.x & 63;
    int wid  = blockIdx.x * (blockDim.x >> 6) + (threadIdx.x >> 6);
    int nw   = gridDim.x * (blockDim.x >> 6);
    float wg[64], w1c[64];
#pragma unroll
    for (int j = 0; j < 64; ++j) { wg[j] = Wg[j*64 + lane]; w1c[j] = W1[j*64 + lane]; }
    float w2c0 = W2[lane*4+0], w2c1 = W2[lane*4+1], w2c2 = W2[lane*4+2], w2c3 = W2[lane*4+3];
    float bgl = bg[lane], b1l = b1[lane];
    float b20 = b2[0], b21 = b2[1], b22 = b2[2], b23 = b2[3];
    for (int i0 = wid*2; i0 < n; i0 += nw*2) {
        int iA = __builtin_amdgcn_readfirstlane(i0);
        int iB = iA + 1;
        size_t oA = (size_t)iA*64 + lane, oB = oA + 64;
        float avA = agg[oA], avB = agg[oB];
        float s0A=0.f, s1A=0.f, s0B=0.f, s1B=0.f;
#pragma unroll
        for (int j = 0; j < 64; j += 2) {
            s0A = fmaf(bcast(avA,j),   wg[j],   s0A);
            s1A = fmaf(bcast(avA,j+1), wg[j+1], s1A);
            s0B = fmaf(bcast(avB,j),   wg[j],   s0B);
            s1B = fmaf(bcast(avB,j+1), wg[j+1], s1B);
        }
        float finA = fmaxf(s0A+s1A + bgl, 0.f) + x5[oA] + x2[oA];
        float finB = fmaxf(s0B+s1B + bgl, 0.f) + x5[oB] + x2[oB];
        float t0A=0.f, t1A=0.f, t0B=0.f, t1B=0.f;
#pragma unroll
        for (int j = 0; j < 64; j += 2) {
            t0A = fmaf(bcast(finA,j),   w1c[j],   t0A);
            t1A = fmaf(bcast(finA,j+1), w1c[j+1], t1A);
            t0B = fmaf(bcast(finB,j),   w1c[j],   t0B);
            t1B = fmaf(bcast(finB,j+1), w1c[j+1], t1B);
        }
        float tA = fmaxf(t0A+t1A + b1l, 0.f);
        float tB = fmaxf(t0B+t1B + b1l, 0.f);
        float o0A = wredsum(tA * w2c0), o1A = wredsum(tA * w2c1);
        float o2A = wredsum(tA * w2c2), o3A = wredsum(tA * w2c3);
        float o0B = wredsum(tB * w2c0), o1B = wredsum(tB * w2c1);
        float o2B = wredsum(tB * w2c2), o3B = wredsum(tB * w2c3);
        if (lane == 0) {
            *(float4*)(out + (size_t)iA*4) = make_float4(o0A+b20, o1A+b21, o2A+b22, o3A+b23);
            *(float4*)(out + (size_t)iB*4) = make_float4(o0B+b20, o1B+b21, o2B+b22, o3B+b23);
        }
    }
}

// ---------------- launch ----------------

extern "C" void kernel_launch(void* const* d_in, const int* in_sizes, int n_in,
                              void* d_out, int out_size, void* d_ws, size_t ws_size,
                              hipStream_t stream)
{
    const int N = 100000, M = 10000, E0 = 1600000, E1 = 320000;
    const int NB0 = (N + 255) / 256;   // 391
    const int NB1 = (M + 255) / 256;   // 40
    const int NBL = (M + 255) / 256;   // 40

    const float* feat = (const float*)d_in[0];
    const float* pts  = (const float*)d_in[1];
    const float* ctr  = (const float*)d_in[2];
    const int*   lab  = (const int*)d_in[3];
    const int2*  e0   = (const int2*)d_in[4];
    const int2*  e1   = (const int2*)d_in[5];
    const float* feW  = (const float*)d_in[6];
    const float* feb  = (const float*)d_in[7];
    const float* Wh   = (const float*)d_in[8];
    const float* bh   = (const float*)d_in[9];
    const float* Wf   = (const float*)d_in[10];
    const float* bf   = (const float*)d_in[11];
    const float* Wg   = (const float*)d_in[12];
    const float* bg   = (const float*)d_in[13];
    const float* m2lW = (const float*)d_in[14];
    const float* m2lb = (const float*)d_in[15];
    const float* l2mW = (const float*)d_in[16];
    const float* l2mb = (const float*)d_in[17];
    const float* cW1  = (const float*)d_in[18];
    const float* cb1  = (const float*)d_in[19];
    const float* cW2  = (const float*)d_in[20];
    const float* cb2  = (const float*)d_in[21];
    float* out = (float*)d_out;

    char* ws = (char*)d_ws;
    size_t off = 0;
    auto alloc = [&](size_t bytes) -> char* {
        char* r = ws + off; off += (bytes + 255) & ~(size_t)255; return r;
    };
    float* rel   = (float*)alloc((size_t)N*3*4);
    float* x1    = (float*)alloc((size_t)N*64*4);   // x1, later x5
    float* x2    = (float*)alloc((size_t)N*64*4);   // hosts ebufs pre-compute
    float* p     = (float*)alloc((size_t)N*64*4);   // p0 / h / p2
    float* q     = (float*)alloc((size_t)N*64*4);   // q0/agg0, [p1|q1], q2/agg2
    float* c     = (float*)alloc((size_t)M*64*4);
    float* c4    = (float*)alloc((size_t)M*64*4);
    int* rs0     = (int*)alloc((size_t)(N+2)*4);
    int* srcs0   = (int*)alloc((size_t)E0*4);
    int* rs1     = (int*)alloc((size_t)(M+2)*4);
    int* srcs1   = (int*)alloc((size_t)E1*4);
    int* rsL     = (int*)alloc((size_t)(M+2)*4);
    int* srcsL   = (int*)alloc((size_t)N*4);
    int* cnt0    = (int*)alloc((size_t)NB0*4);
    int* cnt1    = (int*)alloc((size_t)NB1*4);
    int* cntL    = (int*)alloc((size_t)NBL*4);
    int* base0   = (int*)alloc((size_t)(NB0+1)*4);
    int* base1   = (int*)alloc((size_t)(NB1+1)*4);
    int* baseL   = (int*)alloc((size_t)(NBL+1)*4);
    int* cur0    = (int*)alloc((size_t)NB0*4);
    int* cur1    = (int*)alloc((size_t)NB1*4);
    int* curL    = (int*)alloc((size_t)NBL*4);
    (void)ws_size; (void)in_sizes; (void)n_in; (void)out_size;

    int2* ebuf0 = (int2*)x2;
    int2* ebuf1 = ebuf0 + E0;
    int2* ebufL = ebuf1 + E1;

    dim3 blk(256);
    const int gridN = 2048, gridM = 640, gSeg = 3072;

    // ---- CSR builds ----
    hipMemsetAsync(cnt0, 0, (size_t)NB0*4, stream);
    hipMemsetAsync(cnt1, 0, (size_t)NB1*4, stream);
    hipMemsetAsync(cntL, 0, (size_t)NBL*4, stream);
    k_bhist_e<<<1024, blk, 0, stream>>>(e0, cnt0, E0, NB0);
    k_bhist_e<<<512,  blk, 0, stream>>>(e1, cnt1, E1, NB1);
    k_bhist_l<<<512,  blk, 0, stream>>>(lab, cntL, N, NBL);
    k_bscan3<<<3, 512, 0, stream>>>(cnt0, base0, cur0, NB0, E0,
                                    cnt1, base1, cur1, NB1, E1,
                                    cntL, baseL, curL, NBL, N);
    k_bucket_e<<<(E0 + BKT*EPT - 1)/(BKT*EPT), BKT, 0, stream>>>(e0, cur0, ebuf0, E0, NB0);
    k_bucket_e<<<(E1 + BKT*EPT - 1)/(BKT*EPT), BKT, 0, stream>>>(e1, cur1, ebuf1, E1, NB1);
    k_bucket_l<<<(N  + BKT*EPT - 1)/(BKT*EPT), BKT, 0, stream>>>(lab, curL, ebufL, N, NBL);
    k_final<<<NB0, 512, 0, stream>>>(ebuf0, base0, rs0, srcs0, N, E0, NB0);
    k_final<<<NB1, 512, 0, stream>>>(ebuf1, base1, rs1, srcs1, M, E1, NB1);
    k_final<<<NBL, 512, 0, stream>>>(ebufL, baseL, rsL, srcsL, M, N, NBL);

    // ---- layer 0 ----
    k_feat_pre0<<<gridN, blk, 0, stream>>>(feat, pts, ctr, lab, feW, feb,
                                           Wh+0*64*3, bh+0*3, Wf+0*67*64, bf+0*64,
                                           rel, x1, p, q, N);
    k_seg_max_gnn<<<gSeg, blk, 0, stream>>>(rs0, srcs0, p, q, N);
    k_post_m2l<<<gridN, blk, 0, stream>>>(q, Wg+0*64*64, bg+0*64, x1, rel,
                                          m2lW, m2lb, x2, p, N);

    // ---- layer 1 (clusters) ----
    float* p1 = q;
    float* q1 = q + (size_t)M*64;
    k_seglab_pre1<<<gridM, blk, 0, stream>>>(rsL, srcsL, p, ctr,
                                             Wh+1*64*3, bh+1*3, Wf+1*67*64, bf+1*64,
                                             c, p1, q1, M);
    k_seg_max_gnn<<<640, blk, 0, stream>>>(rs1, srcs1, p1, q1, M);
    k_gnn_post<<<gridM, blk, 0, stream>>>(q1, Wg+1*64*64, bg+1*64, c, c4, M);

    // ---- l2m + layer 2 + classifier ----
    k_l2m_pre2<<<gridN, blk, 0, stream>>>(c4, lab, rel, pts, l2mW, l2mb,
                                          Wh+2*64*3, bh+2*3, Wf+2*67*64, bf+2*64,
                                          x1, p, q, N);
    k_seg_max_gnn<<<gSeg, blk, 0, stream>>>(rs0, srcs0, p, q, N);
    k_gnn_post_final<<<gridN, blk, 0, stream>>>(q, Wg+2*64*64, bg+2*64, x1, x2,
                                                cW1, cb1, cW2, cb2, out, N);
}

// Round 8
// 541.590 us; speedup vs baseline: 1.1023x; 1.0061x over previous
//
#include <hip/hip_runtime.h>

// ---------------- helpers ----------------

__device__ __forceinline__ float wredsum(float v) {
#pragma unroll
    for (int o = 32; o; o >>= 1) v += __shfl_xor(v, o);
    return v;
}

// lane-broadcast via v_readlane (const lane) -> uniform operand for fma
__device__ __forceinline__ float bcast(float v, int l) {
    return __int_as_float(__builtin_amdgcn_readlane(__float_as_int(v), l));
}

// 64 NAMED weight scalars per matrix (never an array -> never demoted to scratch).
#define REPD(M,P,B) \
 M(0,P,B)  M(1,P,B)  M(2,P,B)  M(3,P,B)  M(4,P,B)  M(5,P,B)  M(6,P,B)  M(7,P,B) \
 M(8,P,B)  M(9,P,B)  M(10,P,B) M(11,P,B) M(12,P,B) M(13,P,B) M(14,P,B) M(15,P,B) \
 M(16,P,B) M(17,P,B) M(18,P,B) M(19,P,B) M(20,P,B) M(21,P,B) M(22,P,B) M(23,P,B) \
 M(24,P,B) M(25,P,B) M(26,P,B) M(27,P,B) M(28,P,B) M(29,P,B) M(30,P,B) M(31,P,B) \
 M(32,P,B) M(33,P,B) M(34,P,B) M(35,P,B) M(36,P,B) M(37,P,B) M(38,P,B) M(39,P,B) \
 M(40,P,B) M(41,P,B) M(42,P,B) M(43,P,B) M(44,P,B) M(45,P,B) M(46,P,B) M(47,P,B) \
 M(48,P,B) M(49,P,B) M(50,P,B) M(51,P,B) M(52,P,B) M(53,P,B) M(54,P,B) M(55,P,B) \
 M(56,P,B) M(57,P,B) M(58,P,B) M(59,P,B) M(60,P,B) M(61,P,B) M(62,P,B) M(63,P,B)

#define WLOAD(J,P,B) float P##J = (B)[(J)*64+lane];

#define REPP(M,P,X,S0,S1) \
 M(0,1,P,X,S0,S1)  M(2,3,P,X,S0,S1)  M(4,5,P,X,S0,S1)  M(6,7,P,X,S0,S1) \
 M(8,9,P,X,S0,S1)  M(10,11,P,X,S0,S1) M(12,13,P,X,S0,S1) M(14,15,P,X,S0,S1) \
 M(16,17,P,X,S0,S1) M(18,19,P,X,S0,S1) M(20,21,P,X,S0,S1) M(22,23,P,X,S0,S1) \
 M(24,25,P,X,S0,S1) M(26,27,P,X,S0,S1) M(28,29,P,X,S0,S1) M(30,31,P,X,S0,S1) \
 M(32,33,P,X,S0,S1) M(34,35,P,X,S0,S1) M(36,37,P,X,S0,S1) M(38,39,P,X,S0,S1) \
 M(40,41,P,X,S0,S1) M(42,43,P,X,S0,S1) M(44,45,P,X,S0,S1) M(46,47,P,X,S0,S1) \
 M(48,49,P,X,S0,S1) M(50,51,P,X,S0,S1) M(52,53,P,X,S0,S1) M(54,55,P,X,S0,S1) \
 M(56,57,P,X,S0,S1) M(58,59,P,X,S0,S1) M(60,61,P,X,S0,S1) M(62,63,P,X,S0,S1)

#define WFMA(J,K,P,X,S0,S1) \
 S0 = fmaf(bcast(X,J), P##J, S0); \
 S1 = fmaf(bcast(X,K), P##K, S1);

// ================= bucketed CSR build =================

__global__ __launch_bounds__(256) void k_bhist_e(
    const int2* __restrict__ e, int* __restrict__ gcnt, int E, int nb)
{
    __shared__ int c[400];
    for (int i = threadIdx.x; i < nb; i += 256) c[i] = 0;
    __syncthreads();
    for (int idx = blockIdx.x*256 + threadIdx.x; idx < E; idx += gridDim.x*256)
        atomicAdd(&c[e[idx].y >> 8], 1);
    __syncthreads();
    for (int i = threadIdx.x; i < nb; i += 256) if (c[i]) atomicAdd(&gcnt[i], c[i]);
}

__global__ __launch_bounds__(256) void k_bhist_l(
    const int* __restrict__ lab, int* __restrict__ gcnt, int n, int nb)
{
    __shared__ int c[400];
    for (int i = threadIdx.x; i < nb; i += 256) c[i] = 0;
    __syncthreads();
    for (int idx = blockIdx.x*256 + threadIdx.x; idx < n; idx += gridDim.x*256)
        atomicAdd(&c[lab[idx] >> 8], 1);
    __syncthreads();
    for (int i = threadIdx.x; i < nb; i += 256) if (c[i]) atomicAdd(&gcnt[i], c[i]);
}

__global__ __launch_bounds__(512) void k_bscan3(
    const int* c0, int* b0, int* u0, int nb0, int t0,
    const int* c1, int* b1, int* u1, int nb1, int t1,
    const int* c2, int* b2, int* u2, int nb2, int t2)
{
    const int* cnt; int* base; int* cur; int nb; int tot;
    if (blockIdx.x == 0) { cnt=c0; base=b0; cur=u0; nb=nb0; tot=t0; }
    else if (blockIdx.x == 1) { cnt=c1; base=b1; cur=u1; nb=nb1; tot=t1; }
    else { cnt=c2; base=b2; cur=u2; nb=nb2; tot=t2; }
    __shared__ int sc[512];
    int t = threadIdx.x;
    int v = (t < nb) ? cnt[t] : 0;
    sc[t] = v; __syncthreads();
    for (int o = 1; o < 512; o <<= 1) {
        int a = (t >= o) ? sc[t-o] : 0;
        __syncthreads();
        sc[t] += a;
        __syncthreads();
    }
    if (t < nb) { int ex = sc[t] - v; base[t] = ex; cur[t] = ex; }
    if (t == nb) base[nb] = tot;
}

#define BKT 512
#define EPT 8
__global__ __launch_bounds__(BKT) void k_bucket_e(
    const int2* __restrict__ e, int* __restrict__ cur,
    int2* __restrict__ ebuf, int E, int nb)
{
    __shared__ int cnt[400];
    __shared__ int chunk[400];
    int t = threadIdx.x;
    int base = blockIdx.x * (BKT*EPT);
    for (int i = t; i < nb; i += BKT) cnt[i] = 0;
    __syncthreads();
    int2 ed[EPT]; int rk[EPT];
#pragma unroll
    for (int k = 0; k < EPT; ++k) {
        int idx = base + k*BKT + t;
        if (idx < E) { ed[k] = e[idx]; rk[k] = atomicAdd(&cnt[ed[k].y >> 8], 1); }
        else rk[k] = -1;
    }
    __syncthreads();
    for (int i = t; i < nb; i += BKT) { int c = cnt[i]; if (c) chunk[i] = atomicAdd(&cur[i], c); }
    __syncthreads();
#pragma unroll
    for (int k = 0; k < EPT; ++k)
        if (rk[k] >= 0) ebuf[chunk[ed[k].y >> 8] + rk[k]] = ed[k];
}

__global__ __launch_bounds__(BKT) void k_bucket_l(
    const int* __restrict__ lab, int* __restrict__ cur,
    int2* __restrict__ ebuf, int n, int nb)
{
    __shared__ int cnt[400];
    __shared__ int chunk[400];
    int t = threadIdx.x;
    int base = blockIdx.x * (BKT*EPT);
    for (int i = t; i < nb; i += BKT) cnt[i] = 0;
    __syncthreads();
    int2 ed[EPT]; int rk[EPT];
#pragma unroll
    for (int k = 0; k < EPT; ++k) {
        int idx = base + k*BKT + t;
        if (idx < n) { ed[k] = make_int2(idx, lab[idx]); rk[k] = atomicAdd(&cnt[ed[k].y >> 8], 1); }
        else rk[k] = -1;
    }
    __syncthreads();
    for (int i = t; i < nb; i += BKT) { int c = cnt[i]; if (c) chunk[i] = atomicAdd(&cur[i], c); }
    __syncthreads();
#pragma unroll
    for (int k = 0; k < EPT; ++k)
        if (rk[k] >= 0) ebuf[chunk[ed[k].y >> 8] + rk[k]] = ed[k];
}

__global__ __launch_bounds__(512) void k_final(
    const int2* __restrict__ ebuf, const int* __restrict__ base_,
    int* __restrict__ rs, int* __restrict__ srcs, int ndst, int etot, int nb)
{
    __shared__ int h[256];
    __shared__ int sc[256];
    int b = blockIdx.x, t = threadIdx.x;
    int base = base_[b];
    int cnt  = base_[b+1] - base;
    int d0 = b << 8;
    if (t < 256) h[t] = 0;
    __syncthreads();
    for (int i = t; i < cnt; i += 512) atomicAdd(&h[ebuf[base+i].y - d0], 1);
    __syncthreads();
    int v = (t < 256) ? h[t] : 0;
    if (t < 256) sc[t] = v;
    __syncthreads();
    for (int o = 1; o < 256; o <<= 1) {
        int a = (t < 256 && t >= o) ? sc[t-o] : 0;
        __syncthreads();
        if (t < 256) sc[t] += a;
        __syncthreads();
    }
    if (t < 256) {
        int gpos = base + sc[t] - v;
        if (d0 + t < ndst) rs[d0+t] = gpos;
        h[t] = gpos;
    }
    if (b == nb-1 && t == 0) rs[ndst] = etot;
    __syncthreads();
    for (int i = t; i < cnt; i += 512) {
        int2 ed = ebuf[base+i];
        int pos = atomicAdd(&h[ed.y - d0], 1);
        srcs[pos] = ed.x;
    }
}

// ================= compute kernels =================

// rel, x1 = relu([feat, rel]@feW + feb); fused gnn_pre layer0 -> p, q
__global__ __launch_bounds__(256, 2) void k_feat_pre0(
    const float* __restrict__ feat, const float* __restrict__ pts,
    const float* __restrict__ ctr, const int* __restrict__ lab,
    const float* __restrict__ Wfe, const float* __restrict__ bfe,
    const float* __restrict__ Wh, const float* __restrict__ bh,
    const float* __restrict__ Wf, const float* __restrict__ bf,
    float* __restrict__ rel, float* __restrict__ x1,
    float* __restrict__ p, float* __restrict__ q, int n)
{
    int lane = threadIdx.x & 63;
    int wid  = blockIdx.x * (blockDim.x >> 6) + (threadIdx.x >> 6);
    int nw   = gridDim.x * (blockDim.x >> 6);
    float fe0 = Wfe[0*64+lane], fe1 = Wfe[1*64+lane], fe2 = Wfe[2*64+lane], fe3 = Wfe[3*64+lane];
    float fe4 = Wfe[4*64+lane], fe5 = Wfe[5*64+lane], fe6 = Wfe[6*64+lane];
    float bfe_l = bfe[lane];
    REPD(WLOAD, wc, Wf + 3*64)          // wc0..wc63 = Wf[(3+j)*64+lane]
    float w0 = Wf[0*64+lane], w1 = Wf[1*64+lane], w2 = Wf[2*64+lane];
    float bfl = bf[lane];
    float wh0 = Wh[lane*3+0], wh1 = Wh[lane*3+1], wh2 = Wh[lane*3+2];
    float bh0 = bh[0], bh1 = bh[1], bh2 = bh[2];
    for (int i0 = wid*2; i0 < n; i0 += nw*2) {
        int iA = __builtin_amdgcn_readfirstlane(i0);
        int iB = iA + 1;
        int lA = lab[iA], lB = lab[iB];
        float pA0 = pts[iA*3+0], pA1 = pts[iA*3+1], pA2 = pts[iA*3+2];
        float pB0 = pts[iB*3+0], pB1 = pts[iB*3+1], pB2 = pts[iB*3+2];
        float rA0 = pA0 - ctr[lA*3+0], rA1 = pA1 - ctr[lA*3+1], rA2 = pA2 - ctr[lA*3+2];
        float rB0 = pB0 - ctr[lB*3+0], rB1 = pB1 - ctr[lB*3+1], rB2 = pB2 - ctr[lB*3+2];
        if (lane == 0)      { rel[iA*3+0]=rA0; rel[iA*3+1]=rA1; rel[iA*3+2]=rA2; }
        else if (lane == 1) { rel[iB*3+0]=rB0; rel[iB*3+1]=rB1; rel[iB*3+2]=rB2; }
        float aA = bfe_l, aB = bfe_l;
        aA = fmaf(feat[iA*4+0], fe0, aA); aB = fmaf(feat[iB*4+0], fe0, aB);
        aA = fmaf(feat[iA*4+1], fe1, aA); aB = fmaf(feat[iB*4+1], fe1, aB);
        aA = fmaf(feat[iA*4+2], fe2, aA); aB = fmaf(feat[iB*4+2], fe2, aB);
        aA = fmaf(feat[iA*4+3], fe3, aA); aB = fmaf(feat[iB*4+3], fe3, aB);
        aA = fmaf(rA0, fe4, aA); aB = fmaf(rB0, fe4, aB);
        aA = fmaf(rA1, fe5, aA); aB = fmaf(rB1, fe5, aB);
        aA = fmaf(rA2, fe6, aA); aB = fmaf(rB2, fe6, aB);
        float xvA = fmaxf(aA, 0.f), xvB = fmaxf(aB, 0.f);
        x1[(size_t)iA*64+lane] = xvA;
        x1[(size_t)iB*64+lane] = xvB;
        float d0A = xvA*wh0, d1A = xvA*wh1, d2A = xvA*wh2;
        float d0B = xvB*wh0, d1B = xvB*wh1, d2B = xvB*wh2;
#pragma unroll
        for (int o = 32; o; o >>= 1) {
            d0A += __shfl_xor(d0A,o); d1A += __shfl_xor(d1A,o); d2A += __shfl_xor(d2A,o);
            d0B += __shfl_xor(d0B,o); d1B += __shfl_xor(d1B,o); d2B += __shfl_xor(d2B,o);
        }
        d0A = tanhf(d0A+bh0); d1A = tanhf(d1A+bh1); d2A = tanhf(d2A+bh2);
        d0B = tanhf(d0B+bh0); d1B = tanhf(d1B+bh1); d2B = tanhf(d2B+bh2);
        float s0A=0.f, s1A=0.f, s0B=0.f, s1B=0.f;
        REPP(WFMA, wc, xvA, s0A, s1A)
        REPP(WFMA, wc, xvB, s0B, s1B)
        p[(size_t)iA*64+lane] = s0A+s1A + pA0*w0 + pA1*w1 + pA2*w2;
        p[(size_t)iB*64+lane] = s0B+s1B + pB0*w0 + pB1*w1 + pB2*w2;
        q[(size_t)iA*64+lane] = (d0A-pA0)*w0 + (d1A-pA1)*w1 + (d2A-pA2)*w2 + bfl;
        q[(size_t)iB*64+lane] = (d0B-pB0)*w0 + (d1B-pB1)*w1 + (d2B-pB2)*w2 + bfl;
    }
}

// CSR gather-max fused with relu(max+q) in place into q; 2 dests/wave, 4 streams.
__global__ __launch_bounds__(256) void k_seg_max_gnn(
    const int* __restrict__ rs, const int* __restrict__ srcs,
    const float* __restrict__ p, float* __restrict__ q, int n)
{
    int lane = threadIdx.x & 63;
    int wid  = blockIdx.x * (blockDim.x >> 6) + (threadIdx.x >> 6);
    int nw   = gridDim.x * (blockDim.x >> 6);
    for (int d0 = wid*2; d0 < n; d0 += nw*2) {
        int dA = __builtin_amdgcn_readfirstlane(d0);
        int begA = rs[dA], endA = rs[dA+1], endB = rs[dA+2];
        int ca = begA, cb = endA;
        float aA0=-1e30f, aA1=-1e30f, aB0=-1e30f, aB1=-1e30f;
        while (ca+2 <= endA && cb+2 <= endB) {
            int s0=srcs[ca], s1=srcs[ca+1], s2=srcs[cb], s3=srcs[cb+1];
            aA0 = fmaxf(aA0, p[(size_t)s0*64+lane]);
            aA1 = fmaxf(aA1, p[(size_t)s1*64+lane]);
            aB0 = fmaxf(aB0, p[(size_t)s2*64+lane]);
            aB1 = fmaxf(aB1, p[(size_t)s3*64+lane]);
            ca += 2; cb += 2;
        }
        while (ca+2 <= endA) {
            int s0=srcs[ca], s1=srcs[ca+1];
            aA0 = fmaxf(aA0, p[(size_t)s0*64+lane]);
            aA1 = fmaxf(aA1, p[(size_t)s1*64+lane]);
            ca += 2;
        }
        while (cb+2 <= endB) {
            int s2=srcs[cb], s3=srcs[cb+1];
            aB0 = fmaxf(aB0, p[(size_t)s2*64+lane]);
            aB1 = fmaxf(aB1, p[(size_t)s3*64+lane]);
            cb += 2;
        }
        if (ca < endA) aA0 = fmaxf(aA0, p[(size_t)srcs[ca]*64+lane]);
        if (cb < endB) aB0 = fmaxf(aB0, p[(size_t)srcs[cb]*64+lane]);
        float accA = fmaxf(aA0, aA1), accB = fmaxf(aB0, aB1);
        size_t oA = (size_t)dA*64 + lane, oB = oA + 64;
        q[oA] = fmaxf(accA + q[oA], 0.f);
        q[oB] = fmaxf(accB + q[oB], 0.f);
    }
}

// x2 = relu(agg@Wg+bg)+x1; h = relu([x2,rel]@Wm+bm)
__global__ __launch_bounds__(256, 1) void k_post_m2l(
    const float* __restrict__ agg, const float* __restrict__ Wg,
    const float* __restrict__ bg, const float* __restrict__ x1,
    const float* __restrict__ rel,
    const float* __restrict__ Wm, const float* __restrict__ bm,
    float* __restrict__ x2, float* __restrict__ h, int n)
{
    int lane = threadIdx.x & 63;
    int wid  = blockIdx.x * (blockDim.x >> 6) + (threadIdx.x >> 6);
    int nw   = gridDim.x * (blockDim.x >> 6);
    REPD(WLOAD, wg, Wg)
    REPD(WLOAD, wm, Wm)
    float wm64 = Wm[64*64+lane], wm65 = Wm[65*64+lane], wm66 = Wm[66*64+lane];
    float bgl = bg[lane], bml = bm[lane];
    for (int i0 = wid*2; i0 < n; i0 += nw*2) {
        int iA = __builtin_amdgcn_readfirstlane(i0);
        int iB = iA + 1;
        size_t oA = (size_t)iA*64 + lane, oB = oA + 64;
        float avA = agg[oA], avB = agg[oB];
        float s0A=0.f, s1A=0.f, s0B=0.f, s1B=0.f;
        REPP(WFMA, wg, avA, s0A, s1A)
        REPP(WFMA, wg, avB, s0B, s1B)
        float x2A = fmaxf(s0A+s1A + bgl, 0.f) + x1[oA];
        float x2B = fmaxf(s0B+s1B + bgl, 0.f) + x1[oB];
        x2[oA] = x2A; x2[oB] = x2B;
        float t0A=0.f, t1A=0.f, t0B=0.f, t1B=0.f;
        REPP(WFMA, wm, x2A, t0A, t1A)
        REPP(WFMA, wm, x2B, t0B, t1B)
        float hA = t0A+t1A + bml + rel[iA*3+0]*wm64 + rel[iA*3+1]*wm65 + rel[iA*3+2]*wm66;
        float hB = t0B+t1B + bml + rel[iB*3+0]*wm64 + rel[iB*3+1]*wm65 + rel[iB*3+2]*wm66;
        h[oA] = fmaxf(hA, 0.f);
        h[oB] = fmaxf(hB, 0.f);
    }
}

// c = segmax(h by labels); fused gnn_pre layer1 -> pa, qa   (M nodes, 2/wave)
__global__ __launch_bounds__(256, 2) void k_seglab_pre1(
    const int* __restrict__ rsL, const int* __restrict__ srcsL,
    const float* __restrict__ h, const float* __restrict__ pos,
    const float* __restrict__ Wh, const float* __restrict__ bh,
    const float* __restrict__ Wf, const float* __restrict__ bf,
    float* __restrict__ c, float* __restrict__ pa, float* __restrict__ qa, int m)
{
    int lane = threadIdx.x & 63;
    int wid  = blockIdx.x * (blockDim.x >> 6) + (threadIdx.x >> 6);
    int nw   = gridDim.x * (blockDim.x >> 6);
    REPD(WLOAD, wc, Wf + 3*64)
    float w0 = Wf[0*64+lane], w1 = Wf[1*64+lane], w2 = Wf[2*64+lane];
    float bfl = bf[lane];
    float wh0 = Wh[lane*3+0], wh1 = Wh[lane*3+1], wh2 = Wh[lane*3+2];
    float bh0 = bh[0], bh1 = bh[1], bh2 = bh[2];
    for (int d0 = wid*2; d0 < m; d0 += nw*2) {
        int dA = __builtin_amdgcn_readfirstlane(d0);
        int dB = dA + 1;
        int begA = rsL[dA], endA = rsL[dA+1], endB = rsL[dA+2];
        int ca = begA, cb = endA;
        float aA0=-1e30f, aA1=-1e30f, aB0=-1e30f, aB1=-1e30f;
        while (ca+2 <= endA && cb+2 <= endB) {
            int s0=srcsL[ca], s1=srcsL[ca+1], s2=srcsL[cb], s3=srcsL[cb+1];
            aA0 = fmaxf(aA0, h[(size_t)s0*64+lane]);
            aA1 = fmaxf(aA1, h[(size_t)s1*64+lane]);
            aB0 = fmaxf(aB0, h[(size_t)s2*64+lane]);
            aB1 = fmaxf(aB1, h[(size_t)s3*64+lane]);
            ca += 2; cb += 2;
        }
        while (ca+2 <= endA) {
            int s0=srcsL[ca], s1=srcsL[ca+1];
            aA0 = fmaxf(aA0, h[(size_t)s0*64+lane]);
            aA1 = fmaxf(aA1, h[(size_t)s1*64+lane]);
            ca += 2;
        }
        while (cb+2 <= endB) {
            int s2=srcsL[cb], s3=srcsL[cb+1];
            aB0 = fmaxf(aB0, h[(size_t)s2*64+lane]);
            aB1 = fmaxf(aB1, h[(size_t)s3*64+lane]);
            cb += 2;
        }
        if (ca < endA) aA0 = fmaxf(aA0, h[(size_t)srcsL[ca]*64+lane]);
        if (cb < endB) aB0 = fmaxf(aB0, h[(size_t)srcsL[cb]*64+lane]);
        float cvA = fmaxf(fmaxf(aA0,aA1), 0.f);
        float cvB = fmaxf(fmaxf(aB0,aB1), 0.f);
        c[(size_t)dA*64+lane] = cvA;
        c[(size_t)dB*64+lane] = cvB;
        float d0A = cvA*wh0, d1A = cvA*wh1, d2A = cvA*wh2;
        float d0B = cvB*wh0, d1B = cvB*wh1, d2B = cvB*wh2;
#pragma unroll
        for (int o = 32; o; o >>= 1) {
            d0A += __shfl_xor(d0A,o); d1A += __shfl_xor(d1A,o); d2A += __shfl_xor(d2A,o);
            d0B += __shfl_xor(d0B,o); d1B += __shfl_xor(d1B,o); d2B += __shfl_xor(d2B,o);
        }
        d0A = tanhf(d0A+bh0); d1A = tanhf(d1A+bh1); d2A = tanhf(d2A+bh2);
        d0B = tanhf(d0B+bh0); d1B = tanhf(d1B+bh1); d2B = tanhf(d2B+bh2);
        float pA0 = pos[dA*3+0], pA1 = pos[dA*3+1], pA2 = pos[dA*3+2];
        float pB0 = pos[dB*3+0], pB1 = pos[dB*3+1], pB2 = pos[dB*3+2];
        float s0A=0.f, s1A=0.f, s0B=0.f, s1B=0.f;
        REPP(WFMA, wc, cvA, s0A, s1A)
        REPP(WFMA, wc, cvB, s0B, s1B)
        pa[(size_t)dA*64+lane] = s0A+s1A + pA0*w0 + pA1*w1 + pA2*w2;
        pa[(size_t)dB*64+lane] = s0B+s1B + pB0*w0 + pB1*w1 + pB2*w2;
        qa[(size_t)dA*64+lane] = (d0A-pA0)*w0 + (d1A-pA1)*w1 + (d2A-pA2)*w2 + bfl;
        qa[(size_t)dB*64+lane] = (d0B-pB0)*w0 + (d1B-pB1)*w1 + (d2B-pB2)*w2 + bfl;
    }
}

// out = relu(agg@Wg + bg) + xres
__global__ __launch_bounds__(256, 2) void k_gnn_post(
    const float* __restrict__ agg, const float* __restrict__ Wg,
    const float* __restrict__ bg, const float* __restrict__ xres,
    float* __restrict__ out, int n)
{
    int lane = threadIdx.x & 63;
    int wid  = blockIdx.x * (blockDim.x >> 6) + (threadIdx.x >> 6);
    int nw   = gridDim.x * (blockDim.x >> 6);
    REPD(WLOAD, wg, Wg)
    float bgl = bg[lane];
    for (int i0 = wid*2; i0 < n; i0 += nw*2) {
        int iA = __builtin_amdgcn_readfirstlane(i0);
        size_t oA = (size_t)iA*64 + lane, oB = oA + 64;
        float avA = agg[oA], avB = agg[oB];
        float s0A=0.f, s1A=0.f, s0B=0.f, s1B=0.f;
        REPP(WFMA, wg, avA, s0A, s1A)
        REPP(WFMA, wg, avB, s0B, s1B)
        out[oA] = fmaxf(s0A+s1A + bgl, 0.f) + xres[oA];
        out[oB] = fmaxf(s0B+s1B + bgl, 0.f) + xres[oB];
    }
}

// x5 = relu([c4[lab], rel]@Wm+bm); fused gnn_pre layer2 -> p, q
__global__ __launch_bounds__(256, 1) void k_l2m_pre2(
    const float* __restrict__ c4, const int* __restrict__ lab,
    const float* __restrict__ rel, const float* __restrict__ pts,
    const float* __restrict__ Wm, const float* __restrict__ bm,
    const float* __restrict__ Wh, const float* __restrict__ bh,
    const float* __restrict__ Wf, const float* __restrict__ bf,
    float* __restrict__ x5, float* __restrict__ p, float* __restrict__ q, int n)
{
    int lane = threadIdx.x & 63;
    int wid  = blockIdx.x * (blockDim.x >> 6) + (threadIdx.x >> 6);
    int nw   = gridDim.x * (blockDim.x >> 6);
    REPD(WLOAD, wm, Wm)
    REPD(WLOAD, wf, Wf + 3*64)
    float wm64 = Wm[64*64+lane], wm65 = Wm[65*64+lane], wm66 = Wm[66*64+lane];
    float w0 = Wf[0*64+lane], w1 = Wf[1*64+lane], w2 = Wf[2*64+lane];
    float bml = bm[lane], bfl = bf[lane];
    float wh0 = Wh[lane*3+0], wh1 = Wh[lane*3+1], wh2 = Wh[lane*3+2];
    float bh0 = bh[0], bh1 = bh[1], bh2 = bh[2];
    for (int i0 = wid*2; i0 < n; i0 += nw*2) {
        int iA = __builtin_amdgcn_readfirstlane(i0);
        int iB = iA + 1;
        int lA = lab[iA], lB = lab[iB];
        float cvA = c4[(size_t)lA*64 + lane];
        float cvB = c4[(size_t)lB*64 + lane];
        float s0A=0.f, s1A=0.f, s0B=0.f, s1B=0.f;
        REPP(WFMA, wm, cvA, s0A, s1A)
        REPP(WFMA, wm, cvB, s0B, s1B)
        float hA = s0A+s1A + bml + rel[iA*3+0]*wm64 + rel[iA*3+1]*wm65 + rel[iA*3+2]*wm66;
        float hB = s0B+s1B + bml + rel[iB*3+0]*wm64 + rel[iB*3+1]*wm65 + rel[iB*3+2]*wm66;
        float xvA = fmaxf(hA, 0.f), xvB = fmaxf(hB, 0.f);
        size_t oA = (size_t)iA*64 + lane, oB = oA + 64;
        x5[oA] = xvA; x5[oB] = xvB;
        float d0A = xvA*wh0, d1A = xvA*wh1, d2A = xvA*wh2;
        float d0B = xvB*wh0, d1B = xvB*wh1, d2B = xvB*wh2;
#pragma unroll
        for (int o = 32; o; o >>= 1) {
            d0A += __shfl_xor(d0A,o); d1A += __shfl_xor(d1A,o); d2A += __shfl_xor(d2A,o);
            d0B += __shfl_xor(d0B,o); d1B += __shfl_xor(d1B,o); d2B += __shfl_xor(d2B,o);
        }
        d0A = tanhf(d0A+bh0); d1A = tanhf(d1A+bh1); d2A = tanhf(d2A+bh2);
        d0B = tanhf(d0B+bh0); d1B = tanhf(d1B+bh1); d2B = tanhf(d2B+bh2);
        float pA0 = pts[iA*3+0], pA1 = pts[iA*3+1], pA2 = pts[iA*3+2];
        float pB0 = pts[iB*3+0], pB1 = pts[iB*3+1], pB2 = pts[iB*3+2];
        float t0A=0.f, t1A=0.f, t0B=0.f, t1B=0.f;
        REPP(WFMA, wf, xvA, t0A, t1A)
        REPP(WFMA, wf, xvB, t0B, t1B)
        p[oA] = t0A+t1A + pA0*w0 + pA1*w1 + pA2*w2;
        p[oB] = t0B+t1B + pB0*w0 + pB1*w1 + pB2*w2;
        q[oA] = (d0A-pA0)*w0 + (d1A-pA1)*w1 + (d2A-pA2)*w2 + bfl;
        q[oB] = (d0B-pB0)*w0 + (d1B-pB1)*w1 + (d2B-pB2)*w2 + bfl;
    }
}

// x6 = relu(agg@Wg+bg)+x5; fin = x6+x2; t = relu(fin@W1+b1); out = t@W2+b2
__global__ __launch_bounds__(256, 1) void k_gnn_post_final(
    const float* __restrict__ agg, const float* __restrict__ Wg,
    const float* __restrict__ bg,
    const float* __restrict__ x5, const float* __restrict__ x2,
    const float* __restrict__ W1, const float* __restrict__ b1,
    const float* __restrict__ W2, const float* __restrict__ b2,
    float* __restrict__ out, int n)
{
    int lane = threadIdx.x & 63;
    int wid  = blockIdx.x * (blockDim.x >> 6) + (threadIdx.x >> 6);
    int nw   = gridDim.x * (blockDim.x >> 6);
    REPD(WLOAD, wg, Wg)
    REPD(WLOAD, w1c, W1)
    float w2c0 = W2[lane*4+0], w2c1 = W2[lane*4+1], w2c2 = W2[lane*4+2], w2c3 = W2[lane*4+3];
    float bgl = bg[lane], b1l = b1[lane];
    float b20 = b2[0], b21 = b2[1], b22 = b2[2], b23 = b2[3];
    for (int i0 = wid*2; i0 < n; i0 += nw*2) {
        int iA = __builtin_amdgcn_readfirstlane(i0);
        int iB = iA + 1;
        size_t oA = (size_t)iA*64 + lane, oB = oA + 64;
        float avA = agg[oA], avB = agg[oB];
        float s0A=0.f, s1A=0.f, s0B=0.f, s1B=0.f;
        REPP(WFMA, wg, avA, s0A, s1A)
        REPP(WFMA, wg, avB, s0B, s1B)
        float finA = fmaxf(s0A+s1A + bgl, 0.f) + x5[oA] + x2[oA];
        float finB = fmaxf(s0B+s1B + bgl, 0.f) + x5[oB] + x2[oB];
        float t0A=0.f, t1A=0.f, t0B=0.f, t1B=0.f;
        REPP(WFMA, w1c, finA, t0A, t1A)
        REPP(WFMA, w1c, finB, t0B, t1B)
        float tA = fmaxf(t0A+t1A + b1l, 0.f);
        float tB = fmaxf(t0B+t1B + b1l, 0.f);
        float o0A = wredsum(tA * w2c0), o1A = wredsum(tA * w2c1);
        float o2A = wredsum(tA * w2c2), o3A = wredsum(tA * w2c3);
        float o0B = wredsum(tB * w2c0), o1B = wredsum(tB * w2c1);
        float o2B = wredsum(tB * w2c2), o3B = wredsum(tB * w2c3);
        if (lane == 0) {
            *(float4*)(out + (size_t)iA*4) = make_float4(o0A+b20, o1A+b21, o2A+b22, o3A+b23);
            *(float4*)(out + (size_t)iB*4) = make_float4(o0B+b20, o1B+b21, o2B+b22, o3B+b23);
        }
    }
}

// ---------------- launch ----------------

extern "C" void kernel_launch(void* const* d_in, const int* in_sizes, int n_in,
                              void* d_out, int out_size, void* d_ws, size_t ws_size,
                              hipStream_t stream)
{
    const int N = 100000, M = 10000, E0 = 1600000, E1 = 320000;
    const int NB0 = (N + 255) / 256;   // 391
    const int NB1 = (M + 255) / 256;   // 40
    const int NBL = (M + 255) / 256;   // 40

    const float* feat = (const float*)d_in[0];
    const float* pts  = (const float*)d_in[1];
    const float* ctr  = (const float*)d_in[2];
    const int*   lab  = (const int*)d_in[3];
    const int2*  e0   = (const int2*)d_in[4];
    const int2*  e1   = (const int2*)d_in[5];
    const float* feW  = (const float*)d_in[6];
    const float* feb  = (const float*)d_in[7];
    const float* Wh   = (const float*)d_in[8];
    const float* bh   = (const float*)d_in[9];
    const float* Wf   = (const float*)d_in[10];
    const float* bf   = (const float*)d_in[11];
    const float* Wg   = (const float*)d_in[12];
    const float* bg   = (const float*)d_in[13];
    const float* m2lW = (const float*)d_in[14];
    const float* m2lb = (const float*)d_in[15];
    const float* l2mW = (const float*)d_in[16];
    const float* l2mb = (const float*)d_in[17];
    const float* cW1  = (const float*)d_in[18];
    const float* cb1  = (const float*)d_in[19];
    const float* cW2  = (const float*)d_in[20];
    const float* cb2  = (const float*)d_in[21];
    float* out = (float*)d_out;

    char* ws = (char*)d_ws;
    size_t off = 0;
    auto alloc = [&](size_t bytes) -> char* {
        char* r = ws + off; off += (bytes + 255) & ~(size_t)255; return r;
    };
    float* rel   = (float*)alloc((size_t)N*3*4);
    float* x1    = (float*)alloc((size_t)N*64*4);   // x1, later x5
    float* x2    = (float*)alloc((size_t)N*64*4);   // hosts ebufs pre-compute
    float* p     = (float*)alloc((size_t)N*64*4);   // p0 / h / p2
    float* q     = (float*)alloc((size_t)N*64*4);   // q0/agg0, [p1|q1], q2/agg2
    float* c     = (float*)alloc((size_t)M*64*4);
    float* c4    = (float*)alloc((size_t)M*64*4);
    int* rs0     = (int*)alloc((size_t)(N+2)*4);
    int* srcs0   = (int*)alloc((size_t)E0*4);
    int* rs1     = (int*)alloc((size_t)(M+2)*4);
    int* srcs1   = (int*)alloc((size_t)E1*4);
    int* rsL     = (int*)alloc((size_t)(M+2)*4);
    int* srcsL   = (int*)alloc((size_t)N*4);
    int* cnt0    = (int*)alloc((size_t)NB0*4);
    int* cnt1    = (int*)alloc((size_t)NB1*4);
    int* cntL    = (int*)alloc((size_t)NBL*4);
    int* base0   = (int*)alloc((size_t)(NB0+1)*4);
    int* base1   = (int*)alloc((size_t)(NB1+1)*4);
    int* baseL   = (int*)alloc((size_t)(NBL+1)*4);
    int* cur0    = (int*)alloc((size_t)NB0*4);
    int* cur1    = (int*)alloc((size_t)NB1*4);
    int* curL    = (int*)alloc((size_t)NBL*4);
    (void)ws_size; (void)in_sizes; (void)n_in; (void)out_size;

    int2* ebuf0 = (int2*)x2;
    int2* ebuf1 = ebuf0 + E0;
    int2* ebufL = ebuf1 + E1;

    dim3 blk(256);
    const int gridN = 2048, gridM = 640, gSeg = 3072;

    // ---- CSR builds ----
    hipMemsetAsync(cnt0, 0, (size_t)NB0*4, stream);
    hipMemsetAsync(cnt1, 0, (size_t)NB1*4, stream);
    hipMemsetAsync(cntL, 0, (size_t)NBL*4, stream);
    k_bhist_e<<<1024, blk, 0, stream>>>(e0, cnt0, E0, NB0);
    k_bhist_e<<<512,  blk, 0, stream>>>(e1, cnt1, E1, NB1);
    k_bhist_l<<<512,  blk, 0, stream>>>(lab, cntL, N, NBL);
    k_bscan3<<<3, 512, 0, stream>>>(cnt0, base0, cur0, NB0, E0,
                                    cnt1, base1, cur1, NB1, E1,
                                    cntL, baseL, curL, NBL, N);
    k_bucket_e<<<(E0 + BKT*EPT - 1)/(BKT*EPT), BKT, 0, stream>>>(e0, cur0, ebuf0, E0, NB0);
    k_bucket_e<<<(E1 + BKT*EPT - 1)/(BKT*EPT), BKT, 0, stream>>>(e1, cur1, ebuf1, E1, NB1);
    k_bucket_l<<<(N  + BKT*EPT - 1)/(BKT*EPT), BKT, 0, stream>>>(lab, curL, ebufL, N, NBL);
    k_final<<<NB0, 512, 0, stream>>>(ebuf0, base0, rs0, srcs0, N, E0, NB0);
    k_final<<<NB1, 512, 0, stream>>>(ebuf1, base1, rs1, srcs1, M, E1, NB1);
    k_final<<<NBL, 512, 0, stream>>>(ebufL, baseL, rsL, srcsL, M, N, NBL);

    // ---- layer 0 ----
    k_feat_pre0<<<gridN, blk, 0, stream>>>(feat, pts, ctr, lab, feW, feb,
                                           Wh+0*64*3, bh+0*3, Wf+0*67*64, bf+0*64,
                                           rel, x1, p, q, N);
    k_seg_max_gnn<<<gSeg, blk, 0, stream>>>(rs0, srcs0, p, q, N);
    k_post_m2l<<<gridN, blk, 0, stream>>>(q, Wg+0*64*64, bg+0*64, x1, rel,
                                          m2lW, m2lb, x2, p, N);

    // ---- layer 1 (clusters) ----
    float* p1 = q;
    float* q1 = q + (size_t)M*64;
    k_seglab_pre1<<<gridM, blk, 0, stream>>>(rsL, srcsL, p, ctr,
                                             Wh+1*64*3, bh+1*3, Wf+1*67*64, bf+1*64,
                                             c, p1, q1, M);
    k_seg_max_gnn<<<640, blk, 0, stream>>>(rs1, srcs1, p1, q1, M);
    k_gnn_post<<<gridM, blk, 0, stream>>>(q1, Wg+1*64*64, bg+1*64, c, c4, M);

    // ---- l2m + layer 2 + classifier ----
    k_l2m_pre2<<<gridN, blk, 0, stream>>>(c4, lab, rel, pts, l2mW, l2mb,
                                          Wh+2*64*3, bh+2*3, Wf+2*67*64, bf+2*64,
                                          x1, p, q, N);
    k_seg_max_gnn<<<gSeg, blk, 0, stream>>>(rs0, srcs0, p, q, N);
    k_gnn_post_final<<<gridN, blk, 0, stream>>>(q, Wg+2*64*64, bg+2*64, x1, x2,
                                                cW1, cb1, cW2, cb2, out, N);
}

// Round 9
// 522.505 us; speedup vs baseline: 1.1426x; 1.0365x over previous
//
#include <hip/hip_runtime.h>

// ---------------- helpers ----------------

__device__ __forceinline__ float wredsum(float v) {
#pragma unroll
    for (int o = 32; o; o >>= 1) v += __shfl_xor(v, o);
    return v;
}

__device__ __forceinline__ float bcast(float v, int l) {
    return __int_as_float(__builtin_amdgcn_readlane(__float_as_int(v), l));
}

// 64 NAMED weight scalars per matrix (VALU matvec kernels)
#define REPD(M,P,B) \
 M(0,P,B)  M(1,P,B)  M(2,P,B)  M(3,P,B)  M(4,P,B)  M(5,P,B)  M(6,P,B)  M(7,P,B) \
 M(8,P,B)  M(9,P,B)  M(10,P,B) M(11,P,B) M(12,P,B) M(13,P,B) M(14,P,B) M(15,P,B) \
 M(16,P,B) M(17,P,B) M(18,P,B) M(19,P,B) M(20,P,B) M(21,P,B) M(22,P,B) M(23,P,B) \
 M(24,P,B) M(25,P,B) M(26,P,B) M(27,P,B) M(28,P,B) M(29,P,B) M(30,P,B) M(31,P,B) \
 M(32,P,B) M(33,P,B) M(34,P,B) M(35,P,B) M(36,P,B) M(37,P,B) M(38,P,B) M(39,P,B) \
 M(40,P,B) M(41,P,B) M(42,P,B) M(43,P,B) M(44,P,B) M(45,P,B) M(46,P,B) M(47,P,B) \
 M(48,P,B) M(49,P,B) M(50,P,B) M(51,P,B) M(52,P,B) M(53,P,B) M(54,P,B) M(55,P,B) \
 M(56,P,B) M(57,P,B) M(58,P,B) M(59,P,B) M(60,P,B) M(61,P,B) M(62,P,B) M(63,P,B)

#define WLOAD(J,P,B) float P##J = (B)[(J)*64+lane];

#define REPP(M,P,X,S0,S1) \
 M(0,1,P,X,S0,S1)  M(2,3,P,X,S0,S1)  M(4,5,P,X,S0,S1)  M(6,7,P,X,S0,S1) \
 M(8,9,P,X,S0,S1)  M(10,11,P,X,S0,S1) M(12,13,P,X,S0,S1) M(14,15,P,X,S0,S1) \
 M(16,17,P,X,S0,S1) M(18,19,P,X,S0,S1) M(20,21,P,X,S0,S1) M(22,23,P,X,S0,S1) \
 M(24,25,P,X,S0,S1) M(26,27,P,X,S0,S1) M(28,29,P,X,S0,S1) M(30,31,P,X,S0,S1) \
 M(32,33,P,X,S0,S1) M(34,35,P,X,S0,S1) M(36,37,P,X,S0,S1) M(38,39,P,X,S0,S1) \
 M(40,41,P,X,S0,S1) M(42,43,P,X,S0,S1) M(44,45,P,X,S0,S1) M(46,47,P,X,S0,S1) \
 M(48,49,P,X,S0,S1) M(50,51,P,X,S0,S1) M(52,53,P,X,S0,S1) M(54,55,P,X,S0,S1) \
 M(56,57,P,X,S0,S1) M(58,59,P,X,S0,S1) M(60,61,P,X,S0,S1) M(62,63,P,X,S0,S1)

#define WFMA(J,K,P,X,S0,S1) \
 S0 = fmaf(bcast(X,J), P##J, S0); \
 S1 = fmaf(bcast(X,K), P##K, S1);

// ---------------- MFMA split-bf16 machinery ----------------

typedef short bf16x8 __attribute__((ext_vector_type(8)));
typedef float f32x4  __attribute__((ext_vector_type(4)));

__device__ __forceinline__ unsigned short f2bf_rne(float x) {
    unsigned u = __float_as_uint(x);
    unsigned r = u + 0x7FFFu + ((u >> 16) & 1u);
    return (unsigned short)(r >> 16);
}

// A-fragment for one k-tile: lane holds row = lane&15; k = kt*32 + (j>>2)*16 + (lane>>4)*4 + (j&3)
__device__ __forceinline__ void a_frag(const float* __restrict__ row, int kt, int g4,
                                       bf16x8& ah, bf16x8& al)
{
    const float4 a0 = *(const float4*)(row + kt*32 + g4);
    const float4 a1 = *(const float4*)(row + kt*32 + 16 + g4);
    float v0 = a0.x, v1 = a0.y, v2 = a0.z, v3 = a0.w;
    float v4 = a1.x, v5 = a1.y, v6 = a1.z, v7 = a1.w;
#define CVT1(idx, val) { \
    unsigned short hh = f2bf_rne(val); \
    float lf = (val) - __uint_as_float((unsigned)hh << 16); \
    ah[idx] = (short)hh; al[idx] = (short)f2bf_rne(lf); }
    CVT1(0,v0) CVT1(1,v1) CVT1(2,v2) CVT1(3,v3)
    CVT1(4,v4) CVT1(5,v5) CVT1(6,v6) CVT1(7,v7)
#undef CVT1
}

// Pack a 64x64 fp32 W into B-fragment order, bf16 hi/lo.
// dst[frag*1024 + h*512 + lane*8 + j] shorts; frag = kt*4+nt;
// element: k = kt*32 + (j>>2)*16 + (lane>>4)*4 + (j&3); n = nt*16 + (lane&15)
__global__ __launch_bounds__(256) void k_packB(
    const float* __restrict__ W, unsigned short* __restrict__ dst)
{
    int t = threadIdx.x;
    for (int slot = t; slot < 512; slot += 256) {
        int frag = slot >> 6;
        int lane = slot & 63;
        int kt = frag >> 2, nt = frag & 3;
        int g4 = (lane >> 4) * 4, n = nt*16 + (lane & 15);
        for (int j = 0; j < 8; ++j) {
            int k = kt*32 + (j>>2)*16 + g4 + (j&3);
            float x = W[k*64 + n];
            unsigned short hh = f2bf_rne(x);
            float lf = x - __uint_as_float((unsigned)hh << 16);
            dst[frag*1024 + 0*512 + lane*8 + j] = hh;
            dst[frag*1024 + 1*512 + lane*8 + j] = f2bf_rne(lf);
        }
    }
}

// Y = X[Ntiles*16 x 64] @ W (packed) + bias, then epilogue:
//  EPI=0: out = relu(Y) + res
//  EPI=1: out = relu(Y + rel . Wtail[64..66])
template<int EPI>
__global__ __launch_bounds__(256) void k_gemm(
    const float* __restrict__ X, const unsigned short* __restrict__ pW,
    const float* __restrict__ bias, const float* __restrict__ res,
    const float* __restrict__ rel, const float* __restrict__ Wtail,
    float* __restrict__ out, int ntiles)
{
    int lane = threadIdx.x & 63;
    int tile = blockIdx.x*4 + (threadIdx.x >> 6);
    if (tile >= ntiles) return;
    int r0 = tile * 16;
    int g4 = (lane >> 4) * 4;
    const float* rowp = X + (size_t)(r0 + (lane & 15)) * 64;
    bf16x8 ah0, al0, ah1, al1;
    a_frag(rowp, 0, g4, ah0, al0);
    a_frag(rowp, 1, g4, ah1, al1);
    f32x4 acc[4];
#pragma unroll
    for (int nt = 0; nt < 4; ++nt) {
        f32x4 a = {0.f, 0.f, 0.f, 0.f};
#pragma unroll
        for (int kt = 0; kt < 2; ++kt) {
            bf16x8 bh = *(const bf16x8*)(pW + (kt*4+nt)*1024 + lane*8);
            bf16x8 bl = *(const bf16x8*)(pW + (kt*4+nt)*1024 + 512 + lane*8);
            bf16x8 aH = kt ? ah1 : ah0;
            bf16x8 aL = kt ? al1 : al0;
            a = __builtin_amdgcn_mfma_f32_16x16x32_bf16(aH, bh, a, 0, 0, 0);
            a = __builtin_amdgcn_mfma_f32_16x16x32_bf16(aL, bh, a, 0, 0, 0);
            a = __builtin_amdgcn_mfma_f32_16x16x32_bf16(aH, bl, a, 0, 0, 0);
        }
        acc[nt] = a;
    }
    int rbase = r0 + (lane >> 4) * 4;
#pragma unroll
    for (int nt = 0; nt < 4; ++nt) {
        int c = nt*16 + (lane & 15);
        float bc = bias[c];
        float w0t = 0.f, w1t = 0.f, w2t = 0.f;
        if (EPI == 1) { w0t = Wtail[64*64+c]; w1t = Wtail[65*64+c]; w2t = Wtail[66*64+c]; }
#pragma unroll
        for (int reg = 0; reg < 4; ++reg) {
            int r = rbase + reg;
            float v = acc[nt][reg] + bc;
            if (EPI == 0) {
                v = fmaxf(v, 0.f) + res[(size_t)r*64 + c];
            } else {
                v += rel[r*3+0]*w0t + rel[r*3+1]*w1t + rel[r*3+2]*w2t;
                v = fmaxf(v, 0.f);
            }
            out[(size_t)r*64 + c] = v;
        }
    }
}

// ================= bucketed CSR build =================

__global__ __launch_bounds__(256) void k_bhist_e(
    const int2* __restrict__ e, int* __restrict__ gcnt, int E, int nb)
{
    __shared__ int c[400];
    for (int i = threadIdx.x; i < nb; i += 256) c[i] = 0;
    __syncthreads();
    for (int idx = blockIdx.x*256 + threadIdx.x; idx < E; idx += gridDim.x*256)
        atomicAdd(&c[e[idx].y >> 8], 1);
    __syncthreads();
    for (int i = threadIdx.x; i < nb; i += 256) if (c[i]) atomicAdd(&gcnt[i], c[i]);
}

__global__ __launch_bounds__(256) void k_bhist_l(
    const int* __restrict__ lab, int* __restrict__ gcnt, int n, int nb)
{
    __shared__ int c[400];
    for (int i = threadIdx.x; i < nb; i += 256) c[i] = 0;
    __syncthreads();
    for (int idx = blockIdx.x*256 + threadIdx.x; idx < n; idx += gridDim.x*256)
        atomicAdd(&c[lab[idx] >> 8], 1);
    __syncthreads();
    for (int i = threadIdx.x; i < nb; i += 256) if (c[i]) atomicAdd(&gcnt[i], c[i]);
}

__global__ __launch_bounds__(512) void k_bscan3(
    const int* c0, int* b0, int* u0, int nb0, int t0,
    const int* c1, int* b1, int* u1, int nb1, int t1,
    const int* c2, int* b2, int* u2, int nb2, int t2)
{
    const int* cnt; int* base; int* cur; int nb; int tot;
    if (blockIdx.x == 0) { cnt=c0; base=b0; cur=u0; nb=nb0; tot=t0; }
    else if (blockIdx.x == 1) { cnt=c1; base=b1; cur=u1; nb=nb1; tot=t1; }
    else { cnt=c2; base=b2; cur=u2; nb=nb2; tot=t2; }
    __shared__ int sc[512];
    int t = threadIdx.x;
    int v = (t < nb) ? cnt[t] : 0;
    sc[t] = v; __syncthreads();
    for (int o = 1; o < 512; o <<= 1) {
        int a = (t >= o) ? sc[t-o] : 0;
        __syncthreads();
        sc[t] += a;
        __syncthreads();
    }
    if (t < nb) { int ex = sc[t] - v; base[t] = ex; cur[t] = ex; }
    if (t == nb) base[nb] = tot;
}

#define BKT 512
#define EPT 8
__global__ __launch_bounds__(BKT) void k_bucket_e(
    const int2* __restrict__ e, int* __restrict__ cur,
    int2* __restrict__ ebuf, int E, int nb)
{
    __shared__ int cnt[400];
    __shared__ int chunk[400];
    int t = threadIdx.x;
    int base = blockIdx.x * (BKT*EPT);
    for (int i = t; i < nb; i += BKT) cnt[i] = 0;
    __syncthreads();
    int2 ed[EPT]; int rk[EPT];
#pragma unroll
    for (int k = 0; k < EPT; ++k) {
        int idx = base + k*BKT + t;
        if (idx < E) { ed[k] = e[idx]; rk[k] = atomicAdd(&cnt[ed[k].y >> 8], 1); }
        else rk[k] = -1;
    }
    __syncthreads();
    for (int i = t; i < nb; i += BKT) { int c = cnt[i]; if (c) chunk[i] = atomicAdd(&cur[i], c); }
    __syncthreads();
#pragma unroll
    for (int k = 0; k < EPT; ++k)
        if (rk[k] >= 0) ebuf[chunk[ed[k].y >> 8] + rk[k]] = ed[k];
}

__global__ __launch_bounds__(BKT) void k_bucket_l(
    const int* __restrict__ lab, int* __restrict__ cur,
    int2* __restrict__ ebuf, int n, int nb)
{
    __shared__ int cnt[400];
    __shared__ int chunk[400];
    int t = threadIdx.x;
    int base = blockIdx.x * (BKT*EPT);
    for (int i = t; i < nb; i += BKT) cnt[i] = 0;
    __syncthreads();
    int2 ed[EPT]; int rk[EPT];
#pragma unroll
    for (int k = 0; k < EPT; ++k) {
        int idx = base + k*BKT + t;
        if (idx < n) { ed[k] = make_int2(idx, lab[idx]); rk[k] = atomicAdd(&cnt[ed[k].y >> 8], 1); }
        else rk[k] = -1;
    }
    __syncthreads();
    for (int i = t; i < nb; i += BKT) { int c = cnt[i]; if (c) chunk[i] = atomicAdd(&cur[i], c); }
    __syncthreads();
#pragma unroll
    for (int k = 0; k < EPT; ++k)
        if (rk[k] >= 0) ebuf[chunk[ed[k].y >> 8] + rk[k]] = ed[k];
}

__global__ __launch_bounds__(512) void k_final(
    const int2* __restrict__ ebuf, const int* __restrict__ base_,
    int* __restrict__ rs, int* __restrict__ srcs, int ndst, int etot, int nb)
{
    __shared__ int h[256];
    __shared__ int sc[256];
    int b = blockIdx.x, t = threadIdx.x;
    int base = base_[b];
    int cnt  = base_[b+1] - base;
    int d0 = b << 8;
    if (t < 256) h[t] = 0;
    __syncthreads();
    for (int i = t; i < cnt; i += 512) atomicAdd(&h[ebuf[base+i].y - d0], 1);
    __syncthreads();
    int v = (t < 256) ? h[t] : 0;
    if (t < 256) sc[t] = v;
    __syncthreads();
    for (int o = 1; o < 256; o <<= 1) {
        int a = (t < 256 && t >= o) ? sc[t-o] : 0;
        __syncthreads();
        if (t < 256) sc[t] += a;
        __syncthreads();
    }
    if (t < 256) {
        int gpos = base + sc[t] - v;
        if (d0 + t < ndst) rs[d0+t] = gpos;
        h[t] = gpos;
    }
    if (b == nb-1 && t == 0) rs[ndst] = etot;
    __syncthreads();
    for (int i = t; i < cnt; i += 512) {
        int2 ed = ebuf[base+i];
        int pos = atomicAdd(&h[ed.y - d0], 1);
        srcs[pos] = ed.x;
    }
}

// ================= compute kernels (VALU) =================

__global__ __launch_bounds__(256, 2) void k_feat_pre0(
    const float* __restrict__ feat, const float* __restrict__ pts,
    const float* __restrict__ ctr, const int* __restrict__ lab,
    const float* __restrict__ Wfe, const float* __restrict__ bfe,
    const float* __restrict__ Wh, const float* __restrict__ bh,
    const float* __restrict__ Wf, const float* __restrict__ bf,
    float* __restrict__ rel, float* __restrict__ x1,
    float* __restrict__ p, float* __restrict__ q, int n)
{
    int lane = threadIdx.x & 63;
    int wid  = blockIdx.x * (blockDim.x >> 6) + (threadIdx.x >> 6);
    int nw   = gridDim.x * (blockDim.x >> 6);
    float fe0 = Wfe[0*64+lane], fe1 = Wfe[1*64+lane], fe2 = Wfe[2*64+lane], fe3 = Wfe[3*64+lane];
    float fe4 = Wfe[4*64+lane], fe5 = Wfe[5*64+lane], fe6 = Wfe[6*64+lane];
    float bfe_l = bfe[lane];
    REPD(WLOAD, wc, Wf + 3*64)
    float w0 = Wf[0*64+lane], w1 = Wf[1*64+lane], w2 = Wf[2*64+lane];
    float bfl = bf[lane];
    float wh0 = Wh[lane*3+0], wh1 = Wh[lane*3+1], wh2 = Wh[lane*3+2];
    float bh0 = bh[0], bh1 = bh[1], bh2 = bh[2];
    for (int i0 = wid*2; i0 < n; i0 += nw*2) {
        int iA = __builtin_amdgcn_readfirstlane(i0);
        int iB = iA + 1;
        int lA = lab[iA], lB = lab[iB];
        float pA0 = pts[iA*3+0], pA1 = pts[iA*3+1], pA2 = pts[iA*3+2];
        float pB0 = pts[iB*3+0], pB1 = pts[iB*3+1], pB2 = pts[iB*3+2];
        float rA0 = pA0 - ctr[lA*3+0], rA1 = pA1 - ctr[lA*3+1], rA2 = pA2 - ctr[lA*3+2];
        float rB0 = pB0 - ctr[lB*3+0], rB1 = pB1 - ctr[lB*3+1], rB2 = pB2 - ctr[lB*3+2];
        if (lane == 0)      { rel[iA*3+0]=rA0; rel[iA*3+1]=rA1; rel[iA*3+2]=rA2; }
        else if (lane == 1) { rel[iB*3+0]=rB0; rel[iB*3+1]=rB1; rel[iB*3+2]=rB2; }
        float aA = bfe_l, aB = bfe_l;
        aA = fmaf(feat[iA*4+0], fe0, aA); aB = fmaf(feat[iB*4+0], fe0, aB);
        aA = fmaf(feat[iA*4+1], fe1, aA); aB = fmaf(feat[iB*4+1], fe1, aB);
        aA = fmaf(feat[iA*4+2], fe2, aA); aB = fmaf(feat[iB*4+2], fe2, aB);
        aA = fmaf(feat[iA*4+3], fe3, aA); aB = fmaf(feat[iB*4+3], fe3, aB);
        aA = fmaf(rA0, fe4, aA); aB = fmaf(rB0, fe4, aB);
        aA = fmaf(rA1, fe5, aA); aB = fmaf(rB1, fe5, aB);
        aA = fmaf(rA2, fe6, aA); aB = fmaf(rB2, fe6, aB);
        float xvA = fmaxf(aA, 0.f), xvB = fmaxf(aB, 0.f);
        x1[(size_t)iA*64+lane] = xvA;
        x1[(size_t)iB*64+lane] = xvB;
        float d0A = xvA*wh0, d1A = xvA*wh1, d2A = xvA*wh2;
        float d0B = xvB*wh0, d1B = xvB*wh1, d2B = xvB*wh2;
#pragma unroll
        for (int o = 32; o; o >>= 1) {
            d0A += __shfl_xor(d0A,o); d1A += __shfl_xor(d1A,o); d2A += __shfl_xor(d2A,o);
            d0B += __shfl_xor(d0B,o); d1B += __shfl_xor(d1B,o); d2B += __shfl_xor(d2B,o);
        }
        d0A = tanhf(d0A+bh0); d1A = tanhf(d1A+bh1); d2A = tanhf(d2A+bh2);
        d0B = tanhf(d0B+bh0); d1B = tanhf(d1B+bh1); d2B = tanhf(d2B+bh2);
        float s0A=0.f, s1A=0.f, s0B=0.f, s1B=0.f;
        REPP(WFMA, wc, xvA, s0A, s1A)
        REPP(WFMA, wc, xvB, s0B, s1B)
        p[(size_t)iA*64+lane] = s0A+s1A + pA0*w0 + pA1*w1 + pA2*w2;
        p[(size_t)iB*64+lane] = s0B+s1B + pB0*w0 + pB1*w1 + pB2*w2;
        q[(size_t)iA*64+lane] = (d0A-pA0)*w0 + (d1A-pA1)*w1 + (d2A-pA2)*w2 + bfl;
        q[(size_t)iB*64+lane] = (d0B-pB0)*w0 + (d1B-pB1)*w1 + (d2B-pB2)*w2 + bfl;
    }
}

__global__ __launch_bounds__(256) void k_seg_max_gnn(
    const int* __restrict__ rs, const int* __restrict__ srcs,
    const float* __restrict__ p, float* __restrict__ q, int n)
{
    int lane = threadIdx.x & 63;
    int wid  = blockIdx.x * (blockDim.x >> 6) + (threadIdx.x >> 6);
    int nw   = gridDim.x * (blockDim.x >> 6);
    for (int d0 = wid*2; d0 < n; d0 += nw*2) {
        int dA = __builtin_amdgcn_readfirstlane(d0);
        int begA = rs[dA], endA = rs[dA+1], endB = rs[dA+2];
        int ca = begA, cb = endA;
        float aA0=-1e30f, aA1=-1e30f, aB0=-1e30f, aB1=-1e30f;
        while (ca+2 <= endA && cb+2 <= endB) {
            int s0=srcs[ca], s1=srcs[ca+1], s2=srcs[cb], s3=srcs[cb+1];
            aA0 = fmaxf(aA0, p[(size_t)s0*64+lane]);
            aA1 = fmaxf(aA1, p[(size_t)s1*64+lane]);
            aB0 = fmaxf(aB0, p[(size_t)s2*64+lane]);
            aB1 = fmaxf(aB1, p[(size_t)s3*64+lane]);
            ca += 2; cb += 2;
        }
        while (ca+2 <= endA) {
            int s0=srcs[ca], s1=srcs[ca+1];
            aA0 = fmaxf(aA0, p[(size_t)s0*64+lane]);
            aA1 = fmaxf(aA1, p[(size_t)s1*64+lane]);
            ca += 2;
        }
        while (cb+2 <= endB) {
            int s2=srcs[cb], s3=srcs[cb+1];
            aB0 = fmaxf(aB0, p[(size_t)s2*64+lane]);
            aB1 = fmaxf(aB1, p[(size_t)s3*64+lane]);
            cb += 2;
        }
        if (ca < endA) aA0 = fmaxf(aA0, p[(size_t)srcs[ca]*64+lane]);
        if (cb < endB) aB0 = fmaxf(aB0, p[(size_t)srcs[cb]*64+lane]);
        float accA = fmaxf(aA0, aA1), accB = fmaxf(aB0, aB1);
        size_t oA = (size_t)dA*64 + lane, oB = oA + 64;
        q[oA] = fmaxf(accA + q[oA], 0.f);
        q[oB] = fmaxf(accB + q[oB], 0.f);
    }
}

__global__ __launch_bounds__(256, 2) void k_seglab_pre1(
    const int* __restrict__ rsL, const int* __restrict__ srcsL,
    const float* __restrict__ h, const float* __restrict__ pos,
    const float* __restrict__ Wh, const float* __restrict__ bh,
    const float* __restrict__ Wf, const float* __restrict__ bf,
    float* __restrict__ c, float* __restrict__ pa, float* __restrict__ qa, int m)
{
    int lane = threadIdx.x & 63;
    int wid  = blockIdx.x * (blockDim.x >> 6) + (threadIdx.x >> 6);
    int nw   = gridDim.x * (blockDim.x >> 6);
    REPD(WLOAD, wc, Wf + 3*64)
    float w0 = Wf[0*64+lane], w1 = Wf[1*64+lane], w2 = Wf[2*64+lane];
    float bfl = bf[lane];
    float wh0 = Wh[lane*3+0], wh1 = Wh[lane*3+1], wh2 = Wh[lane*3+2];
    float bh0 = bh[0], bh1 = bh[1], bh2 = bh[2];
    for (int d0 = wid*2; d0 < m; d0 += nw*2) {
        int dA = __builtin_amdgcn_readfirstlane(d0);
        int dB = dA + 1;
        int begA = rsL[dA], endA = rsL[dA+1], endB = rsL[dA+2];
        int ca = begA, cb = endA;
        float aA0=-1e30f, aA1=-1e30f, aB0=-1e30f, aB1=-1e30f;
        while (ca+2 <= endA && cb+2 <= endB) {
            int s0=srcsL[ca], s1=srcsL[ca+1], s2=srcsL[cb], s3=srcsL[cb+1];
            aA0 = fmaxf(aA0, h[(size_t)s0*64+lane]);
            aA1 = fmaxf(aA1, h[(size_t)s1*64+lane]);
            aB0 = fmaxf(aB0, h[(size_t)s2*64+lane]);
            aB1 = fmaxf(aB1, h[(size_t)s3*64+lane]);
            ca += 2; cb += 2;
        }
        while (ca+2 <= endA) {
            int s0=srcsL[ca], s1=srcsL[ca+1];
            aA0 = fmaxf(aA0, h[(size_t)s0*64+lane]);
            aA1 = fmaxf(aA1, h[(size_t)s1*64+lane]);
            ca += 2;
        }
        while (cb+2 <= endB) {
            int s2=srcsL[cb], s3=srcsL[cb+1];
            aB0 = fmaxf(aB0, h[(size_t)s2*64+lane]);
            aB1 = fmaxf(aB1, h[(size_t)s3*64+lane]);
            cb += 2;
        }
        if (ca < endA) aA0 = fmaxf(aA0, h[(size_t)srcsL[ca]*64+lane]);
        if (cb < endB) aB0 = fmaxf(aB0, h[(size_t)srcsL[cb]*64+lane]);
        float cvA = fmaxf(fmaxf(aA0,aA1), 0.f);
        float cvB = fmaxf(fmaxf(aB0,aB1), 0.f);
        c[(size_t)dA*64+lane] = cvA;
        c[(size_t)dB*64+lane] = cvB;
        float d0A = cvA*wh0, d1A = cvA*wh1, d2A = cvA*wh2;
        float d0B = cvB*wh0, d1B = cvB*wh1, d2B = cvB*wh2;
#pragma unroll
        for (int o = 32; o; o >>= 1) {
            d0A += __shfl_xor(d0A,o); d1A += __shfl_xor(d1A,o); d2A += __shfl_xor(d2A,o);
            d0B += __shfl_xor(d0B,o); d1B += __shfl_xor(d1B,o); d2B += __shfl_xor(d2B,o);
        }
        d0A = tanhf(d0A+bh0); d1A = tanhf(d1A+bh1); d2A = tanhf(d2A+bh2);
        d0B = tanhf(d0B+bh0); d1B = tanhf(d1B+bh1); d2B = tanhf(d2B+bh2);
        float pA0 = pos[dA*3+0], pA1 = pos[dA*3+1], pA2 = pos[dA*3+2];
        float pB0 = pos[dB*3+0], pB1 = pos[dB*3+1], pB2 = pos[dB*3+2];
        float s0A=0.f, s1A=0.f, s0B=0.f, s1B=0.f;
        REPP(WFMA, wc, cvA, s0A, s1A)
        REPP(WFMA, wc, cvB, s0B, s1B)
        pa[(size_t)dA*64+lane] = s0A+s1A + pA0*w0 + pA1*w1 + pA2*w2;
        pa[(size_t)dB*64+lane] = s0B+s1B + pB0*w0 + pB1*w1 + pB2*w2;
        qa[(size_t)dA*64+lane] = (d0A-pA0)*w0 + (d1A-pA1)*w1 + (d2A-pA2)*w2 + bfl;
        qa[(size_t)dB*64+lane] = (d0B-pB0)*w0 + (d1B-pB1)*w1 + (d2B-pB2)*w2 + bfl;
    }
}

__global__ __launch_bounds__(256, 2) void k_gnn_post(
    const float* __restrict__ agg, const float* __restrict__ Wg,
    const float* __restrict__ bg, const float* __restrict__ xres,
    float* __restrict__ out, int n)
{
    int lane = threadIdx.x & 63;
    int wid  = blockIdx.x * (blockDim.x >> 6) + (threadIdx.x >> 6);
    int nw   = gridDim.x * (blockDim.x >> 6);
    REPD(WLOAD, wg, Wg)
    float bgl = bg[lane];
    for (int i0 = wid*2; i0 < n; i0 += nw*2) {
        int iA = __builtin_amdgcn_readfirstlane(i0);
        size_t oA = (size_t)iA*64 + lane, oB = oA + 64;
        float avA = agg[oA], avB = agg[oB];
        float s0A=0.f, s1A=0.f, s0B=0.f, s1B=0.f;
        REPP(WFMA, wg, avA, s0A, s1A)
        REPP(WFMA, wg, avB, s0B, s1B)
        out[oA] = fmaxf(s0A+s1A + bgl, 0.f) + xres[oA];
        out[oB] = fmaxf(s0B+s1B + bgl, 0.f) + xres[oB];
    }
}

__global__ __launch_bounds__(256, 1) void k_l2m_pre2(
    const float* __restrict__ c4, const int* __restrict__ lab,
    const float* __restrict__ rel, const float* __restrict__ pts,
    const float* __restrict__ Wm, const float* __restrict__ bm,
    const float* __restrict__ Wh, const float* __restrict__ bh,
    const float* __restrict__ Wf, const float* __restrict__ bf,
    float* __restrict__ x5, float* __restrict__ p, float* __restrict__ q, int n)
{
    int lane = threadIdx.x & 63;
    int wid  = blockIdx.x * (blockDim.x >> 6) + (threadIdx.x >> 6);
    int nw   = gridDim.x * (blockDim.x >> 6);
    REPD(WLOAD, wm, Wm)
    REPD(WLOAD, wf, Wf + 3*64)
    float wm64 = Wm[64*64+lane], wm65 = Wm[65*64+lane], wm66 = Wm[66*64+lane];
    float w0 = Wf[0*64+lane], w1 = Wf[1*64+lane], w2 = Wf[2*64+lane];
    float bml = bm[lane], bfl = bf[lane];
    float wh0 = Wh[lane*3+0], wh1 = Wh[lane*3+1], wh2 = Wh[lane*3+2];
    float bh0 = bh[0], bh1 = bh[1], bh2 = bh[2];
    for (int i0 = wid*2; i0 < n; i0 += nw*2) {
        int iA = __builtin_amdgcn_readfirstlane(i0);
        int iB = iA + 1;
        int lA = lab[iA], lB = lab[iB];
        float cvA = c4[(size_t)lA*64 + lane];
        float cvB = c4[(size_t)lB*64 + lane];
        float s0A=0.f, s1A=0.f, s0B=0.f, s1B=0.f;
        REPP(WFMA, wm, cvA, s0A, s1A)
        REPP(WFMA, wm, cvB, s0B, s1B)
        float hA = s0A+s1A + bml + rel[iA*3+0]*wm64 + rel[iA*3+1]*wm65 + rel[iA*3+2]*wm66;
        float hB = s0B+s1B + bml + rel[iB*3+0]*wm64 + rel[iB*3+1]*wm65 + rel[iB*3+2]*wm66;
        float xvA = fmaxf(hA, 0.f), xvB = fmaxf(hB, 0.f);
        size_t oA = (size_t)iA*64 + lane, oB = oA + 64;
        x5[oA] = xvA; x5[oB] = xvB;
        float d0A = xvA*wh0, d1A = xvA*wh1, d2A = xvA*wh2;
        float d0B = xvB*wh0, d1B = xvB*wh1, d2B = xvB*wh2;
#pragma unroll
        for (int o = 32; o; o >>= 1) {
            d0A += __shfl_xor(d0A,o); d1A += __shfl_xor(d1A,o); d2A += __shfl_xor(d2A,o);
            d0B += __shfl_xor(d0B,o); d1B += __shfl_xor(d1B,o); d2B += __shfl_xor(d2B,o);
        }
        d0A = tanhf(d0A+bh0); d1A = tanhf(d1A+bh1); d2A = tanhf(d2A+bh2);
        d0B = tanhf(d0B+bh0); d1B = tanhf(d1B+bh1); d2B = tanhf(d2B+bh2);
        float pA0 = pts[iA*3+0], pA1 = pts[iA*3+1], pA2 = pts[iA*3+2];
        float pB0 = pts[iB*3+0], pB1 = pts[iB*3+1], pB2 = pts[iB*3+2];
        float t0A=0.f, t1A=0.f, t0B=0.f, t1B=0.f;
        REPP(WFMA, wf, xvA, t0A, t1A)
        REPP(WFMA, wf, xvB, t0B, t1B)
        p[oA] = t0A+t1A + pA0*w0 + pA1*w1 + pA2*w2;
        p[oB] = t0B+t1B + pB0*w0 + pB1*w1 + pB2*w2;
        q[oA] = (d0A-pA0)*w0 + (d1A-pA1)*w1 + (d2A-pA2)*w2 + bfl;
        q[oB] = (d0B-pB0)*w0 + (d1B-pB1)*w1 + (d2B-pB2)*w2 + bfl;
    }
}

__global__ __launch_bounds__(256, 1) void k_gnn_post_final(
    const float* __restrict__ agg, const float* __restrict__ Wg,
    const float* __restrict__ bg,
    const float* __restrict__ x5, const float* __restrict__ x2,
    const float* __restrict__ W1, const float* __restrict__ b1,
    const float* __restrict__ W2, const float* __restrict__ b2,
    float* __restrict__ out, int n)
{
    int lane = threadIdx.x & 63;
    int wid  = blockIdx.x * (blockDim.x >> 6) + (threadIdx.x >> 6);
    int nw   = gridDim.x * (blockDim.x >> 6);
    REPD(WLOAD, wg, Wg)
    REPD(WLOAD, w1c, W1)
    float w2c0 = W2[lane*4+0], w2c1 = W2[lane*4+1], w2c2 = W2[lane*4+2], w2c3 = W2[lane*4+3];
    float bgl = bg[lane], b1l = b1[lane];
    float b20 = b2[0], b21 = b2[1], b22 = b2[2], b23 = b2[3];
    for (int i0 = wid*2; i0 < n; i0 += nw*2) {
        int iA = __builtin_amdgcn_readfirstlane(i0);
        int iB = iA + 1;
        size_t oA = (size_t)iA*64 + lane, oB = oA + 64;
        float avA = agg[oA], avB = agg[oB];
        float s0A=0.f, s1A=0.f, s0B=0.f, s1B=0.f;
        REPP(WFMA, wg, avA, s0A, s1A)
        REPP(WFMA, wg, avB, s0B, s1B)
        float finA = fmaxf(s0A+s1A + bgl, 0.f) + x5[oA] + x2[oA];
        float finB = fmaxf(s0B+s1B + bgl, 0.f) + x5[oB] + x2[oB];
        float t0A=0.f, t1A=0.f, t0B=0.f, t1B=0.f;
        REPP(WFMA, w1c, finA, t0A, t1A)
        REPP(WFMA, w1c, finB, t0B, t1B)
        float tA = fmaxf(t0A+t1A + b1l, 0.f);
        float tB = fmaxf(t0B+t1B + b1l, 0.f);
        float o0A = wredsum(tA * w2c0), o1A = wredsum(tA * w2c1);
        float o2A = wredsum(tA * w2c2), o3A = wredsum(tA * w2c3);
        float o0B = wredsum(tB * w2c0), o1B = wredsum(tB * w2c1);
        float o2B = wredsum(tB * w2c2), o3B = wredsum(tB * w2c3);
        if (lane == 0) {
            *(float4*)(out + (size_t)iA*4) = make_float4(o0A+b20, o1A+b21, o2A+b22, o3A+b23);
            *(float4*)(out + (size_t)iB*4) = make_float4(o0B+b20, o1B+b21, o2B+b22, o3B+b23);
        }
    }
}

// ---------------- launch ----------------

extern "C" void kernel_launch(void* const* d_in, const int* in_sizes, int n_in,
                              void* d_out, int out_size, void* d_ws, size_t ws_size,
                              hipStream_t stream)
{
    const int N = 100000, M = 10000, E0 = 1600000, E1 = 320000;
    const int NB0 = (N + 255) / 256;
    const int NB1 = (M + 255) / 256;
    const int NBL = (M + 255) / 256;

    const float* feat = (const float*)d_in[0];
    const float* pts  = (const float*)d_in[1];
    const float* ctr  = (const float*)d_in[2];
    const int*   lab  = (const int*)d_in[3];
    const int2*  e0   = (const int2*)d_in[4];
    const int2*  e1   = (const int2*)d_in[5];
    const float* feW  = (const float*)d_in[6];
    const float* feb  = (const float*)d_in[7];
    const float* Wh   = (const float*)d_in[8];
    const float* bh   = (const float*)d_in[9];
    const float* Wf   = (const float*)d_in[10];
    const float* bf   = (const float*)d_in[11];
    const float* Wg   = (const float*)d_in[12];
    const float* bg   = (const float*)d_in[13];
    const float* m2lW = (const float*)d_in[14];
    const float* m2lb = (const float*)d_in[15];
    const float* l2mW = (const float*)d_in[16];
    const float* l2mb = (const float*)d_in[17];
    const float* cW1  = (const float*)d_in[18];
    const float* cb1  = (const float*)d_in[19];
    const float* cW2  = (const float*)d_in[20];
    const float* cb2  = (const float*)d_in[21];
    float* out = (float*)d_out;

    char* ws = (char*)d_ws;
    size_t off = 0;
    auto alloc = [&](size_t bytes) -> char* {
        char* r = ws + off; off += (bytes + 255) & ~(size_t)255; return r;
    };
    float* rel   = (float*)alloc((size_t)N*3*4);
    float* x1    = (float*)alloc((size_t)N*64*4);
    float* x2    = (float*)alloc((size_t)N*64*4);   // hosts ebufs pre-compute
    float* p     = (float*)alloc((size_t)N*64*4);
    float* q     = (float*)alloc((size_t)N*64*4);
    float* c     = (float*)alloc((size_t)M*64*4);
    float* c4    = (float*)alloc((size_t)M*64*4);
    int* rs0     = (int*)alloc((size_t)(N+2)*4);
    int* srcs0   = (int*)alloc((size_t)E0*4);
    int* rs1     = (int*)alloc((size_t)(M+2)*4);
    int* srcs1   = (int*)alloc((size_t)E1*4);
    int* rsL     = (int*)alloc((size_t)(M+2)*4);
    int* srcsL   = (int*)alloc((size_t)N*4);
    int* cnt0    = (int*)alloc((size_t)NB0*4);
    int* cnt1    = (int*)alloc((size_t)NB1*4);
    int* cntL    = (int*)alloc((size_t)NBL*4);
    int* base0   = (int*)alloc((size_t)(NB0+1)*4);
    int* base1   = (int*)alloc((size_t)(NB1+1)*4);
    int* baseL   = (int*)alloc((size_t)(NBL+1)*4);
    int* cur0    = (int*)alloc((size_t)NB0*4);
    int* cur1    = (int*)alloc((size_t)NB1*4);
    int* curL    = (int*)alloc((size_t)NBL*4);
    unsigned short* pWg0 = (unsigned short*)alloc(8192*2);   // packed Wg layer0
    unsigned short* pWm  = (unsigned short*)alloc(8192*2);   // packed m2lW rows 0..63
    (void)ws_size; (void)in_sizes; (void)n_in; (void)out_size;

    int2* ebuf0 = (int2*)x2;
    int2* ebuf1 = ebuf0 + E0;
    int2* ebufL = ebuf1 + E1;

    dim3 blk(256);
    const int gridN = 2048, gridM = 640, gSeg = 3072;
    const int NT = N / 16;                 // 6250 row-tiles
    const int gG = (NT + 3) / 4;           // 4 waves per block

    // ---- weight prepack (independent) ----
    k_packB<<<1, blk, 0, stream>>>(Wg + 0*64*64, pWg0);
    k_packB<<<1, blk, 0, stream>>>(m2lW, pWm);

    // ---- CSR builds ----
    hipMemsetAsync(cnt0, 0, (size_t)NB0*4, stream);
    hipMemsetAsync(cnt1, 0, (size_t)NB1*4, stream);
    hipMemsetAsync(cntL, 0, (size_t)NBL*4, stream);
    k_bhist_e<<<1024, blk, 0, stream>>>(e0, cnt0, E0, NB0);
    k_bhist_e<<<512,  blk, 0, stream>>>(e1, cnt1, E1, NB1);
    k_bhist_l<<<512,  blk, 0, stream>>>(lab, cntL, N, NBL);
    k_bscan3<<<3, 512, 0, stream>>>(cnt0, base0, cur0, NB0, E0,
                                    cnt1, base1, cur1, NB1, E1,
                                    cntL, baseL, curL, NBL, N);
    k_bucket_e<<<(E0 + BKT*EPT - 1)/(BKT*EPT), BKT, 0, stream>>>(e0, cur0, ebuf0, E0, NB0);
    k_bucket_e<<<(E1 + BKT*EPT - 1)/(BKT*EPT), BKT, 0, stream>>>(e1, cur1, ebuf1, E1, NB1);
    k_bucket_l<<<(N  + BKT*EPT - 1)/(BKT*EPT), BKT, 0, stream>>>(lab, curL, ebufL, N, NBL);
    k_final<<<NB0, 512, 0, stream>>>(ebuf0, base0, rs0, srcs0, N, E0, NB0);
    k_final<<<NB1, 512, 0, stream>>>(ebuf1, base1, rs1, srcs1, M, E1, NB1);
    k_final<<<NBL, 512, 0, stream>>>(ebufL, baseL, rsL, srcsL, M, N, NBL);

    // ---- layer 0 ----
    k_feat_pre0<<<gridN, blk, 0, stream>>>(feat, pts, ctr, lab, feW, feb,
                                           Wh+0*64*3, bh+0*3, Wf+0*67*64, bf+0*64,
                                           rel, x1, p, q, N);
    k_seg_max_gnn<<<gSeg, blk, 0, stream>>>(rs0, srcs0, p, q, N);
    // x2 = relu(agg@Wg0 + bg0) + x1        (MFMA split-bf16)
    k_gemm<0><<<gG, blk, 0, stream>>>(q, pWg0, bg+0*64, x1, nullptr, nullptr, x2, NT);
    // h = relu(x2@Wm + rel.Wm[64:67] + bm)  (MFMA split-bf16), h -> p
    k_gemm<1><<<gG, blk, 0, stream>>>(x2, pWm, m2lb, nullptr, rel, m2lW, p, NT);

    // ---- layer 1 (clusters) ----
    float* p1 = q;
    float* q1 = q + (size_t)M*64;
    k_seglab_pre1<<<gridM, blk, 0, stream>>>(rsL, srcsL, p, ctr,
                                             Wh+1*64*3, bh+1*3, Wf+1*67*64, bf+1*64,
                                             c, p1, q1, M);
    k_seg_max_gnn<<<640, blk, 0, stream>>>(rs1, srcs1, p1, q1, M);
    k_gnn_post<<<gridM, blk, 0, stream>>>(q1, Wg+1*64*64, bg+1*64, c, c4, M);

    // ---- l2m + layer 2 + classifier ----
    k_l2m_pre2<<<gridN, blk, 0, stream>>>(c4, lab, rel, pts, l2mW, l2mb,
                                          Wh+2*64*3, bh+2*3, Wf+2*67*64, bf+2*64,
                                          x1, p, q, N);
    k_seg_max_gnn<<<gSeg, blk, 0, stream>>>(rs0, srcs0, p, q, N);
    k_gnn_post_final<<<gridN, blk, 0, stream>>>(q, Wg+2*64*64, bg+2*64, x1, x2,
                                                cW1, cb1, cW2, cb2, out, N);
}

// Round 10
// 470.270 us; speedup vs baseline: 1.2695x; 1.1111x over previous
//
#include <hip/hip_runtime.h>

// ---------------- helpers ----------------

__device__ __forceinline__ float wredsum(float v) {
#pragma unroll
    for (int o = 32; o; o >>= 1) v += __shfl_xor(v, o);
    return v;
}

__device__ __forceinline__ float bcast(float v, int l) {
    return __int_as_float(__builtin_amdgcn_readlane(__float_as_int(v), l));
}

// 64 NAMED weight scalars per matrix (remaining VALU matvec kernels, M-sized)
#define REPD(M,P,B) \
 M(0,P,B)  M(1,P,B)  M(2,P,B)  M(3,P,B)  M(4,P,B)  M(5,P,B)  M(6,P,B)  M(7,P,B) \
 M(8,P,B)  M(9,P,B)  M(10,P,B) M(11,P,B) M(12,P,B) M(13,P,B) M(14,P,B) M(15,P,B) \
 M(16,P,B) M(17,P,B) M(18,P,B) M(19,P,B) M(20,P,B) M(21,P,B) M(22,P,B) M(23,P,B) \
 M(24,P,B) M(25,P,B) M(26,P,B) M(27,P,B) M(28,P,B) M(29,P,B) M(30,P,B) M(31,P,B) \
 M(32,P,B) M(33,P,B) M(34,P,B) M(35,P,B) M(36,P,B) M(37,P,B) M(38,P,B) M(39,P,B) \
 M(40,P,B) M(41,P,B) M(42,P,B) M(43,P,B) M(44,P,B) M(45,P,B) M(46,P,B) M(47,P,B) \
 M(48,P,B) M(49,P,B) M(50,P,B) M(51,P,B) M(52,P,B) M(53,P,B) M(54,P,B) M(55,P,B) \
 M(56,P,B) M(57,P,B) M(58,P,B) M(59,P,B) M(60,P,B) M(61,P,B) M(62,P,B) M(63,P,B)

#define WLOAD(J,P,B) float P##J = (B)[(J)*64+lane];

#define REPP(M,P,X,S0,S1) \
 M(0,1,P,X,S0,S1)  M(2,3,P,X,S0,S1)  M(4,5,P,X,S0,S1)  M(6,7,P,X,S0,S1) \
 M(8,9,P,X,S0,S1)  M(10,11,P,X,S0,S1) M(12,13,P,X,S0,S1) M(14,15,P,X,S0,S1) \
 M(16,17,P,X,S0,S1) M(18,19,P,X,S0,S1) M(20,21,P,X,S0,S1) M(22,23,P,X,S0,S1) \
 M(24,25,P,X,S0,S1) M(26,27,P,X,S0,S1) M(28,29,P,X,S0,S1) M(30,31,P,X,S0,S1) \
 M(32,33,P,X,S0,S1) M(34,35,P,X,S0,S1) M(36,37,P,X,S0,S1) M(38,39,P,X,S0,S1) \
 M(40,41,P,X,S0,S1) M(42,43,P,X,S0,S1) M(44,45,P,X,S0,S1) M(46,47,P,X,S0,S1) \
 M(48,49,P,X,S0,S1) M(50,51,P,X,S0,S1) M(52,53,P,X,S0,S1) M(54,55,P,X,S0,S1) \
 M(56,57,P,X,S0,S1) M(58,59,P,X,S0,S1) M(60,61,P,X,S0,S1) M(62,63,P,X,S0,S1)

#define WFMA(J,K,P,X,S0,S1) \
 S0 = fmaf(bcast(X,J), P##J, S0); \
 S1 = fmaf(bcast(X,K), P##K, S1);

// ---------------- MFMA split-bf16 machinery ----------------

typedef short bf16x8 __attribute__((ext_vector_type(8)));
typedef float f32x4  __attribute__((ext_vector_type(4)));

__device__ __forceinline__ unsigned short f2bf_rne(float x) {
    unsigned u = __float_as_uint(x);
    unsigned r = u + 0x7FFFu + ((u >> 16) & 1u);
    return (unsigned short)(r >> 16);
}

__device__ __forceinline__ void a_frag(const float* __restrict__ row, int kt, int g4,
                                       bf16x8& ah, bf16x8& al)
{
    const float4 a0 = *(const float4*)(row + kt*32 + g4);
    const float4 a1 = *(const float4*)(row + kt*32 + 16 + g4);
    float v0 = a0.x, v1 = a0.y, v2 = a0.z, v3 = a0.w;
    float v4 = a1.x, v5 = a1.y, v6 = a1.z, v7 = a1.w;
#define CVT1(idx, val) { \
    unsigned short hh = f2bf_rne(val); \
    float lf = (val) - __uint_as_float((unsigned)hh << 16); \
    ah[idx] = (short)hh; al[idx] = (short)f2bf_rne(lf); }
    CVT1(0,v0) CVT1(1,v1) CVT1(2,v2) CVT1(3,v3)
    CVT1(4,v4) CVT1(5,v5) CVT1(6,v6) CVT1(7,v7)
#undef CVT1
}

// Pack 7 64x64 fp32 W into B-fragment order (bf16 hi/lo), one block per matrix.
__global__ __launch_bounds__(256) void k_packB7(
    const float* W0, unsigned short* d0, const float* W1, unsigned short* d1,
    const float* W2, unsigned short* d2, const float* W3, unsigned short* d3,
    const float* W4, unsigned short* d4, const float* W5, unsigned short* d5,
    const float* W6, unsigned short* d6)
{
    const float* W; unsigned short* dst;
    switch (blockIdx.x) {
        case 0: W=W0; dst=d0; break;
        case 1: W=W1; dst=d1; break;
        case 2: W=W2; dst=d2; break;
        case 3: W=W3; dst=d3; break;
        case 4: W=W4; dst=d4; break;
        case 5: W=W5; dst=d5; break;
        default: W=W6; dst=d6; break;
    }
    int t = threadIdx.x;
    for (int slot = t; slot < 512; slot += 256) {
        int frag = slot >> 6;
        int lane = slot & 63;
        int kt = frag >> 2, nt = frag & 3;
        int g4 = (lane >> 4) * 4, n = nt*16 + (lane & 15);
        for (int j = 0; j < 8; ++j) {
            int k = kt*32 + (j>>2)*16 + g4 + (j&3);
            float x = W[k*64 + n];
            unsigned short hh = f2bf_rne(x);
            float lf = x - __uint_as_float((unsigned)hh << 16);
            dst[frag*1024 + 0*512 + lane*8 + j] = hh;
            dst[frag*1024 + 1*512 + lane*8 + j] = f2bf_rne(lf);
        }
    }
}

// Y = X[gathered rows]@W + epilogue.
//  EPI=0: out = relu(Y+bias) + res1
//  EPI=1: out = relu(Y+bias + vec3[r].Wtail)     (vec3 = rel; optional ridx gather)
//  EPI=2: out = Y + vec3[r].Wtail                (vec3 = pts; p computation)
//  EPI=3: out = relu(Y+bias) + res1 + res2       (fin; safe in-place)
//  EPI=4: out = relu(Y+bias)                     (classifier hidden)
template<int EPI>
__global__ __launch_bounds__(256) void k_gemm(
    const float* __restrict__ X, const unsigned short* __restrict__ pW,
    const float* __restrict__ bias, const float* __restrict__ res1,
    const float* __restrict__ res2, const float* __restrict__ vec3,
    const float* __restrict__ Wtail, const int* __restrict__ ridx,
    float* __restrict__ out, int ntiles)
{
    int lane = threadIdx.x & 63;
    int tile = blockIdx.x*4 + (threadIdx.x >> 6);
    if (tile >= ntiles) return;
    int r0 = tile * 16;
    int g4 = (lane >> 4) * 4;
    int rA = r0 + (lane & 15);
    int xrow = ridx ? ridx[rA] : rA;
    const float* rowp = X + (size_t)xrow * 64;
    bf16x8 ah0, al0, ah1, al1;
    a_frag(rowp, 0, g4, ah0, al0);
    a_frag(rowp, 1, g4, ah1, al1);
    f32x4 acc[4];
#pragma unroll
    for (int nt = 0; nt < 4; ++nt) {
        f32x4 a = {0.f, 0.f, 0.f, 0.f};
#pragma unroll
        for (int kt = 0; kt < 2; ++kt) {
            bf16x8 bh = *(const bf16x8*)(pW + (kt*4+nt)*1024 + lane*8);
            bf16x8 bl = *(const bf16x8*)(pW + (kt*4+nt)*1024 + 512 + lane*8);
            bf16x8 aH = kt ? ah1 : ah0;
            bf16x8 aL = kt ? al1 : al0;
            a = __builtin_amdgcn_mfma_f32_16x16x32_bf16(aH, bh, a, 0, 0, 0);
            a = __builtin_amdgcn_mfma_f32_16x16x32_bf16(aL, bh, a, 0, 0, 0);
            a = __builtin_amdgcn_mfma_f32_16x16x32_bf16(aH, bl, a, 0, 0, 0);
        }
        acc[nt] = a;
    }
    int rbase = r0 + (lane >> 4) * 4;
#pragma unroll
    for (int nt = 0; nt < 4; ++nt) {
        int c = nt*16 + (lane & 15);
        float bc = (EPI == 2) ? 0.f : bias[c];
        float w0t = 0.f, w1t = 0.f, w2t = 0.f;
        if (EPI == 1 || EPI == 2) {
            w0t = Wtail[0*64+c]; w1t = Wtail[1*64+c]; w2t = Wtail[2*64+c];
        }
#pragma unroll
        for (int reg = 0; reg < 4; ++reg) {
            int r = rbase + reg;
            float v = acc[nt][reg] + bc;
            if (EPI == 0) {
                v = fmaxf(v, 0.f) + res1[(size_t)r*64 + c];
            } else if (EPI == 1) {
                v += vec3[r*3+0]*w0t + vec3[r*3+1]*w1t + vec3[r*3+2]*w2t;
                v = fmaxf(v, 0.f);
            } else if (EPI == 2) {
                v += vec3[r*3+0]*w0t + vec3[r*3+1]*w1t + vec3[r*3+2]*w2t;
            } else if (EPI == 3) {
                v = fmaxf(v, 0.f) + res1[(size_t)r*64 + c] + res2[(size_t)r*64 + c];
            } else {
                v = fmaxf(v, 0.f);
            }
            out[(size_t)r*64 + c] = v;
        }
    }
}

// ================= bucketed CSR build =================

__global__ __launch_bounds__(256) void k_bhist_e(
    const int2* __restrict__ e, int* __restrict__ gcnt, int E, int nb)
{
    __shared__ int c[400];
    for (int i = threadIdx.x; i < nb; i += 256) c[i] = 0;
    __syncthreads();
    for (int idx = blockIdx.x*256 + threadIdx.x; idx < E; idx += gridDim.x*256)
        atomicAdd(&c[e[idx].y >> 8], 1);
    __syncthreads();
    for (int i = threadIdx.x; i < nb; i += 256) if (c[i]) atomicAdd(&gcnt[i], c[i]);
}

__global__ __launch_bounds__(256) void k_bhist_l(
    const int* __restrict__ lab, int* __restrict__ gcnt, int n, int nb)
{
    __shared__ int c[400];
    for (int i = threadIdx.x; i < nb; i += 256) c[i] = 0;
    __syncthreads();
    for (int idx = blockIdx.x*256 + threadIdx.x; idx < n; idx += gridDim.x*256)
        atomicAdd(&c[lab[idx] >> 8], 1);
    __syncthreads();
    for (int i = threadIdx.x; i < nb; i += 256) if (c[i]) atomicAdd(&gcnt[i], c[i]);
}

__global__ __launch_bounds__(512) void k_bscan3(
    const int* c0, int* b0, int* u0, int nb0, int t0,
    const int* c1, int* b1, int* u1, int nb1, int t1,
    const int* c2, int* b2, int* u2, int nb2, int t2)
{
    const int* cnt; int* base; int* cur; int nb; int tot;
    if (blockIdx.x == 0) { cnt=c0; base=b0; cur=u0; nb=nb0; tot=t0; }
    else if (blockIdx.x == 1) { cnt=c1; base=b1; cur=u1; nb=nb1; tot=t1; }
    else { cnt=c2; base=b2; cur=u2; nb=nb2; tot=t2; }
    __shared__ int sc[512];
    int t = threadIdx.x;
    int v = (t < nb) ? cnt[t] : 0;
    sc[t] = v; __syncthreads();
    for (int o = 1; o < 512; o <<= 1) {
        int a = (t >= o) ? sc[t-o] : 0;
        __syncthreads();
        sc[t] += a;
        __syncthreads();
    }
    if (t < nb) { int ex = sc[t] - v; base[t] = ex; cur[t] = ex; }
    if (t == nb) base[nb] = tot;
}

#define BKT 512
#define EPT 8
__global__ __launch_bounds__(BKT) void k_bucket_e(
    const int2* __restrict__ e, int* __restrict__ cur,
    int2* __restrict__ ebuf, int E, int nb)
{
    __shared__ int cnt[400];
    __shared__ int chunk[400];
    int t = threadIdx.x;
    int base = blockIdx.x * (BKT*EPT);
    for (int i = t; i < nb; i += BKT) cnt[i] = 0;
    __syncthreads();
    int2 ed[EPT]; int rk[EPT];
#pragma unroll
    for (int k = 0; k < EPT; ++k) {
        int idx = base + k*BKT + t;
        if (idx < E) { ed[k] = e[idx]; rk[k] = atomicAdd(&cnt[ed[k].y >> 8], 1); }
        else rk[k] = -1;
    }
    __syncthreads();
    for (int i = t; i < nb; i += BKT) { int c = cnt[i]; if (c) chunk[i] = atomicAdd(&cur[i], c); }
    __syncthreads();
#pragma unroll
    for (int k = 0; k < EPT; ++k)
        if (rk[k] >= 0) ebuf[chunk[ed[k].y >> 8] + rk[k]] = ed[k];
}

__global__ __launch_bounds__(BKT) void k_bucket_l(
    const int* __restrict__ lab, int* __restrict__ cur,
    int2* __restrict__ ebuf, int n, int nb)
{
    __shared__ int cnt[400];
    __shared__ int chunk[400];
    int t = threadIdx.x;
    int base = blockIdx.x * (BKT*EPT);
    for (int i = t; i < nb; i += BKT) cnt[i] = 0;
    __syncthreads();
    int2 ed[EPT]; int rk[EPT];
#pragma unroll
    for (int k = 0; k < EPT; ++k) {
        int idx = base + k*BKT + t;
        if (idx < n) { ed[k] = make_int2(idx, lab[idx]); rk[k] = atomicAdd(&cnt[ed[k].y >> 8], 1); }
        else rk[k] = -1;
    }
    __syncthreads();
    for (int i = t; i < nb; i += BKT) { int c = cnt[i]; if (c) chunk[i] = atomicAdd(&cur[i], c); }
    __syncthreads();
#pragma unroll
    for (int k = 0; k < EPT; ++k)
        if (rk[k] >= 0) ebuf[chunk[ed[k].y >> 8] + rk[k]] = ed[k];
}

__global__ __launch_bounds__(512) void k_final(
    const int2* __restrict__ ebuf, const int* __restrict__ base_,
    int* __restrict__ rs, int* __restrict__ srcs, int ndst, int etot, int nb)
{
    __shared__ int h[256];
    __shared__ int sc[256];
    int b = blockIdx.x, t = threadIdx.x;
    int base = base_[b];
    int cnt  = base_[b+1] - base;
    int d0 = b << 8;
    if (t < 256) h[t] = 0;
    __syncthreads();
    for (int i = t; i < cnt; i += 512) atomicAdd(&h[ebuf[base+i].y - d0], 1);
    __syncthreads();
    int v = (t < 256) ? h[t] : 0;
    if (t < 256) sc[t] = v;
    __syncthreads();
    for (int o = 1; o < 256; o <<= 1) {
        int a = (t < 256 && t >= o) ? sc[t-o] : 0;
        __syncthreads();
        if (t < 256) sc[t] += a;
        __syncthreads();
    }
    if (t < 256) {
        int gpos = base + sc[t] - v;
        if (d0 + t < ndst) rs[d0+t] = gpos;
        h[t] = gpos;
    }
    if (b == nb-1 && t == 0) rs[ndst] = etot;
    __syncthreads();
    for (int i = t; i < cnt; i += 512) {
        int2 ed = ebuf[base+i];
        int pos = atomicAdd(&h[ed.y - d0], 1);
        srcs[pos] = ed.x;
    }
}

// ================= VALU kernels =================

// rel, x1 = relu([feat, rel]@feW + feb), q = (tanh(x1@Wh+bh)-pts)@Wf[0:3]+bf
__global__ __launch_bounds__(256, 2) void k_feat_q(
    const float* __restrict__ feat, const float* __restrict__ pts,
    const float* __restrict__ ctr, const int* __restrict__ lab,
    const float* __restrict__ Wfe, const float* __restrict__ bfe,
    const float* __restrict__ Wh, const float* __restrict__ bh,
    const float* __restrict__ Wf, const float* __restrict__ bf,
    float* __restrict__ rel, float* __restrict__ x1, float* __restrict__ q, int n)
{
    int lane = threadIdx.x & 63;
    int wid  = blockIdx.x * (blockDim.x >> 6) + (threadIdx.x >> 6);
    int nw   = gridDim.x * (blockDim.x >> 6);
    float fe0 = Wfe[0*64+lane], fe1 = Wfe[1*64+lane], fe2 = Wfe[2*64+lane], fe3 = Wfe[3*64+lane];
    float fe4 = Wfe[4*64+lane], fe5 = Wfe[5*64+lane], fe6 = Wfe[6*64+lane];
    float bfe_l = bfe[lane];
    float w0 = Wf[0*64+lane], w1 = Wf[1*64+lane], w2 = Wf[2*64+lane];
    float bfl = bf[lane];
    float wh0 = Wh[lane*3+0], wh1 = Wh[lane*3+1], wh2 = Wh[lane*3+2];
    float bh0 = bh[0], bh1 = bh[1], bh2 = bh[2];
    for (int i0 = wid*2; i0 < n; i0 += nw*2) {
        int iA = __builtin_amdgcn_readfirstlane(i0);
        int iB = iA + 1;
        int lA = lab[iA], lB = lab[iB];
        float pA0 = pts[iA*3+0], pA1 = pts[iA*3+1], pA2 = pts[iA*3+2];
        float pB0 = pts[iB*3+0], pB1 = pts[iB*3+1], pB2 = pts[iB*3+2];
        float rA0 = pA0 - ctr[lA*3+0], rA1 = pA1 - ctr[lA*3+1], rA2 = pA2 - ctr[lA*3+2];
        float rB0 = pB0 - ctr[lB*3+0], rB1 = pB1 - ctr[lB*3+1], rB2 = pB2 - ctr[lB*3+2];
        if (lane == 0)      { rel[iA*3+0]=rA0; rel[iA*3+1]=rA1; rel[iA*3+2]=rA2; }
        else if (lane == 1) { rel[iB*3+0]=rB0; rel[iB*3+1]=rB1; rel[iB*3+2]=rB2; }
        float aA = bfe_l, aB = bfe_l;
        aA = fmaf(feat[iA*4+0], fe0, aA); aB = fmaf(feat[iB*4+0], fe0, aB);
        aA = fmaf(feat[iA*4+1], fe1, aA); aB = fmaf(feat[iB*4+1], fe1, aB);
        aA = fmaf(feat[iA*4+2], fe2, aA); aB = fmaf(feat[iB*4+2], fe2, aB);
        aA = fmaf(feat[iA*4+3], fe3, aA); aB = fmaf(feat[iB*4+3], fe3, aB);
        aA = fmaf(rA0, fe4, aA); aB = fmaf(rB0, fe4, aB);
        aA = fmaf(rA1, fe5, aA); aB = fmaf(rB1, fe5, aB);
        aA = fmaf(rA2, fe6, aA); aB = fmaf(rB2, fe6, aB);
        float xvA = fmaxf(aA, 0.f), xvB = fmaxf(aB, 0.f);
        x1[(size_t)iA*64+lane] = xvA;
        x1[(size_t)iB*64+lane] = xvB;
        float d0A = xvA*wh0, d1A = xvA*wh1, d2A = xvA*wh2;
        float d0B = xvB*wh0, d1B = xvB*wh1, d2B = xvB*wh2;
#pragma unroll
        for (int o = 32; o; o >>= 1) {
            d0A += __shfl_xor(d0A,o); d1A += __shfl_xor(d1A,o); d2A += __shfl_xor(d2A,o);
            d0B += __shfl_xor(d0B,o); d1B += __shfl_xor(d1B,o); d2B += __shfl_xor(d2B,o);
        }
        d0A = tanhf(d0A+bh0); d1A = tanhf(d1A+bh1); d2A = tanhf(d2A+bh2);
        d0B = tanhf(d0B+bh0); d1B = tanhf(d1B+bh1); d2B = tanhf(d2B+bh2);
        q[(size_t)iA*64+lane] = (d0A-pA0)*w0 + (d1A-pA1)*w1 + (d2A-pA2)*w2 + bfl;
        q[(size_t)iB*64+lane] = (d0B-pB0)*w0 + (d1B-pB1)*w1 + (d2B-pB2)*w2 + bfl;
    }
}

// q = (tanh(x@Wh+bh) - pos)@Wf[0:3] + bf     (delta-only, 2 nodes/wave)
__global__ __launch_bounds__(256, 2) void k_qdelta(
    const float* __restrict__ x, const float* __restrict__ pos,
    const float* __restrict__ Wh, const float* __restrict__ bh,
    const float* __restrict__ Wf, const float* __restrict__ bf,
    float* __restrict__ q, int n)
{
    int lane = threadIdx.x & 63;
    int wid  = blockIdx.x * (blockDim.x >> 6) + (threadIdx.x >> 6);
    int nw   = gridDim.x * (blockDim.x >> 6);
    float w0 = Wf[0*64+lane], w1 = Wf[1*64+lane], w2 = Wf[2*64+lane];
    float bfl = bf[lane];
    float wh0 = Wh[lane*3+0], wh1 = Wh[lane*3+1], wh2 = Wh[lane*3+2];
    float bh0 = bh[0], bh1 = bh[1], bh2 = bh[2];
    for (int i0 = wid*2; i0 < n; i0 += nw*2) {
        int iA = __builtin_amdgcn_readfirstlane(i0);
        int iB = iA + 1;
        float xvA = x[(size_t)iA*64+lane], xvB = x[(size_t)iB*64+lane];
        float d0A = xvA*wh0, d1A = xvA*wh1, d2A = xvA*wh2;
        float d0B = xvB*wh0, d1B = xvB*wh1, d2B = xvB*wh2;
#pragma unroll
        for (int o = 32; o; o >>= 1) {
            d0A += __shfl_xor(d0A,o); d1A += __shfl_xor(d1A,o); d2A += __shfl_xor(d2A,o);
            d0B += __shfl_xor(d0B,o); d1B += __shfl_xor(d1B,o); d2B += __shfl_xor(d2B,o);
        }
        d0A = tanhf(d0A+bh0); d1A = tanhf(d1A+bh1); d2A = tanhf(d2A+bh2);
        d0B = tanhf(d0B+bh0); d1B = tanhf(d1B+bh1); d2B = tanhf(d2B+bh2);
        float pA0 = pos[iA*3+0], pA1 = pos[iA*3+1], pA2 = pos[iA*3+2];
        float pB0 = pos[iB*3+0], pB1 = pos[iB*3+1], pB2 = pos[iB*3+2];
        q[(size_t)iA*64+lane] = (d0A-pA0)*w0 + (d1A-pA1)*w1 + (d2A-pA2)*w2 + bfl;
        q[(size_t)iB*64+lane] = (d0B-pB0)*w0 + (d1B-pB1)*w1 + (d2B-pB2)*w2 + bfl;
    }
}

// out = t@W2 + b2   (t >= 0, 4 outputs per node)
__global__ __launch_bounds__(256, 2) void k_cls_tail(
    const float* __restrict__ t_, const float* __restrict__ W2,
    const float* __restrict__ b2, float* __restrict__ out, int n)
{
    int lane = threadIdx.x & 63;
    int wid  = blockIdx.x * (blockDim.x >> 6) + (threadIdx.x >> 6);
    int nw   = gridDim.x * (blockDim.x >> 6);
    float w2c0 = W2[lane*4+0], w2c1 = W2[lane*4+1], w2c2 = W2[lane*4+2], w2c3 = W2[lane*4+3];
    float b20 = b2[0], b21 = b2[1], b22 = b2[2], b23 = b2[3];
    for (int i0 = wid*2; i0 < n; i0 += nw*2) {
        int iA = __builtin_amdgcn_readfirstlane(i0);
        int iB = iA + 1;
        float tA = t_[(size_t)iA*64+lane], tB = t_[(size_t)iB*64+lane];
        float o0A = wredsum(tA * w2c0), o1A = wredsum(tA * w2c1);
        float o2A = wredsum(tA * w2c2), o3A = wredsum(tA * w2c3);
        float o0B = wredsum(tB * w2c0), o1B = wredsum(tB * w2c1);
        float o2B = wredsum(tB * w2c2), o3B = wredsum(tB * w2c3);
        if (lane == 0) {
            *(float4*)(out + (size_t)iA*4) = make_float4(o0A+b20, o1A+b21, o2A+b22, o3A+b23);
            *(float4*)(out + (size_t)iB*4) = make_float4(o0B+b20, o1B+b21, o2B+b22, o3B+b23);
        }
    }
}

__global__ __launch_bounds__(256) void k_seg_max_gnn(
    const int* __restrict__ rs, const int* __restrict__ srcs,
    const float* __restrict__ p, float* __restrict__ q, int n)
{
    int lane = threadIdx.x & 63;
    int wid  = blockIdx.x * (blockDim.x >> 6) + (threadIdx.x >> 6);
    int nw   = gridDim.x * (blockDim.x >> 6);
    for (int d0 = wid*2; d0 < n; d0 += nw*2) {
        int dA = __builtin_amdgcn_readfirstlane(d0);
        int begA = rs[dA], endA = rs[dA+1], endB = rs[dA+2];
        int ca = begA, cb = endA;
        float aA0=-1e30f, aA1=-1e30f, aB0=-1e30f, aB1=-1e30f;
        while (ca+2 <= endA && cb+2 <= endB) {
            int s0=srcs[ca], s1=srcs[ca+1], s2=srcs[cb], s3=srcs[cb+1];
            aA0 = fmaxf(aA0, p[(size_t)s0*64+lane]);
            aA1 = fmaxf(aA1, p[(size_t)s1*64+lane]);
            aB0 = fmaxf(aB0, p[(size_t)s2*64+lane]);
            aB1 = fmaxf(aB1, p[(size_t)s3*64+lane]);
            ca += 2; cb += 2;
        }
        while (ca+2 <= endA) {
            int s0=srcs[ca], s1=srcs[ca+1];
            aA0 = fmaxf(aA0, p[(size_t)s0*64+lane]);
            aA1 = fmaxf(aA1, p[(size_t)s1*64+lane]);
            ca += 2;
        }
        while (cb+2 <= endB) {
            int s2=srcs[cb], s3=srcs[cb+1];
            aB0 = fmaxf(aB0, p[(size_t)s2*64+lane]);
            aB1 = fmaxf(aB1, p[(size_t)s3*64+lane]);
            cb += 2;
        }
        if (ca < endA) aA0 = fmaxf(aA0, p[(size_t)srcs[ca]*64+lane]);
        if (cb < endB) aB0 = fmaxf(aB0, p[(size_t)srcs[cb]*64+lane]);
        float accA = fmaxf(aA0, aA1), accB = fmaxf(aB0, aB1);
        size_t oA = (size_t)dA*64 + lane, oB = oA + 64;
        q[oA] = fmaxf(accA + q[oA], 0.f);
        q[oB] = fmaxf(accB + q[oB], 0.f);
    }
}

__global__ __launch_bounds__(256, 2) void k_seglab_pre1(
    const int* __restrict__ rsL, const int* __restrict__ srcsL,
    const float* __restrict__ h, const float* __restrict__ pos,
    const float* __restrict__ Wh, const float* __restrict__ bh,
    const float* __restrict__ Wf, const float* __restrict__ bf,
    float* __restrict__ c, float* __restrict__ pa, float* __restrict__ qa, int m)
{
    int lane = threadIdx.x & 63;
    int wid  = blockIdx.x * (blockDim.x >> 6) + (threadIdx.x >> 6);
    int nw   = gridDim.x * (blockDim.x >> 6);
    REPD(WLOAD, wc, Wf + 3*64)
    float w0 = Wf[0*64+lane], w1 = Wf[1*64+lane], w2 = Wf[2*64+lane];
    float bfl = bf[lane];
    float wh0 = Wh[lane*3+0], wh1 = Wh[lane*3+1], wh2 = Wh[lane*3+2];
    float bh0 = bh[0], bh1 = bh[1], bh2 = bh[2];
    for (int d0 = wid*2; d0 < m; d0 += nw*2) {
        int dA = __builtin_amdgcn_readfirstlane(d0);
        int dB = dA + 1;
        int begA = rsL[dA], endA = rsL[dA+1], endB = rsL[dA+2];
        int ca = begA, cb = endA;
        float aA0=-1e30f, aA1=-1e30f, aB0=-1e30f, aB1=-1e30f;
        while (ca+2 <= endA && cb+2 <= endB) {
            int s0=srcsL[ca], s1=srcsL[ca+1], s2=srcsL[cb], s3=srcsL[cb+1];
            aA0 = fmaxf(aA0, h[(size_t)s0*64+lane]);
            aA1 = fmaxf(aA1, h[(size_t)s1*64+lane]);
            aB0 = fmaxf(aB0, h[(size_t)s2*64+lane]);
            aB1 = fmaxf(aB1, h[(size_t)s3*64+lane]);
            ca += 2; cb += 2;
        }
        while (ca+2 <= endA) {
            int s0=srcsL[ca], s1=srcsL[ca+1];
            aA0 = fmaxf(aA0, h[(size_t)s0*64+lane]);
            aA1 = fmaxf(aA1, h[(size_t)s1*64+lane]);
            ca += 2;
        }
        while (cb+2 <= endB) {
            int s2=srcsL[cb], s3=srcsL[cb+1];
            aB0 = fmaxf(aB0, h[(size_t)s2*64+lane]);
            aB1 = fmaxf(aB1, h[(size_t)s3*64+lane]);
            cb += 2;
        }
        if (ca < endA) aA0 = fmaxf(aA0, h[(size_t)srcsL[ca]*64+lane]);
        if (cb < endB) aB0 = fmaxf(aB0, h[(size_t)srcsL[cb]*64+lane]);
        float cvA = fmaxf(fmaxf(aA0,aA1), 0.f);
        float cvB = fmaxf(fmaxf(aB0,aB1), 0.f);
        c[(size_t)dA*64+lane] = cvA;
        c[(size_t)dB*64+lane] = cvB;
        float d0A = cvA*wh0, d1A = cvA*wh1, d2A = cvA*wh2;
        float d0B = cvB*wh0, d1B = cvB*wh1, d2B = cvB*wh2;
#pragma unroll
        for (int o = 32; o; o >>= 1) {
            d0A += __shfl_xor(d0A,o); d1A += __shfl_xor(d1A,o); d2A += __shfl_xor(d2A,o);
            d0B += __shfl_xor(d0B,o); d1B += __shfl_xor(d1B,o); d2B += __shfl_xor(d2B,o);
        }
        d0A = tanhf(d0A+bh0); d1A = tanhf(d1A+bh1); d2A = tanhf(d2A+bh2);
        d0B = tanhf(d0B+bh0); d1B = tanhf(d1B+bh1); d2B = tanhf(d2B+bh2);
        float pA0 = pos[dA*3+0], pA1 = pos[dA*3+1], pA2 = pos[dA*3+2];
        float pB0 = pos[dB*3+0], pB1 = pos[dB*3+1], pB2 = pos[dB*3+2];
        float s0A=0.f, s1A=0.f, s0B=0.f, s1B=0.f;
        REPP(WFMA, wc, cvA, s0A, s1A)
        REPP(WFMA, wc, cvB, s0B, s1B)
        pa[(size_t)dA*64+lane] = s0A+s1A + pA0*w0 + pA1*w1 + pA2*w2;
        pa[(size_t)dB*64+lane] = s0B+s1B + pB0*w0 + pB1*w1 + pB2*w2;
        qa[(size_t)dA*64+lane] = (d0A-pA0)*w0 + (d1A-pA1)*w1 + (d2A-pA2)*w2 + bfl;
        qa[(size_t)dB*64+lane] = (d0B-pB0)*w0 + (d1B-pB1)*w1 + (d2B-pB2)*w2 + bfl;
    }
}

__global__ __launch_bounds__(256, 2) void k_gnn_post(
    const float* __restrict__ agg, const float* __restrict__ Wg,
    const float* __restrict__ bg, const float* __restrict__ xres,
    float* __restrict__ out, int n)
{
    int lane = threadIdx.x & 63;
    int wid  = blockIdx.x * (blockDim.x >> 6) + (threadIdx.x >> 6);
    int nw   = gridDim.x * (blockDim.x >> 6);
    REPD(WLOAD, wg, Wg)
    float bgl = bg[lane];
    for (int i0 = wid*2; i0 < n; i0 += nw*2) {
        int iA = __builtin_amdgcn_readfirstlane(i0);
        size_t oA = (size_t)iA*64 + lane, oB = oA + 64;
        float avA = agg[oA], avB = agg[oB];
        float s0A=0.f, s1A=0.f, s0B=0.f, s1B=0.f;
        REPP(WFMA, wg, avA, s0A, s1A)
        REPP(WFMA, wg, avB, s0B, s1B)
        out[oA] = fmaxf(s0A+s1A + bgl, 0.f) + xres[oA];
        out[oB] = fmaxf(s0B+s1B + bgl, 0.f) + xres[oB];
    }
}

// ---------------- launch ----------------

extern "C" void kernel_launch(void* const* d_in, const int* in_sizes, int n_in,
                              void* d_out, int out_size, void* d_ws, size_t ws_size,
                              hipStream_t stream)
{
    const int N = 100000, M = 10000, E0 = 1600000, E1 = 320000;
    const int NB0 = (N + 255) / 256;
    const int NB1 = (M + 255) / 256;
    const int NBL = (M + 255) / 256;

    const float* feat = (const float*)d_in[0];
    const float* pts  = (const float*)d_in[1];
    const float* ctr  = (const float*)d_in[2];
    const int*   lab  = (const int*)d_in[3];
    const int2*  e0   = (const int2*)d_in[4];
    const int2*  e1   = (const int2*)d_in[5];
    const float* feW  = (const float*)d_in[6];
    const float* feb  = (const float*)d_in[7];
    const float* Wh   = (const float*)d_in[8];
    const float* bh   = (const float*)d_in[9];
    const float* Wf   = (const float*)d_in[10];
    const float* bf   = (const float*)d_in[11];
    const float* Wg   = (const float*)d_in[12];
    const float* bg   = (const float*)d_in[13];
    const float* m2lW = (const float*)d_in[14];
    const float* m2lb = (const float*)d_in[15];
    const float* l2mW = (const float*)d_in[16];
    const float* l2mb = (const float*)d_in[17];
    const float* cW1  = (const float*)d_in[18];
    const float* cb1  = (const float*)d_in[19];
    const float* cW2  = (const float*)d_in[20];
    const float* cb2  = (const float*)d_in[21];
    float* out = (float*)d_out;

    char* ws = (char*)d_ws;
    size_t off = 0;
    auto alloc = [&](size_t bytes) -> char* {
        char* r = ws + off; off += (bytes + 255) & ~(size_t)255; return r;
    };
    float* rel   = (float*)alloc((size_t)N*3*4);
    float* x1    = (float*)alloc((size_t)N*64*4);   // x1, later x5
    float* x2    = (float*)alloc((size_t)N*64*4);   // hosts ebufs pre-compute
    float* p     = (float*)alloc((size_t)N*64*4);   // p0/h/p2/t
    float* q     = (float*)alloc((size_t)N*64*4);   // q/agg/fin
    float* c     = (float*)alloc((size_t)M*64*4);
    float* c4    = (float*)alloc((size_t)M*64*4);
    int* rs0     = (int*)alloc((size_t)(N+2)*4);
    int* srcs0   = (int*)alloc((size_t)E0*4);
    int* rs1     = (int*)alloc((size_t)(M+2)*4);
    int* srcs1   = (int*)alloc((size_t)E1*4);
    int* rsL     = (int*)alloc((size_t)(M+2)*4);
    int* srcsL   = (int*)alloc((size_t)N*4);
    int* cnt0    = (int*)alloc((size_t)NB0*4);
    int* cnt1    = (int*)alloc((size_t)NB1*4);
    int* cntL    = (int*)alloc((size_t)NBL*4);
    int* base0   = (int*)alloc((size_t)(NB0+1)*4);
    int* base1   = (int*)alloc((size_t)(NB1+1)*4);
    int* baseL   = (int*)alloc((size_t)(NBL+1)*4);
    int* cur0    = (int*)alloc((size_t)NB0*4);
    int* cur1    = (int*)alloc((size_t)NB1*4);
    int* curL    = (int*)alloc((size_t)NBL*4);
    unsigned short* pWf0  = (unsigned short*)alloc(8192*2);
    unsigned short* pWg0  = (unsigned short*)alloc(8192*2);
    unsigned short* pWm   = (unsigned short*)alloc(8192*2);
    unsigned short* pWl2m = (unsigned short*)alloc(8192*2);
    unsigned short* pWf2  = (unsigned short*)alloc(8192*2);
    unsigned short* pWg2  = (unsigned short*)alloc(8192*2);
    unsigned short* pW1   = (unsigned short*)alloc(8192*2);
    (void)ws_size; (void)in_sizes; (void)n_in; (void)out_size;

    int2* ebuf0 = (int2*)x2;
    int2* ebuf1 = ebuf0 + E0;
    int2* ebufL = ebuf1 + E1;

    dim3 blk(256);
    const int gridN = 2048, gridM = 640, gSeg = 3072;
    const int NT = N / 16;
    const int gG = (NT + 3) / 4;

    // ---- weight prepack ----
    k_packB7<<<7, blk, 0, stream>>>(
        Wf + 0*67*64 + 3*64, pWf0,
        Wg + 0*64*64,        pWg0,
        m2lW,                pWm,
        l2mW,                pWl2m,
        Wf + 2*67*64 + 3*64, pWf2,
        Wg + 2*64*64,        pWg2,
        cW1,                 pW1);

    // ---- CSR builds ----
    hipMemsetAsync(cnt0, 0, (size_t)NB0*4, stream);
    hipMemsetAsync(cnt1, 0, (size_t)NB1*4, stream);
    hipMemsetAsync(cntL, 0, (size_t)NBL*4, stream);
    k_bhist_e<<<1024, blk, 0, stream>>>(e0, cnt0, E0, NB0);
    k_bhist_e<<<512,  blk, 0, stream>>>(e1, cnt1, E1, NB1);
    k_bhist_l<<<512,  blk, 0, stream>>>(lab, cntL, N, NBL);
    k_bscan3<<<3, 512, 0, stream>>>(cnt0, base0, cur0, NB0, E0,
                                    cnt1, base1, cur1, NB1, E1,
                                    cntL, baseL, curL, NBL, N);
    k_bucket_e<<<(E0 + BKT*EPT - 1)/(BKT*EPT), BKT, 0, stream>>>(e0, cur0, ebuf0, E0, NB0);
    k_bucket_e<<<(E1 + BKT*EPT - 1)/(BKT*EPT), BKT, 0, stream>>>(e1, cur1, ebuf1, E1, NB1);
    k_bucket_l<<<(N  + BKT*EPT - 1)/(BKT*EPT), BKT, 0, stream>>>(lab, curL, ebufL, N, NBL);
    k_final<<<NB0, 512, 0, stream>>>(ebuf0, base0, rs0, srcs0, N, E0, NB0);
    k_final<<<NB1, 512, 0, stream>>>(ebuf1, base1, rs1, srcs1, M, E1, NB1);
    k_final<<<NBL, 512, 0, stream>>>(ebufL, baseL, rsL, srcsL, M, N, NBL);

    // ---- layer 0 ----
    k_feat_q<<<gridN, blk, 0, stream>>>(feat, pts, ctr, lab, feW, feb,
                                        Wh+0*64*3, bh+0*3, Wf+0*67*64, bf+0*64,
                                        rel, x1, q, N);
    k_gemm<2><<<gG, blk, 0, stream>>>(x1, pWf0, nullptr, nullptr, nullptr,
                                      pts, Wf+0*67*64, nullptr, p, NT);
    k_seg_max_gnn<<<gSeg, blk, 0, stream>>>(rs0, srcs0, p, q, N);
    k_gemm<0><<<gG, blk, 0, stream>>>(q, pWg0, bg+0*64, x1, nullptr,
                                      nullptr, nullptr, nullptr, x2, NT);
    k_gemm<1><<<gG, blk, 0, stream>>>(x2, pWm, m2lb, nullptr, nullptr,
                                      rel, m2lW+64*64, nullptr, p, NT);

    // ---- layer 1 (clusters, VALU) ----
    float* p1 = q;
    float* q1 = q + (size_t)M*64;
    k_seglab_pre1<<<gridM, blk, 0, stream>>>(rsL, srcsL, p, ctr,
                                             Wh+1*64*3, bh+1*3, Wf+1*67*64, bf+1*64,
                                             c, p1, q1, M);
    k_seg_max_gnn<<<640, blk, 0, stream>>>(rs1, srcs1, p1, q1, M);
    k_gnn_post<<<gridM, blk, 0, stream>>>(q1, Wg+1*64*64, bg+1*64, c, c4, M);

    // ---- l2m + layer 2 + classifier ----
    k_gemm<1><<<gG, blk, 0, stream>>>(c4, pWl2m, l2mb, nullptr, nullptr,
                                      rel, l2mW+64*64, lab, x1, NT);       // x5 -> x1
    k_qdelta<<<gridN, blk, 0, stream>>>(x1, pts, Wh+2*64*3, bh+2*3,
                                        Wf+2*67*64, bf+2*64, q, N);
    k_gemm<2><<<gG, blk, 0, stream>>>(x1, pWf2, nullptr, nullptr, nullptr,
                                      pts, Wf+2*67*64, nullptr, p, NT);
    k_seg_max_gnn<<<gSeg, blk, 0, stream>>>(rs0, srcs0, p, q, N);
    k_gemm<3><<<gG, blk, 0, stream>>>(q, pWg2, bg+2*64, x1, x2,
                                      nullptr, nullptr, nullptr, q, NT);   // fin in-place
    k_gemm<4><<<gG, blk, 0, stream>>>(q, pW1, cb1, nullptr, nullptr,
                                      nullptr, nullptr, nullptr, p, NT);   // t
    k_cls_tail<<<gridN, blk, 0, stream>>>(p, cW2, cb2, out, N);
}

// Round 11
// 413.302 us; speedup vs baseline: 1.4445x; 1.1378x over previous
//
#include <hip/hip_runtime.h>

// ---------------- helpers ----------------

__device__ __forceinline__ float wredsum(float v) {
#pragma unroll
    for (int o = 32; o; o >>= 1) v += __shfl_xor(v, o);
    return v;
}

__device__ __forceinline__ float bcast(float v, int l) {
    return __int_as_float(__builtin_amdgcn_readlane(__float_as_int(v), l));
}

// 64 NAMED weight scalars (M-sized VALU kernels)
#define REPD(M,P,B) \
 M(0,P,B)  M(1,P,B)  M(2,P,B)  M(3,P,B)  M(4,P,B)  M(5,P,B)  M(6,P,B)  M(7,P,B) \
 M(8,P,B)  M(9,P,B)  M(10,P,B) M(11,P,B) M(12,P,B) M(13,P,B) M(14,P,B) M(15,P,B) \
 M(16,P,B) M(17,P,B) M(18,P,B) M(19,P,B) M(20,P,B) M(21,P,B) M(22,P,B) M(23,P,B) \
 M(24,P,B) M(25,P,B) M(26,P,B) M(27,P,B) M(28,P,B) M(29,P,B) M(30,P,B) M(31,P,B) \
 M(32,P,B) M(33,P,B) M(34,P,B) M(35,P,B) M(36,P,B) M(37,P,B) M(38,P,B) M(39,P,B) \
 M(40,P,B) M(41,P,B) M(42,P,B) M(43,P,B) M(44,P,B) M(45,P,B) M(46,P,B) M(47,P,B) \
 M(48,P,B) M(49,P,B) M(50,P,B) M(51,P,B) M(52,P,B) M(53,P,B) M(54,P,B) M(55,P,B) \
 M(56,P,B) M(57,P,B) M(58,P,B) M(59,P,B) M(60,P,B) M(61,P,B) M(62,P,B) M(63,P,B)

#define WLOAD(J,P,B) float P##J = (B)[(J)*64+lane];

#define REPP(M,P,X,S0,S1) \
 M(0,1,P,X,S0,S1)  M(2,3,P,X,S0,S1)  M(4,5,P,X,S0,S1)  M(6,7,P,X,S0,S1) \
 M(8,9,P,X,S0,S1)  M(10,11,P,X,S0,S1) M(12,13,P,X,S0,S1) M(14,15,P,X,S0,S1) \
 M(16,17,P,X,S0,S1) M(18,19,P,X,S0,S1) M(20,21,P,X,S0,S1) M(22,23,P,X,S0,S1) \
 M(24,25,P,X,S0,S1) M(26,27,P,X,S0,S1) M(28,29,P,X,S0,S1) M(30,31,P,X,S0,S1) \
 M(32,33,P,X,S0,S1) M(34,35,P,X,S0,S1) M(36,37,P,X,S0,S1) M(38,39,P,X,S0,S1) \
 M(40,41,P,X,S0,S1) M(42,43,P,X,S0,S1) M(44,45,P,X,S0,S1) M(46,47,P,X,S0,S1) \
 M(48,49,P,X,S0,S1) M(50,51,P,X,S0,S1) M(52,53,P,X,S0,S1) M(54,55,P,X,S0,S1) \
 M(56,57,P,X,S0,S1) M(58,59,P,X,S0,S1) M(60,61,P,X,S0,S1) M(62,63,P,X,S0,S1)

#define WFMA(J,K,P,X,S0,S1) \
 S0 = fmaf(bcast(X,J), P##J, S0); \
 S1 = fmaf(bcast(X,K), P##K, S1);

// ---------------- MFMA split-bf16 machinery ----------------

typedef short bf16x8 __attribute__((ext_vector_type(8)));
typedef float f32x4  __attribute__((ext_vector_type(4)));

__device__ __forceinline__ unsigned short f2bf_rne(float x) {
    unsigned u = __float_as_uint(x);
    unsigned r = u + 0x7FFFu + ((u >> 16) & 1u);
    return (unsigned short)(r >> 16);
}

__device__ __forceinline__ void a_frag(const float* __restrict__ row, int kt, int g4,
                                       bf16x8& ah, bf16x8& al)
{
    const float4 a0 = *(const float4*)(row + kt*32 + g4);
    const float4 a1 = *(const float4*)(row + kt*32 + 16 + g4);
    float v0 = a0.x, v1 = a0.y, v2 = a0.z, v3 = a0.w;
    float v4 = a1.x, v5 = a1.y, v6 = a1.z, v7 = a1.w;
#define CVT1(idx, val) { \
    unsigned short hh = f2bf_rne(val); \
    float lf = (val) - __uint_as_float((unsigned)hh << 16); \
    ah[idx] = (short)hh; al[idx] = (short)f2bf_rne(lf); }
    CVT1(0,v0) CVT1(1,v1) CVT1(2,v2) CVT1(3,v3)
    CVT1(4,v4) CVT1(5,v5) CVT1(6,v6) CVT1(7,v7)
#undef CVT1
}

// 3-MFMA split-bf16 64x64 matmul for one 16-row tile
__device__ __forceinline__ void mm64(const bf16x8& ah0, const bf16x8& al0,
                                     const bf16x8& ah1, const bf16x8& al1,
                                     const unsigned short* __restrict__ pW,
                                     int lane, f32x4 acc[4])
{
#pragma unroll
    for (int nt = 0; nt < 4; ++nt) {
        f32x4 a = {0.f, 0.f, 0.f, 0.f};
#pragma unroll
        for (int kt = 0; kt < 2; ++kt) {
            bf16x8 bh = *(const bf16x8*)(pW + (kt*4+nt)*1024 + lane*8);
            bf16x8 bl = *(const bf16x8*)(pW + (kt*4+nt)*1024 + 512 + lane*8);
            bf16x8 aH = kt ? ah1 : ah0;
            bf16x8 aL = kt ? al1 : al0;
            a = __builtin_amdgcn_mfma_f32_16x16x32_bf16(aH, bh, a, 0, 0, 0);
            a = __builtin_amdgcn_mfma_f32_16x16x32_bf16(aL, bh, a, 0, 0, 0);
            a = __builtin_amdgcn_mfma_f32_16x16x32_bf16(aH, bl, a, 0, 0, 0);
        }
        acc[nt] = a;
    }
}

// Pack 7 64x64 fp32 W into B-fragment order (bf16 hi/lo).
__global__ __launch_bounds__(256) void k_packB7(
    const float* W0, unsigned short* d0, const float* W1, unsigned short* d1,
    const float* W2, unsigned short* d2, const float* W3, unsigned short* d3,
    const float* W4, unsigned short* d4, const float* W5, unsigned short* d5,
    const float* W6, unsigned short* d6)
{
    const float* W; unsigned short* dst;
    switch (blockIdx.x) {
        case 0: W=W0; dst=d0; break;
        case 1: W=W1; dst=d1; break;
        case 2: W=W2; dst=d2; break;
        case 3: W=W3; dst=d3; break;
        case 4: W=W4; dst=d4; break;
        case 5: W=W5; dst=d5; break;
        default: W=W6; dst=d6; break;
    }
    int t = threadIdx.x;
    for (int slot = t; slot < 512; slot += 256) {
        int frag = slot >> 6;
        int lane = slot & 63;
        int kt = frag >> 2, nt = frag & 3;
        int g4 = (lane >> 4) * 4, n = nt*16 + (lane & 15);
        for (int j = 0; j < 8; ++j) {
            int k = kt*32 + (j>>2)*16 + g4 + (j&3);
            float x = W[k*64 + n];
            unsigned short hh = f2bf_rne(x);
            float lf = x - __uint_as_float((unsigned)hh << 16);
            dst[frag*1024 + 0*512 + lane*8 + j] = hh;
            dst[frag*1024 + 1*512 + lane*8 + j] = f2bf_rne(lf);
        }
    }
}

// Single-GEMM kernel (only EPI=2 used now): out = X@W + vec3.Wtail
template<int EPI>
__global__ __launch_bounds__(256) void k_gemm(
    const float* __restrict__ X, const unsigned short* __restrict__ pW,
    const float* __restrict__ bias, const float* __restrict__ res1,
    const float* __restrict__ res2, const float* __restrict__ vec3,
    const float* __restrict__ Wtail, const int* __restrict__ ridx,
    float* __restrict__ out, int ntiles)
{
    int lane = threadIdx.x & 63;
    int tile = blockIdx.x*4 + (threadIdx.x >> 6);
    if (tile >= ntiles) return;
    int r0 = tile * 16;
    int g4 = (lane >> 4) * 4;
    int rA = r0 + (lane & 15);
    int xrow = ridx ? ridx[rA] : rA;
    const float* rowp = X + (size_t)xrow * 64;
    bf16x8 ah0, al0, ah1, al1;
    a_frag(rowp, 0, g4, ah0, al0);
    a_frag(rowp, 1, g4, ah1, al1);
    f32x4 acc[4];
    mm64(ah0, al0, ah1, al1, pW, lane, acc);
    int rbase = r0 + (lane >> 4) * 4;
#pragma unroll
    for (int nt = 0; nt < 4; ++nt) {
        int c = nt*16 + (lane & 15);
        float bc = (EPI == 2) ? 0.f : bias[c];
        float w0t = 0.f, w1t = 0.f, w2t = 0.f;
        if (EPI == 1 || EPI == 2) {
            w0t = Wtail[0*64+c]; w1t = Wtail[1*64+c]; w2t = Wtail[2*64+c];
        }
#pragma unroll
        for (int reg = 0; reg < 4; ++reg) {
            int r = rbase + reg;
            float v = acc[nt][reg] + bc;
            if (EPI == 0) {
                v = fmaxf(v, 0.f) + res1[(size_t)r*64 + c];
            } else if (EPI == 1) {
                v += vec3[r*3+0]*w0t + vec3[r*3+1]*w1t + vec3[r*3+2]*w2t;
                v = fmaxf(v, 0.f);
            } else if (EPI == 2) {
                v += vec3[r*3+0]*w0t + vec3[r*3+1]*w1t + vec3[r*3+2]*w2t;
            }
            out[(size_t)r*64 + c] = v;
        }
    }
}

// Fused: x2 = relu(agg@Wg+bg)+x1 (write), h = relu(x2@Wm + rel.Wmt + bm) (write)
__global__ __launch_bounds__(256) void k_post_m2l_g(
    const float* __restrict__ agg, const unsigned short* __restrict__ pWg,
    const float* __restrict__ bg, const float* __restrict__ x1,
    const unsigned short* __restrict__ pWm, const float* __restrict__ bm,
    const float* __restrict__ Wmt, const float* __restrict__ rel,
    float* __restrict__ x2, float* __restrict__ h, int ntiles)
{
    __shared__ float xp[4][16*68];
    int lane = threadIdx.x & 63;
    int w = threadIdx.x >> 6;
    int tile = blockIdx.x*4 + w;
    if (tile >= ntiles) return;
    int r0 = tile*16;
    int g4 = (lane >> 4) * 4;
    int rloc = (lane >> 4) * 4;
    const float* rowp = agg + (size_t)(r0 + (lane & 15)) * 64;
    bf16x8 ah0, al0, ah1, al1;
    a_frag(rowp, 0, g4, ah0, al0);
    a_frag(rowp, 1, g4, ah1, al1);
    f32x4 acc[4];
    mm64(ah0, al0, ah1, al1, pWg, lane, acc);
#pragma unroll
    for (int nt = 0; nt < 4; ++nt) {
        int c = nt*16 + (lane & 15);
        float bc = bg[c];
#pragma unroll
        for (int reg = 0; reg < 4; ++reg) {
            int r = r0 + rloc + reg;
            float v = fmaxf(acc[nt][reg] + bc, 0.f) + x1[(size_t)r*64 + c];
            x2[(size_t)r*64 + c] = v;
            xp[w][(rloc+reg)*68 + c] = v;
        }
    }
    const float* lrow = &xp[w][(lane & 15)*68];
    a_frag(lrow, 0, g4, ah0, al0);
    a_frag(lrow, 1, g4, ah1, al1);
    mm64(ah0, al0, ah1, al1, pWm, lane, acc);
#pragma unroll
    for (int nt = 0; nt < 4; ++nt) {
        int c = nt*16 + (lane & 15);
        float bc = bm[c];
        float w0t = Wmt[0*64+c], w1t = Wmt[1*64+c], w2t = Wmt[2*64+c];
#pragma unroll
        for (int reg = 0; reg < 4; ++reg) {
            int r = r0 + rloc + reg;
            float v = acc[nt][reg] + bc + rel[r*3+0]*w0t + rel[r*3+1]*w1t + rel[r*3+2]*w2t;
            h[(size_t)r*64 + c] = fmaxf(v, 0.f);
        }
    }
}

// Fused: x5 = relu(c4[lab]@Wl + rel.Wlt + bl) (write), p = x5@Wf2 + pts.Wf2t (write)
__global__ __launch_bounds__(256) void k_l2m_pre2_g(
    const float* __restrict__ c4, const int* __restrict__ lab,
    const unsigned short* __restrict__ pWl, const float* __restrict__ bl,
    const float* __restrict__ Wlt, const float* __restrict__ rel,
    const unsigned short* __restrict__ pWf2, const float* __restrict__ Wf2t,
    const float* __restrict__ pts,
    float* __restrict__ x5, float* __restrict__ p, int ntiles)
{
    __shared__ float xp[4][16*68];
    int lane = threadIdx.x & 63;
    int w = threadIdx.x >> 6;
    int tile = blockIdx.x*4 + w;
    if (tile >= ntiles) return;
    int r0 = tile*16;
    int g4 = (lane >> 4) * 4;
    int rloc = (lane >> 4) * 4;
    int rA = r0 + (lane & 15);
    const float* rowp = c4 + (size_t)lab[rA] * 64;
    bf16x8 ah0, al0, ah1, al1;
    a_frag(rowp, 0, g4, ah0, al0);
    a_frag(rowp, 1, g4, ah1, al1);
    f32x4 acc[4];
    mm64(ah0, al0, ah1, al1, pWl, lane, acc);
#pragma unroll
    for (int nt = 0; nt < 4; ++nt) {
        int c = nt*16 + (lane & 15);
        float bc = bl[c];
        float w0t = Wlt[0*64+c], w1t = Wlt[1*64+c], w2t = Wlt[2*64+c];
#pragma unroll
        for (int reg = 0; reg < 4; ++reg) {
            int r = r0 + rloc + reg;
            float v = acc[nt][reg] + bc + rel[r*3+0]*w0t + rel[r*3+1]*w1t + rel[r*3+2]*w2t;
            v = fmaxf(v, 0.f);
            x5[(size_t)r*64 + c] = v;
            xp[w][(rloc+reg)*68 + c] = v;
        }
    }
    const float* lrow = &xp[w][(lane & 15)*68];
    a_frag(lrow, 0, g4, ah0, al0);
    a_frag(lrow, 1, g4, ah1, al1);
    mm64(ah0, al0, ah1, al1, pWf2, lane, acc);
#pragma unroll
    for (int nt = 0; nt < 4; ++nt) {
        int c = nt*16 + (lane & 15);
        float w0t = Wf2t[0*64+c], w1t = Wf2t[1*64+c], w2t = Wf2t[2*64+c];
#pragma unroll
        for (int reg = 0; reg < 4; ++reg) {
            int r = r0 + rloc + reg;
            float v = acc[nt][reg] + pts[r*3+0]*w0t + pts[r*3+1]*w1t + pts[r*3+2]*w2t;
            p[(size_t)r*64 + c] = v;
        }
    }
}

// Fused final: fin = relu(agg@Wg2+bg2)+x5+x2; t = relu(fin@W1+b1); out = t@W2+b2
__global__ __launch_bounds__(256) void k_gemm_final(
    const float* __restrict__ agg, const unsigned short* __restrict__ pWg2,
    const float* __restrict__ bg2,
    const float* __restrict__ x5, const float* __restrict__ x2,
    const unsigned short* __restrict__ pW1, const float* __restrict__ b1,
    const float* __restrict__ W2, const float* __restrict__ b2,
    float* __restrict__ out, int ntiles)
{
    __shared__ float xp[4][16*68];
    int lane = threadIdx.x & 63;
    int w = threadIdx.x >> 6;
    int tile = blockIdx.x*4 + w;
    if (tile >= ntiles) return;
    int r0 = tile*16;
    int g4 = (lane >> 4) * 4;
    int rloc = (lane >> 4) * 4;
    const float* rowp = agg + (size_t)(r0 + (lane & 15)) * 64;
    bf16x8 ah0, al0, ah1, al1;
    a_frag(rowp, 0, g4, ah0, al0);
    a_frag(rowp, 1, g4, ah1, al1);
    f32x4 acc[4];
    mm64(ah0, al0, ah1, al1, pWg2, lane, acc);
#pragma unroll
    for (int nt = 0; nt < 4; ++nt) {
        int c = nt*16 + (lane & 15);
        float bc = bg2[c];
#pragma unroll
        for (int reg = 0; reg < 4; ++reg) {
            int r = r0 + rloc + reg;
            float v = fmaxf(acc[nt][reg] + bc, 0.f)
                    + x5[(size_t)r*64 + c] + x2[(size_t)r*64 + c];
            xp[w][(rloc+reg)*68 + c] = v;
        }
    }
    const float* lrow = &xp[w][(lane & 15)*68];
    a_frag(lrow, 0, g4, ah0, al0);
    a_frag(lrow, 1, g4, ah1, al1);
    mm64(ah0, al0, ah1, al1, pW1, lane, acc);
    float part0[4] = {0.f,0.f,0.f,0.f};
    float part1[4] = {0.f,0.f,0.f,0.f};
    float part2[4] = {0.f,0.f,0.f,0.f};
    float part3[4] = {0.f,0.f,0.f,0.f};
#pragma unroll
    for (int nt = 0; nt < 4; ++nt) {
        int c = nt*16 + (lane & 15);
        float bc = b1[c];
        float4 w2v = *(const float4*)(W2 + c*4);
#pragma unroll
        for (int reg = 0; reg < 4; ++reg) {
            float t = fmaxf(acc[nt][reg] + bc, 0.f);
            part0[reg] = fmaf(t, w2v.x, part0[reg]);
            part1[reg] = fmaf(t, w2v.y, part1[reg]);
            part2[reg] = fmaf(t, w2v.z, part2[reg]);
            part3[reg] = fmaf(t, w2v.w, part3[reg]);
        }
    }
#pragma unroll
    for (int m = 1; m < 16; m <<= 1) {
#pragma unroll
        for (int reg = 0; reg < 4; ++reg) {
            part0[reg] += __shfl_xor(part0[reg], m);
            part1[reg] += __shfl_xor(part1[reg], m);
            part2[reg] += __shfl_xor(part2[reg], m);
            part3[reg] += __shfl_xor(part3[reg], m);
        }
    }
    if ((lane & 15) == 0) {
        float b20 = b2[0], b21 = b2[1], b22 = b2[2], b23 = b2[3];
#pragma unroll
        for (int reg = 0; reg < 4; ++reg) {
            int r = r0 + rloc + reg;
            *(float4*)(out + (size_t)r*4) =
                make_float4(part0[reg]+b20, part1[reg]+b21, part2[reg]+b22, part3[reg]+b23);
        }
    }
}

// ================= bucketed CSR build =================

__global__ __launch_bounds__(256) void k_bhist_e(
    const int2* __restrict__ e, int* __restrict__ gcnt, int E, int nb)
{
    __shared__ int c[400];
    for (int i = threadIdx.x; i < nb; i += 256) c[i] = 0;
    __syncthreads();
    for (int idx = blockIdx.x*256 + threadIdx.x; idx < E; idx += gridDim.x*256)
        atomicAdd(&c[e[idx].y >> 8], 1);
    __syncthreads();
    for (int i = threadIdx.x; i < nb; i += 256) if (c[i]) atomicAdd(&gcnt[i], c[i]);
}

__global__ __launch_bounds__(256) void k_bhist_l(
    const int* __restrict__ lab, int* __restrict__ gcnt, int n, int nb)
{
    __shared__ int c[400];
    for (int i = threadIdx.x; i < nb; i += 256) c[i] = 0;
    __syncthreads();
    for (int idx = blockIdx.x*256 + threadIdx.x; idx < n; idx += gridDim.x*256)
        atomicAdd(&c[lab[idx] >> 8], 1);
    __syncthreads();
    for (int i = threadIdx.x; i < nb; i += 256) if (c[i]) atomicAdd(&gcnt[i], c[i]);
}

__global__ __launch_bounds__(512) void k_bscan3(
    const int* c0, int* b0, int* u0, int nb0, int t0,
    const int* c1, int* b1, int* u1, int nb1, int t1,
    const int* c2, int* b2, int* u2, int nb2, int t2)
{
    const int* cnt; int* base; int* cur; int nb; int tot;
    if (blockIdx.x == 0) { cnt=c0; base=b0; cur=u0; nb=nb0; tot=t0; }
    else if (blockIdx.x == 1) { cnt=c1; base=b1; cur=u1; nb=nb1; tot=t1; }
    else { cnt=c2; base=b2; cur=u2; nb=nb2; tot=t2; }
    __shared__ int sc[512];
    int t = threadIdx.x;
    int v = (t < nb) ? cnt[t] : 0;
    sc[t] = v; __syncthreads();
    for (int o = 1; o < 512; o <<= 1) {
        int a = (t >= o) ? sc[t-o] : 0;
        __syncthreads();
        sc[t] += a;
        __syncthreads();
    }
    if (t < nb) { int ex = sc[t] - v; base[t] = ex; cur[t] = ex; }
    if (t == nb) base[nb] = tot;
}

#define BKT 512
#define EPT 8
__global__ __launch_bounds__(BKT) void k_bucket_e(
    const int2* __restrict__ e, int* __restrict__ cur,
    int2* __restrict__ ebuf, int E, int nb)
{
    __shared__ int cnt[400];
    __shared__ int chunk[400];
    int t = threadIdx.x;
    int base = blockIdx.x * (BKT*EPT);
    for (int i = t; i < nb; i += BKT) cnt[i] = 0;
    __syncthreads();
    int2 ed[EPT]; int rk[EPT];
#pragma unroll
    for (int k = 0; k < EPT; ++k) {
        int idx = base + k*BKT + t;
        if (idx < E) { ed[k] = e[idx]; rk[k] = atomicAdd(&cnt[ed[k].y >> 8], 1); }
        else rk[k] = -1;
    }
    __syncthreads();
    for (int i = t; i < nb; i += BKT) { int c = cnt[i]; if (c) chunk[i] = atomicAdd(&cur[i], c); }
    __syncthreads();
#pragma unroll
    for (int k = 0; k < EPT; ++k)
        if (rk[k] >= 0) ebuf[chunk[ed[k].y >> 8] + rk[k]] = ed[k];
}

__global__ __launch_bounds__(BKT) void k_bucket_l(
    const int* __restrict__ lab, int* __restrict__ cur,
    int2* __restrict__ ebuf, int n, int nb)
{
    __shared__ int cnt[400];
    __shared__ int chunk[400];
    int t = threadIdx.x;
    int base = blockIdx.x * (BKT*EPT);
    for (int i = t; i < nb; i += BKT) cnt[i] = 0;
    __syncthreads();
    int2 ed[EPT]; int rk[EPT];
#pragma unroll
    for (int k = 0; k < EPT; ++k) {
        int idx = base + k*BKT + t;
        if (idx < n) { ed[k] = make_int2(idx, lab[idx]); rk[k] = atomicAdd(&cnt[ed[k].y >> 8], 1); }
        else rk[k] = -1;
    }
    __syncthreads();
    for (int i = t; i < nb; i += BKT) { int c = cnt[i]; if (c) chunk[i] = atomicAdd(&cur[i], c); }
    __syncthreads();
#pragma unroll
    for (int k = 0; k < EPT; ++k)
        if (rk[k] >= 0) ebuf[chunk[ed[k].y >> 8] + rk[k]] = ed[k];
}

__global__ __launch_bounds__(512) void k_final(
    const int2* __restrict__ ebuf, const int* __restrict__ base_,
    int* __restrict__ rs, int* __restrict__ srcs, int ndst, int etot, int nb)
{
    __shared__ int h[256];
    __shared__ int sc[256];
    int b = blockIdx.x, t = threadIdx.x;
    int base = base_[b];
    int cnt  = base_[b+1] - base;
    int d0 = b << 8;
    if (t < 256) h[t] = 0;
    __syncthreads();
    for (int i = t; i < cnt; i += 512) atomicAdd(&h[ebuf[base+i].y - d0], 1);
    __syncthreads();
    int v = (t < 256) ? h[t] : 0;
    if (t < 256) sc[t] = v;
    __syncthreads();
    for (int o = 1; o < 256; o <<= 1) {
        int a = (t < 256 && t >= o) ? sc[t-o] : 0;
        __syncthreads();
        if (t < 256) sc[t] += a;
        __syncthreads();
    }
    if (t < 256) {
        int gpos = base + sc[t] - v;
        if (d0 + t < ndst) rs[d0+t] = gpos;
        h[t] = gpos;
    }
    if (b == nb-1 && t == 0) rs[ndst] = etot;
    __syncthreads();
    for (int i = t; i < cnt; i += 512) {
        int2 ed = ebuf[base+i];
        int pos = atomicAdd(&h[ed.y - d0], 1);
        srcs[pos] = ed.x;
    }
}

// ================= VALU kernels =================

__global__ __launch_bounds__(256, 2) void k_feat_q(
    const float* __restrict__ feat, const float* __restrict__ pts,
    const float* __restrict__ ctr, const int* __restrict__ lab,
    const float* __restrict__ Wfe, const float* __restrict__ bfe,
    const float* __restrict__ Wh, const float* __restrict__ bh,
    const float* __restrict__ Wf, const float* __restrict__ bf,
    float* __restrict__ rel, float* __restrict__ x1, float* __restrict__ q, int n)
{
    int lane = threadIdx.x & 63;
    int wid  = blockIdx.x * (blockDim.x >> 6) + (threadIdx.x >> 6);
    int nw   = gridDim.x * (blockDim.x >> 6);
    float fe0 = Wfe[0*64+lane], fe1 = Wfe[1*64+lane], fe2 = Wfe[2*64+lane], fe3 = Wfe[3*64+lane];
    float fe4 = Wfe[4*64+lane], fe5 = Wfe[5*64+lane], fe6 = Wfe[6*64+lane];
    float bfe_l = bfe[lane];
    float w0 = Wf[0*64+lane], w1 = Wf[1*64+lane], w2 = Wf[2*64+lane];
    float bfl = bf[lane];
    float wh0 = Wh[lane*3+0], wh1 = Wh[lane*3+1], wh2 = Wh[lane*3+2];
    float bh0 = bh[0], bh1 = bh[1], bh2 = bh[2];
    for (int i0 = wid*2; i0 < n; i0 += nw*2) {
        int iA = __builtin_amdgcn_readfirstlane(i0);
        int iB = iA + 1;
        int lA = lab[iA], lB = lab[iB];
        float pA0 = pts[iA*3+0], pA1 = pts[iA*3+1], pA2 = pts[iA*3+2];
        float pB0 = pts[iB*3+0], pB1 = pts[iB*3+1], pB2 = pts[iB*3+2];
        float rA0 = pA0 - ctr[lA*3+0], rA1 = pA1 - ctr[lA*3+1], rA2 = pA2 - ctr[lA*3+2];
        float rB0 = pB0 - ctr[lB*3+0], rB1 = pB1 - ctr[lB*3+1], rB2 = pB2 - ctr[lB*3+2];
        if (lane == 0)      { rel[iA*3+0]=rA0; rel[iA*3+1]=rA1; rel[iA*3+2]=rA2; }
        else if (lane == 1) { rel[iB*3+0]=rB0; rel[iB*3+1]=rB1; rel[iB*3+2]=rB2; }
        float aA = bfe_l, aB = bfe_l;
        aA = fmaf(feat[iA*4+0], fe0, aA); aB = fmaf(feat[iB*4+0], fe0, aB);
        aA = fmaf(feat[iA*4+1], fe1, aA); aB = fmaf(feat[iB*4+1], fe1, aB);
        aA = fmaf(feat[iA*4+2], fe2, aA); aB = fmaf(feat[iB*4+2], fe2, aB);
        aA = fmaf(feat[iA*4+3], fe3, aA); aB = fmaf(feat[iB*4+3], fe3, aB);
        aA = fmaf(rA0, fe4, aA); aB = fmaf(rB0, fe4, aB);
        aA = fmaf(rA1, fe5, aA); aB = fmaf(rB1, fe5, aB);
        aA = fmaf(rA2, fe6, aA); aB = fmaf(rB2, fe6, aB);
        float xvA = fmaxf(aA, 0.f), xvB = fmaxf(aB, 0.f);
        x1[(size_t)iA*64+lane] = xvA;
        x1[(size_t)iB*64+lane] = xvB;
        float d0A = xvA*wh0, d1A = xvA*wh1, d2A = xvA*wh2;
        float d0B = xvB*wh0, d1B = xvB*wh1, d2B = xvB*wh2;
#pragma unroll
        for (int o = 32; o; o >>= 1) {
            d0A += __shfl_xor(d0A,o); d1A += __shfl_xor(d1A,o); d2A += __shfl_xor(d2A,o);
            d0B += __shfl_xor(d0B,o); d1B += __shfl_xor(d1B,o); d2B += __shfl_xor(d2B,o);
        }
        d0A = tanhf(d0A+bh0); d1A = tanhf(d1A+bh1); d2A = tanhf(d2A+bh2);
        d0B = tanhf(d0B+bh0); d1B = tanhf(d1B+bh1); d2B = tanhf(d2B+bh2);
        q[(size_t)iA*64+lane] = (d0A-pA0)*w0 + (d1A-pA1)*w1 + (d2A-pA2)*w2 + bfl;
        q[(size_t)iB*64+lane] = (d0B-pB0)*w0 + (d1B-pB1)*w1 + (d2B-pB2)*w2 + bfl;
    }
}

__global__ __launch_bounds__(256, 2) void k_qdelta(
    const float* __restrict__ x, const float* __restrict__ pos,
    const float* __restrict__ Wh, const float* __restrict__ bh,
    const float* __restrict__ Wf, const float* __restrict__ bf,
    float* __restrict__ q, int n)
{
    int lane = threadIdx.x & 63;
    int wid  = blockIdx.x * (blockDim.x >> 6) + (threadIdx.x >> 6);
    int nw   = gridDim.x * (blockDim.x >> 6);
    float w0 = Wf[0*64+lane], w1 = Wf[1*64+lane], w2 = Wf[2*64+lane];
    float bfl = bf[lane];
    float wh0 = Wh[lane*3+0], wh1 = Wh[lane*3+1], wh2 = Wh[lane*3+2];
    float bh0 = bh[0], bh1 = bh[1], bh2 = bh[2];
    for (int i0 = wid*2; i0 < n; i0 += nw*2) {
        int iA = __builtin_amdgcn_readfirstlane(i0);
        int iB = iA + 1;
        float xvA = x[(size_t)iA*64+lane], xvB = x[(size_t)iB*64+lane];
        float d0A = xvA*wh0, d1A = xvA*wh1, d2A = xvA*wh2;
        float d0B = xvB*wh0, d1B = xvB*wh1, d2B = xvB*wh2;
#pragma unroll
        for (int o = 32; o; o >>= 1) {
            d0A += __shfl_xor(d0A,o); d1A += __shfl_xor(d1A,o); d2A += __shfl_xor(d2A,o);
            d0B += __shfl_xor(d0B,o); d1B += __shfl_xor(d1B,o); d2B += __shfl_xor(d2B,o);
        }
        d0A = tanhf(d0A+bh0); d1A = tanhf(d1A+bh1); d2A = tanhf(d2A+bh2);
        d0B = tanhf(d0B+bh0); d1B = tanhf(d1B+bh1); d2B = tanhf(d2B+bh2);
        float pA0 = pos[iA*3+0], pA1 = pos[iA*3+1], pA2 = pos[iA*3+2];
        float pB0 = pos[iB*3+0], pB1 = pos[iB*3+1], pB2 = pos[iB*3+2];
        q[(size_t)iA*64+lane] = (d0A-pA0)*w0 + (d1A-pA1)*w1 + (d2A-pA2)*w2 + bfl;
        q[(size_t)iB*64+lane] = (d0B-pB0)*w0 + (d1B-pB1)*w1 + (d2B-pB2)*w2 + bfl;
    }
}

// CSR gather-max fused relu(max+q); 2 dests/wave, up to 8 outstanding gathers.
__global__ __launch_bounds__(256) void k_seg_max_gnn(
    const int* __restrict__ rs, const int* __restrict__ srcs,
    const float* __restrict__ p, float* __restrict__ q, int n)
{
    int lane = threadIdx.x & 63;
    int wid  = blockIdx.x * (blockDim.x >> 6) + (threadIdx.x >> 6);
    int nw   = gridDim.x * (blockDim.x >> 6);
    for (int d0 = wid*2; d0 < n; d0 += nw*2) {
        int dA = __builtin_amdgcn_readfirstlane(d0);
        int begA = rs[dA], endA = rs[dA+1], endB = rs[dA+2];
        int ca = begA, cb = endA;
        float aA0=-1e30f, aA1=-1e30f, aA2=-1e30f, aA3=-1e30f;
        float aB0=-1e30f, aB1=-1e30f, aB2=-1e30f, aB3=-1e30f;
        while (ca+4 <= endA && cb+4 <= endB) {
            int s0=srcs[ca], s1=srcs[ca+1], s2=srcs[ca+2], s3=srcs[ca+3];
            int t0=srcs[cb], t1=srcs[cb+1], t2=srcs[cb+2], t3=srcs[cb+3];
            aA0 = fmaxf(aA0, p[(size_t)s0*64+lane]);
            aA1 = fmaxf(aA1, p[(size_t)s1*64+lane]);
            aA2 = fmaxf(aA2, p[(size_t)s2*64+lane]);
            aA3 = fmaxf(aA3, p[(size_t)s3*64+lane]);
            aB0 = fmaxf(aB0, p[(size_t)t0*64+lane]);
            aB1 = fmaxf(aB1, p[(size_t)t1*64+lane]);
            aB2 = fmaxf(aB2, p[(size_t)t2*64+lane]);
            aB3 = fmaxf(aB3, p[(size_t)t3*64+lane]);
            ca += 4; cb += 4;
        }
        while (ca+2 <= endA) {
            int s0=srcs[ca], s1=srcs[ca+1];
            aA0 = fmaxf(aA0, p[(size_t)s0*64+lane]);
            aA1 = fmaxf(aA1, p[(size_t)s1*64+lane]);
            ca += 2;
        }
        while (cb+2 <= endB) {
            int t0=srcs[cb], t1=srcs[cb+1];
            aB0 = fmaxf(aB0, p[(size_t)t0*64+lane]);
            aB1 = fmaxf(aB1, p[(size_t)t1*64+lane]);
            cb += 2;
        }
        if (ca < endA) aA0 = fmaxf(aA0, p[(size_t)srcs[ca]*64+lane]);
        if (cb < endB) aB0 = fmaxf(aB0, p[(size_t)srcs[cb]*64+lane]);
        float accA = fmaxf(fmaxf(aA0, aA1), fmaxf(aA2, aA3));
        float accB = fmaxf(fmaxf(aB0, aB1), fmaxf(aB2, aB3));
        size_t oA = (size_t)dA*64 + lane, oB = oA + 64;
        q[oA] = fmaxf(accA + q[oA], 0.f);
        q[oB] = fmaxf(accB + q[oB], 0.f);
    }
}

__global__ __launch_bounds__(256, 2) void k_seglab_pre1(
    const int* __restrict__ rsL, const int* __restrict__ srcsL,
    const float* __restrict__ h, const float* __restrict__ pos,
    const float* __restrict__ Wh, const float* __restrict__ bh,
    const float* __restrict__ Wf, const float* __restrict__ bf,
    float* __restrict__ c, float* __restrict__ pa, float* __restrict__ qa, int m)
{
    int lane = threadIdx.x & 63;
    int wid  = blockIdx.x * (blockDim.x >> 6) + (threadIdx.x >> 6);
    int nw   = gridDim.x * (blockDim.x >> 6);
    REPD(WLOAD, wc, Wf + 3*64)
    float w0 = Wf[0*64+lane], w1 = Wf[1*64+lane], w2 = Wf[2*64+lane];
    float bfl = bf[lane];
    float wh0 = Wh[lane*3+0], wh1 = Wh[lane*3+1], wh2 = Wh[lane*3+2];
    float bh0 = bh[0], bh1 = bh[1], bh2 = bh[2];
    for (int d0 = wid*2; d0 < m; d0 += nw*2) {
        int dA = __builtin_amdgcn_readfirstlane(d0);
        int dB = dA + 1;
        int begA = rsL[dA], endA = rsL[dA+1], endB = rsL[dA+2];
        int ca = begA, cb = endA;
        float aA0=-1e30f, aA1=-1e30f, aB0=-1e30f, aB1=-1e30f;
        while (ca+2 <= endA && cb+2 <= endB) {
            int s0=srcsL[ca], s1=srcsL[ca+1], s2=srcsL[cb], s3=srcsL[cb+1];
            aA0 = fmaxf(aA0, h[(size_t)s0*64+lane]);
            aA1 = fmaxf(aA1, h[(size_t)s1*64+lane]);
            aB0 = fmaxf(aB0, h[(size_t)s2*64+lane]);
            aB1 = fmaxf(aB1, h[(size_t)s3*64+lane]);
            ca += 2; cb += 2;
        }
        while (ca+2 <= endA) {
            int s0=srcsL[ca], s1=srcsL[ca+1];
            aA0 = fmaxf(aA0, h[(size_t)s0*64+lane]);
            aA1 = fmaxf(aA1, h[(size_t)s1*64+lane]);
            ca += 2;
        }
        while (cb+2 <= endB) {
            int s2=srcsL[cb], s3=srcsL[cb+1];
            aB0 = fmaxf(aB0, h[(size_t)s2*64+lane]);
            aB1 = fmaxf(aB1, h[(size_t)s3*64+lane]);
            cb += 2;
        }
        if (ca < endA) aA0 = fmaxf(aA0, h[(size_t)srcsL[ca]*64+lane]);
        if (cb < endB) aB0 = fmaxf(aB0, h[(size_t)srcsL[cb]*64+lane]);
        float cvA = fmaxf(fmaxf(aA0,aA1), 0.f);
        float cvB = fmaxf(fmaxf(aB0,aB1), 0.f);
        c[(size_t)dA*64+lane] = cvA;
        c[(size_t)dB*64+lane] = cvB;
        float d0A = cvA*wh0, d1A = cvA*wh1, d2A = cvA*wh2;
        float d0B = cvB*wh0, d1B = cvB*wh1, d2B = cvB*wh2;
#pragma unroll
        for (int o = 32; o; o >>= 1) {
            d0A += __shfl_xor(d0A,o); d1A += __shfl_xor(d1A,o); d2A += __shfl_xor(d2A,o);
            d0B += __shfl_xor(d0B,o); d1B += __shfl_xor(d1B,o); d2B += __shfl_xor(d2B,o);
        }
        d0A = tanhf(d0A+bh0); d1A = tanhf(d1A+bh1); d2A = tanhf(d2A+bh2);
        d0B = tanhf(d0B+bh0); d1B = tanhf(d1B+bh1); d2B = tanhf(d2B+bh2);
        float pA0 = pos[dA*3+0], pA1 = pos[dA*3+1], pA2 = pos[dA*3+2];
        float pB0 = pos[dB*3+0], pB1 = pos[dB*3+1], pB2 = pos[dB*3+2];
        float s0A=0.f, s1A=0.f, s0B=0.f, s1B=0.f;
        REPP(WFMA, wc, cvA, s0A, s1A)
        REPP(WFMA, wc, cvB, s0B, s1B)
        pa[(size_t)dA*64+lane] = s0A+s1A + pA0*w0 + pA1*w1 + pA2*w2;
        pa[(size_t)dB*64+lane] = s0B+s1B + pB0*w0 + pB1*w1 + pB2*w2;
        qa[(size_t)dA*64+lane] = (d0A-pA0)*w0 + (d1A-pA1)*w1 + (d2A-pA2)*w2 + bfl;
        qa[(size_t)dB*64+lane] = (d0B-pB0)*w0 + (d1B-pB1)*w1 + (d2B-pB2)*w2 + bfl;
    }
}

__global__ __launch_bounds__(256, 2) void k_gnn_post(
    const float* __restrict__ agg, const float* __restrict__ Wg,
    const float* __restrict__ bg, const float* __restrict__ xres,
    float* __restrict__ out, int n)
{
    int lane = threadIdx.x & 63;
    int wid  = blockIdx.x * (blockDim.x >> 6) + (threadIdx.x >> 6);
    int nw   = gridDim.x * (blockDim.x >> 6);
    REPD(WLOAD, wg, Wg)
    float bgl = bg[lane];
    for (int i0 = wid*2; i0 < n; i0 += nw*2) {
        int iA = __builtin_amdgcn_readfirstlane(i0);
        size_t oA = (size_t)iA*64 + lane, oB = oA + 64;
        float avA = agg[oA], avB = agg[oB];
        float s0A=0.f, s1A=0.f, s0B=0.f, s1B=0.f;
        REPP(WFMA, wg, avA, s0A, s1A)
        REPP(WFMA, wg, avB, s0B, s1B)
        out[oA] = fmaxf(s0A+s1A + bgl, 0.f) + xres[oA];
        out[oB] = fmaxf(s0B+s1B + bgl, 0.f) + xres[oB];
    }
}

// ---------------- launch ----------------

extern "C" void kernel_launch(void* const* d_in, const int* in_sizes, int n_in,
                              void* d_out, int out_size, void* d_ws, size_t ws_size,
                              hipStream_t stream)
{
    const int N = 100000, M = 10000, E0 = 1600000, E1 = 320000;
    const int NB0 = (N + 255) / 256;
    const int NB1 = (M + 255) / 256;
    const int NBL = (M + 255) / 256;

    const float* feat = (const float*)d_in[0];
    const float* pts  = (const float*)d_in[1];
    const float* ctr  = (const float*)d_in[2];
    const int*   lab  = (const int*)d_in[3];
    const int2*  e0   = (const int2*)d_in[4];
    const int2*  e1   = (const int2*)d_in[5];
    const float* feW  = (const float*)d_in[6];
    const float* feb  = (const float*)d_in[7];
    const float* Wh   = (const float*)d_in[8];
    const float* bh   = (const float*)d_in[9];
    const float* Wf   = (const float*)d_in[10];
    const float* bf   = (const float*)d_in[11];
    const float* Wg   = (const float*)d_in[12];
    const float* bg   = (const float*)d_in[13];
    const float* m2lW = (const float*)d_in[14];
    const float* m2lb = (const float*)d_in[15];
    const float* l2mW = (const float*)d_in[16];
    const float* l2mb = (const float*)d_in[17];
    const float* cW1  = (const float*)d_in[18];
    const float* cb1  = (const float*)d_in[19];
    const float* cW2  = (const float*)d_in[20];
    const float* cb2  = (const float*)d_in[21];
    float* out = (float*)d_out;

    char* ws = (char*)d_ws;
    size_t off = 0;
    auto alloc = [&](size_t bytes) -> char* {
        char* r = ws + off; off += (bytes + 255) & ~(size_t)255; return r;
    };
    float* rel   = (float*)alloc((size_t)N*3*4);
    float* x1    = (float*)alloc((size_t)N*64*4);   // x1, later x5
    float* x2    = (float*)alloc((size_t)N*64*4);   // hosts ebufs pre-compute
    float* p     = (float*)alloc((size_t)N*64*4);   // p0/h/p2
    float* q     = (float*)alloc((size_t)N*64*4);   // q/agg
    float* c     = (float*)alloc((size_t)M*64*4);
    float* c4    = (float*)alloc((size_t)M*64*4);
    int* rs0     = (int*)alloc((size_t)(N+2)*4);
    int* srcs0   = (int*)alloc((size_t)E0*4);
    int* rs1     = (int*)alloc((size_t)(M+2)*4);
    int* srcs1   = (int*)alloc((size_t)E1*4);
    int* rsL     = (int*)alloc((size_t)(M+2)*4);
    int* srcsL   = (int*)alloc((size_t)N*4);
    int* cnt0    = (int*)alloc((size_t)NB0*4);
    int* cnt1    = (int*)alloc((size_t)NB1*4);
    int* cntL    = (int*)alloc((size_t)NBL*4);
    int* base0   = (int*)alloc((size_t)(NB0+1)*4);
    int* base1   = (int*)alloc((size_t)(NB1+1)*4);
    int* baseL   = (int*)alloc((size_t)(NBL+1)*4);
    int* cur0    = (int*)alloc((size_t)NB0*4);
    int* cur1    = (int*)alloc((size_t)NB1*4);
    int* curL    = (int*)alloc((size_t)NBL*4);
    unsigned short* pWf0  = (unsigned short*)alloc(8192*2);
    unsigned short* pWg0  = (unsigned short*)alloc(8192*2);
    unsigned short* pWm   = (unsigned short*)alloc(8192*2);
    unsigned short* pWl2m = (unsigned short*)alloc(8192*2);
    unsigned short* pWf2  = (unsigned short*)alloc(8192*2);
    unsigned short* pWg2  = (unsigned short*)alloc(8192*2);
    unsigned short* pW1   = (unsigned short*)alloc(8192*2);
    (void)ws_size; (void)in_sizes; (void)n_in; (void)out_size;

    int2* ebuf0 = (int2*)x2;
    int2* ebuf1 = ebuf0 + E0;
    int2* ebufL = ebuf1 + E1;

    dim3 blk(256);
    const int gridN = 2048, gridM = 640, gSeg = 3072;
    const int NT = N / 16;
    const int gG = (NT + 3) / 4;

    // ---- weight prepack ----
    k_packB7<<<7, blk, 0, stream>>>(
        Wf + 0*67*64 + 3*64, pWf0,
        Wg + 0*64*64,        pWg0,
        m2lW,                pWm,
        l2mW,                pWl2m,
        Wf + 2*67*64 + 3*64, pWf2,
        Wg + 2*64*64,        pWg2,
        cW1,                 pW1);

    // ---- CSR builds ----
    hipMemsetAsync(cnt0, 0, (size_t)NB0*4, stream);
    hipMemsetAsync(cnt1, 0, (size_t)NB1*4, stream);
    hipMemsetAsync(cntL, 0, (size_t)NBL*4, stream);
    k_bhist_e<<<1024, blk, 0, stream>>>(e0, cnt0, E0, NB0);
    k_bhist_e<<<512,  blk, 0, stream>>>(e1, cnt1, E1, NB1);
    k_bhist_l<<<512,  blk, 0, stream>>>(lab, cntL, N, NBL);
    k_bscan3<<<3, 512, 0, stream>>>(cnt0, base0, cur0, NB0, E0,
                                    cnt1, base1, cur1, NB1, E1,
                                    cntL, baseL, curL, NBL, N);
    k_bucket_e<<<(E0 + BKT*EPT - 1)/(BKT*EPT), BKT, 0, stream>>>(e0, cur0, ebuf0, E0, NB0);
    k_bucket_e<<<(E1 + BKT*EPT - 1)/(BKT*EPT), BKT, 0, stream>>>(e1, cur1, ebuf1, E1, NB1);
    k_bucket_l<<<(N  + BKT*EPT - 1)/(BKT*EPT), BKT, 0, stream>>>(lab, curL, ebufL, N, NBL);
    k_final<<<NB0, 512, 0, stream>>>(ebuf0, base0, rs0, srcs0, N, E0, NB0);
    k_final<<<NB1, 512, 0, stream>>>(ebuf1, base1, rs1, srcs1, M, E1, NB1);
    k_final<<<NBL, 512, 0, stream>>>(ebufL, baseL, rsL, srcsL, M, N, NBL);

    // ---- layer 0 ----
    k_feat_q<<<gridN, blk, 0, stream>>>(feat, pts, ctr, lab, feW, feb,
                                        Wh+0*64*3, bh+0*3, Wf+0*67*64, bf+0*64,
                                        rel, x1, q, N);
    k_gemm<2><<<gG, blk, 0, stream>>>(x1, pWf0, nullptr, nullptr, nullptr,
                                      pts, Wf+0*67*64, nullptr, p, NT);
    k_seg_max_gnn<<<gSeg, blk, 0, stream>>>(rs0, srcs0, p, q, N);
    k_post_m2l_g<<<gG, blk, 0, stream>>>(q, pWg0, bg+0*64, x1,
                                         pWm, m2lb, m2lW+64*64, rel,
                                         x2, p, NT);

    // ---- layer 1 (clusters, VALU) ----
    float* p1 = q;
    float* q1 = q + (size_t)M*64;
    k_seglab_pre1<<<gridM, blk, 0, stream>>>(rsL, srcsL, p, ctr,
                                             Wh+1*64*3, bh+1*3, Wf+1*67*64, bf+1*64,
                                             c, p1, q1, M);
    k_seg_max_gnn<<<640, blk, 0, stream>>>(rs1, srcs1, p1, q1, M);
    k_gnn_post<<<gridM, blk, 0, stream>>>(q1, Wg+1*64*64, bg+1*64, c, c4, M);

    // ---- l2m + layer 2 + classifier ----
    k_l2m_pre2_g<<<gG, blk, 0, stream>>>(c4, lab, pWl2m, l2mb, l2mW+64*64, rel,
                                         pWf2, Wf+2*67*64, pts,
                                         x1, p, NT);                        // x5 -> x1
    k_qdelta<<<gridN, blk, 0, stream>>>(x1, pts, Wh+2*64*3, bh+2*3,
                                        Wf+2*67*64, bf+2*64, q, N);
    k_seg_max_gnn<<<gSeg, blk, 0, stream>>>(rs0, srcs0, p, q, N);
    k_gemm_final<<<gG, blk, 0, stream>>>(q, pWg2, bg+2*64, x1, x2,
                                         pW1, cb1, cW2, cb2, out, NT);
}

// Round 12
// 390.185 us; speedup vs baseline: 1.5301x; 1.0592x over previous
//
#include <hip/hip_runtime.h>

// ---------------- helpers ----------------

__device__ __forceinline__ float wredsum(float v) {
#pragma unroll
    for (int o = 32; o; o >>= 1) v += __shfl_xor(v, o);
    return v;
}

__device__ __forceinline__ float bcast(float v, int l) {
    return __int_as_float(__builtin_amdgcn_readlane(__float_as_int(v), l));
}

// 64 NAMED weight scalars (M-sized VALU kernels)
#define REPD(M,P,B) \
 M(0,P,B)  M(1,P,B)  M(2,P,B)  M(3,P,B)  M(4,P,B)  M(5,P,B)  M(6,P,B)  M(7,P,B) \
 M(8,P,B)  M(9,P,B)  M(10,P,B) M(11,P,B) M(12,P,B) M(13,P,B) M(14,P,B) M(15,P,B) \
 M(16,P,B) M(17,P,B) M(18,P,B) M(19,P,B) M(20,P,B) M(21,P,B) M(22,P,B) M(23,P,B) \
 M(24,P,B) M(25,P,B) M(26,P,B) M(27,P,B) M(28,P,B) M(29,P,B) M(30,P,B) M(31,P,B) \
 M(32,P,B) M(33,P,B) M(34,P,B) M(35,P,B) M(36,P,B) M(37,P,B) M(38,P,B) M(39,P,B) \
 M(40,P,B) M(41,P,B) M(42,P,B) M(43,P,B) M(44,P,B) M(45,P,B) M(46,P,B) M(47,P,B) \
 M(48,P,B) M(49,P,B) M(50,P,B) M(51,P,B) M(52,P,B) M(53,P,B) M(54,P,B) M(55,P,B) \
 M(56,P,B) M(57,P,B) M(58,P,B) M(59,P,B) M(60,P,B) M(61,P,B) M(62,P,B) M(63,P,B)

#define WLOAD(J,P,B) float P##J = (B)[(J)*64+lane];

#define REPP(M,P,X,S0,S1) \
 M(0,1,P,X,S0,S1)  M(2,3,P,X,S0,S1)  M(4,5,P,X,S0,S1)  M(6,7,P,X,S0,S1) \
 M(8,9,P,X,S0,S1)  M(10,11,P,X,S0,S1) M(12,13,P,X,S0,S1) M(14,15,P,X,S0,S1) \
 M(16,17,P,X,S0,S1) M(18,19,P,X,S0,S1) M(20,21,P,X,S0,S1) M(22,23,P,X,S0,S1) \
 M(24,25,P,X,S0,S1) M(26,27,P,X,S0,S1) M(28,29,P,X,S0,S1) M(30,31,P,X,S0,S1) \
 M(32,33,P,X,S0,S1) M(34,35,P,X,S0,S1) M(36,37,P,X,S0,S1) M(38,39,P,X,S0,S1) \
 M(40,41,P,X,S0,S1) M(42,43,P,X,S0,S1) M(44,45,P,X,S0,S1) M(46,47,P,X,S0,S1) \
 M(48,49,P,X,S0,S1) M(50,51,P,X,S0,S1) M(52,53,P,X,S0,S1) M(54,55,P,X,S0,S1) \
 M(56,57,P,X,S0,S1) M(58,59,P,X,S0,S1) M(60,61,P,X,S0,S1) M(62,63,P,X,S0,S1)

#define WFMA(J,K,P,X,S0,S1) \
 S0 = fmaf(bcast(X,J), P##J, S0); \
 S1 = fmaf(bcast(X,K), P##K, S1);

// ---------------- MFMA split-bf16 machinery ----------------

typedef short bf16x8 __attribute__((ext_vector_type(8)));
typedef float f32x4  __attribute__((ext_vector_type(4)));

__device__ __forceinline__ unsigned short f2bf_rne(float x) {
    unsigned u = __float_as_uint(x);
    unsigned r = u + 0x7FFFu + ((u >> 16) & 1u);
    return (unsigned short)(r >> 16);
}

__device__ __forceinline__ void a_frag(const float* __restrict__ row, int kt, int g4,
                                       bf16x8& ah, bf16x8& al)
{
    const float4 a0 = *(const float4*)(row + kt*32 + g4);
    const float4 a1 = *(const float4*)(row + kt*32 + 16 + g4);
    float v0 = a0.x, v1 = a0.y, v2 = a0.z, v3 = a0.w;
    float v4 = a1.x, v5 = a1.y, v6 = a1.z, v7 = a1.w;
#define CVT1(idx, val) { \
    unsigned short hh = f2bf_rne(val); \
    float lf = (val) - __uint_as_float((unsigned)hh << 16); \
    ah[idx] = (short)hh; al[idx] = (short)f2bf_rne(lf); }
    CVT1(0,v0) CVT1(1,v1) CVT1(2,v2) CVT1(3,v3)
    CVT1(4,v4) CVT1(5,v5) CVT1(6,v6) CVT1(7,v7)
#undef CVT1
}

// 3-MFMA split-bf16 64x64 matmul for one 16-row tile
__device__ __forceinline__ void mm64(const bf16x8& ah0, const bf16x8& al0,
                                     const bf16x8& ah1, const bf16x8& al1,
                                     const unsigned short* __restrict__ pW,
                                     int lane, f32x4 acc[4])
{
#pragma unroll
    for (int nt = 0; nt < 4; ++nt) {
        f32x4 a = {0.f, 0.f, 0.f, 0.f};
#pragma unroll
        for (int kt = 0; kt < 2; ++kt) {
            bf16x8 bh = *(const bf16x8*)(pW + (kt*4+nt)*1024 + lane*8);
            bf16x8 bl = *(const bf16x8*)(pW + (kt*4+nt)*1024 + 512 + lane*8);
            bf16x8 aH = kt ? ah1 : ah0;
            bf16x8 aL = kt ? al1 : al0;
            a = __builtin_amdgcn_mfma_f32_16x16x32_bf16(aH, bh, a, 0, 0, 0);
            a = __builtin_amdgcn_mfma_f32_16x16x32_bf16(aL, bh, a, 0, 0, 0);
            a = __builtin_amdgcn_mfma_f32_16x16x32_bf16(aH, bl, a, 0, 0, 0);
        }
        acc[nt] = a;
    }
}

// Pack 7 64x64 fp32 W into B-fragment order (bf16 hi/lo).
__global__ __launch_bounds__(256) void k_packB7(
    const float* W0, unsigned short* d0, const float* W1, unsigned short* d1,
    const float* W2, unsigned short* d2, const float* W3, unsigned short* d3,
    const float* W4, unsigned short* d4, const float* W5, unsigned short* d5,
    const float* W6, unsigned short* d6)
{
    const float* W; unsigned short* dst;
    switch (blockIdx.x) {
        case 0: W=W0; dst=d0; break;
        case 1: W=W1; dst=d1; break;
        case 2: W=W2; dst=d2; break;
        case 3: W=W3; dst=d3; break;
        case 4: W=W4; dst=d4; break;
        case 5: W=W5; dst=d5; break;
        default: W=W6; dst=d6; break;
    }
    int t = threadIdx.x;
    for (int slot = t; slot < 512; slot += 256) {
        int frag = slot >> 6;
        int lane = slot & 63;
        int kt = frag >> 2, nt = frag & 3;
        int g4 = (lane >> 4) * 4, n = nt*16 + (lane & 15);
        for (int j = 0; j < 8; ++j) {
            int k = kt*32 + (j>>2)*16 + g4 + (j&3);
            float x = W[k*64 + n];
            unsigned short hh = f2bf_rne(x);
            float lf = x - __uint_as_float((unsigned)hh << 16);
            dst[frag*1024 + 0*512 + lane*8 + j] = hh;
            dst[frag*1024 + 1*512 + lane*8 + j] = f2bf_rne(lf);
        }
    }
}

// p-GEMM: out = X@W + vec3.Wtail  (EPI=2 only)
template<int EPI>
__global__ __launch_bounds__(256) void k_gemm(
    const float* __restrict__ X, const unsigned short* __restrict__ pW,
    const float* __restrict__ bias, const float* __restrict__ res1,
    const float* __restrict__ res2, const float* __restrict__ vec3,
    const float* __restrict__ Wtail, const int* __restrict__ ridx,
    float* __restrict__ out, int ntiles)
{
    int lane = threadIdx.x & 63;
    int tile = blockIdx.x*4 + (threadIdx.x >> 6);
    if (tile >= ntiles) return;
    int r0 = tile * 16;
    int g4 = (lane >> 4) * 4;
    int rA = r0 + (lane & 15);
    int xrow = ridx ? ridx[rA] : rA;
    const float* rowp = X + (size_t)xrow * 64;
    bf16x8 ah0, al0, ah1, al1;
    a_frag(rowp, 0, g4, ah0, al0);
    a_frag(rowp, 1, g4, ah1, al1);
    f32x4 acc[4];
    mm64(ah0, al0, ah1, al1, pW, lane, acc);
    int rbase = r0 + (lane >> 4) * 4;
#pragma unroll
    for (int nt = 0; nt < 4; ++nt) {
        int c = nt*16 + (lane & 15);
        float bc = (EPI == 2) ? 0.f : bias[c];
        float w0t = 0.f, w1t = 0.f, w2t = 0.f;
        if (EPI == 1 || EPI == 2) {
            w0t = Wtail[0*64+c]; w1t = Wtail[1*64+c]; w2t = Wtail[2*64+c];
        }
#pragma unroll
        for (int reg = 0; reg < 4; ++reg) {
            int r = rbase + reg;
            float v = acc[nt][reg] + bc;
            if (EPI == 0) {
                v = fmaxf(v, 0.f) + res1[(size_t)r*64 + c];
            } else if (EPI == 1) {
                v += vec3[r*3+0]*w0t + vec3[r*3+1]*w1t + vec3[r*3+2]*w2t;
                v = fmaxf(v, 0.f);
            } else if (EPI == 2) {
                v += vec3[r*3+0]*w0t + vec3[r*3+1]*w1t + vec3[r*3+2]*w2t;
            }
            out[(size_t)r*64 + c] = v;
        }
    }
}

// Fused: x2 = relu(agg@Wg+bg)+x1 (write), h = relu(x2@Wm + rel.Wmt + bm) (write)
__global__ __launch_bounds__(256) void k_post_m2l_g(
    const float* __restrict__ agg, const unsigned short* __restrict__ pWg,
    const float* __restrict__ bg, const float* __restrict__ x1,
    const unsigned short* __restrict__ pWm, const float* __restrict__ bm,
    const float* __restrict__ Wmt, const float* __restrict__ rel,
    float* __restrict__ x2, float* __restrict__ h, int ntiles)
{
    __shared__ float xp[4][16*68];
    int lane = threadIdx.x & 63;
    int w = threadIdx.x >> 6;
    int tile = blockIdx.x*4 + w;
    if (tile >= ntiles) return;
    int r0 = tile*16;
    int g4 = (lane >> 4) * 4;
    int rloc = (lane >> 4) * 4;
    const float* rowp = agg + (size_t)(r0 + (lane & 15)) * 64;
    bf16x8 ah0, al0, ah1, al1;
    a_frag(rowp, 0, g4, ah0, al0);
    a_frag(rowp, 1, g4, ah1, al1);
    f32x4 acc[4];
    mm64(ah0, al0, ah1, al1, pWg, lane, acc);
#pragma unroll
    for (int nt = 0; nt < 4; ++nt) {
        int c = nt*16 + (lane & 15);
        float bc = bg[c];
#pragma unroll
        for (int reg = 0; reg < 4; ++reg) {
            int r = r0 + rloc + reg;
            float v = fmaxf(acc[nt][reg] + bc, 0.f) + x1[(size_t)r*64 + c];
            x2[(size_t)r*64 + c] = v;
            xp[w][(rloc+reg)*68 + c] = v;
        }
    }
    const float* lrow = &xp[w][(lane & 15)*68];
    a_frag(lrow, 0, g4, ah0, al0);
    a_frag(lrow, 1, g4, ah1, al1);
    mm64(ah0, al0, ah1, al1, pWm, lane, acc);
#pragma unroll
    for (int nt = 0; nt < 4; ++nt) {
        int c = nt*16 + (lane & 15);
        float bc = bm[c];
        float w0t = Wmt[0*64+c], w1t = Wmt[1*64+c], w2t = Wmt[2*64+c];
#pragma unroll
        for (int reg = 0; reg < 4; ++reg) {
            int r = r0 + rloc + reg;
            float v = acc[nt][reg] + bc + rel[r*3+0]*w0t + rel[r*3+1]*w1t + rel[r*3+2]*w2t;
            h[(size_t)r*64 + c] = fmaxf(v, 0.f);
        }
    }
}

// Fused: x5 = relu(c4[lab]@Wl + rel.Wlt + bl); p = x5@Wf2 + pts.Wf2t;
//        q = (tanh(x5@Wh+bh) - pts).Wf2t + bf     (all three written)
__global__ __launch_bounds__(256) void k_l2m_pre2_g(
    const float* __restrict__ c4, const int* __restrict__ lab,
    const unsigned short* __restrict__ pWl, const float* __restrict__ bl,
    const float* __restrict__ Wlt, const float* __restrict__ rel,
    const unsigned short* __restrict__ pWf2, const float* __restrict__ Wf2t,
    const float* __restrict__ pts,
    const float* __restrict__ Wh, const float* __restrict__ bh,
    const float* __restrict__ bf,
    float* __restrict__ x5, float* __restrict__ p, float* __restrict__ q, int ntiles)
{
    __shared__ float xp[4][16*68];
    __shared__ float dd[4][64];
    int lane = threadIdx.x & 63;
    int w = threadIdx.x >> 6;
    int tile = blockIdx.x*4 + w;
    if (tile >= ntiles) return;
    int r0 = tile*16;
    int g4 = (lane >> 4) * 4;
    int rloc = (lane >> 4) * 4;
    int rA = r0 + (lane & 15);
    const float* rowp = c4 + (size_t)lab[rA] * 64;
    bf16x8 ah0, al0, ah1, al1;
    a_frag(rowp, 0, g4, ah0, al0);
    a_frag(rowp, 1, g4, ah1, al1);
    f32x4 acc[4];
    mm64(ah0, al0, ah1, al1, pWl, lane, acc);
#pragma unroll
    for (int nt = 0; nt < 4; ++nt) {
        int c = nt*16 + (lane & 15);
        float bc = bl[c];
        float w0t = Wlt[0*64+c], w1t = Wlt[1*64+c], w2t = Wlt[2*64+c];
#pragma unroll
        for (int reg = 0; reg < 4; ++reg) {
            int r = r0 + rloc + reg;
            float v = acc[nt][reg] + bc + rel[r*3+0]*w0t + rel[r*3+1]*w1t + rel[r*3+2]*w2t;
            v = fmaxf(v, 0.f);
            x5[(size_t)r*64 + c] = v;
            xp[w][(rloc+reg)*68 + c] = v;
        }
    }
    // per-row delta: lane = (row, jj); j = min(jj,2); serial 64-LDS dot (2-way alias free)
    {
        int rowl = lane & 15;
        int jj = lane >> 4;
        int j = jj < 3 ? jj : 2;
        float accd = 0.f;
#pragma unroll 16
        for (int k = 0; k < 64; ++k)
            accd = fmaf(xp[w][rowl*68 + k], Wh[k*3 + j], accd);
        dd[w][rowl*4 + jj] = tanhf(accd + bh[j]);
    }
    const float* lrow = &xp[w][(lane & 15)*68];
    a_frag(lrow, 0, g4, ah0, al0);
    a_frag(lrow, 1, g4, ah1, al1);
    mm64(ah0, al0, ah1, al1, pWf2, lane, acc);
#pragma unroll
    for (int nt = 0; nt < 4; ++nt) {
        int c = nt*16 + (lane & 15);
        float w0t = Wf2t[0*64+c], w1t = Wf2t[1*64+c], w2t = Wf2t[2*64+c];
        float bfc = bf[c];
#pragma unroll
        for (int reg = 0; reg < 4; ++reg) {
            int r = r0 + rloc + reg;
            int rl = rloc + reg;
            float p0 = pts[r*3+0], p1 = pts[r*3+1], p2 = pts[r*3+2];
            float v = acc[nt][reg] + p0*w0t + p1*w1t + p2*w2t;
            p[(size_t)r*64 + c] = v;
            float d0 = dd[w][rl*4+0], d1 = dd[w][rl*4+1], d2 = dd[w][rl*4+2];
            q[(size_t)r*64 + c] = (d0-p0)*w0t + (d1-p1)*w1t + (d2-p2)*w2t + bfc;
        }
    }
}

// Fused final: fin = relu(agg@Wg2+bg2)+x5+x2; t = relu(fin@W1+b1); out = t@W2+b2
__global__ __launch_bounds__(256) void k_gemm_final(
    const float* __restrict__ agg, const unsigned short* __restrict__ pWg2,
    const float* __restrict__ bg2,
    const float* __restrict__ x5, const float* __restrict__ x2,
    const unsigned short* __restrict__ pW1, const float* __restrict__ b1,
    const float* __restrict__ W2, const float* __restrict__ b2,
    float* __restrict__ out, int ntiles)
{
    __shared__ float xp[4][16*68];
    int lane = threadIdx.x & 63;
    int w = threadIdx.x >> 6;
    int tile = blockIdx.x*4 + w;
    if (tile >= ntiles) return;
    int r0 = tile*16;
    int g4 = (lane >> 4) * 4;
    int rloc = (lane >> 4) * 4;
    const float* rowp = agg + (size_t)(r0 + (lane & 15)) * 64;
    bf16x8 ah0, al0, ah1, al1;
    a_frag(rowp, 0, g4, ah0, al0);
    a_frag(rowp, 1, g4, ah1, al1);
    f32x4 acc[4];
    mm64(ah0, al0, ah1, al1, pWg2, lane, acc);
#pragma unroll
    for (int nt = 0; nt < 4; ++nt) {
        int c = nt*16 + (lane & 15);
        float bc = bg2[c];
#pragma unroll
        for (int reg = 0; reg < 4; ++reg) {
            int r = r0 + rloc + reg;
            float v = fmaxf(acc[nt][reg] + bc, 0.f)
                    + x5[(size_t)r*64 + c] + x2[(size_t)r*64 + c];
            xp[w][(rloc+reg)*68 + c] = v;
        }
    }
    const float* lrow = &xp[w][(lane & 15)*68];
    a_frag(lrow, 0, g4, ah0, al0);
    a_frag(lrow, 1, g4, ah1, al1);
    mm64(ah0, al0, ah1, al1, pW1, lane, acc);
    float part0[4] = {0.f,0.f,0.f,0.f};
    float part1[4] = {0.f,0.f,0.f,0.f};
    float part2[4] = {0.f,0.f,0.f,0.f};
    float part3[4] = {0.f,0.f,0.f,0.f};
#pragma unroll
    for (int nt = 0; nt < 4; ++nt) {
        int c = nt*16 + (lane & 15);
        float bc = b1[c];
        float4 w2v = *(const float4*)(W2 + c*4);
#pragma unroll
        for (int reg = 0; reg < 4; ++reg) {
            float t = fmaxf(acc[nt][reg] + bc, 0.f);
            part0[reg] = fmaf(t, w2v.x, part0[reg]);
            part1[reg] = fmaf(t, w2v.y, part1[reg]);
            part2[reg] = fmaf(t, w2v.z, part2[reg]);
            part3[reg] = fmaf(t, w2v.w, part3[reg]);
        }
    }
#pragma unroll
    for (int m = 1; m < 16; m <<= 1) {
#pragma unroll
        for (int reg = 0; reg < 4; ++reg) {
            part0[reg] += __shfl_xor(part0[reg], m);
            part1[reg] += __shfl_xor(part1[reg], m);
            part2[reg] += __shfl_xor(part2[reg], m);
            part3[reg] += __shfl_xor(part3[reg], m);
        }
    }
    if ((lane & 15) == 0) {
        float b20 = b2[0], b21 = b2[1], b22 = b2[2], b23 = b2[3];
#pragma unroll
        for (int reg = 0; reg < 4; ++reg) {
            int r = r0 + rloc + reg;
            *(float4*)(out + (size_t)r*4) =
                make_float4(part0[reg]+b20, part1[reg]+b21, part2[reg]+b22, part3[reg]+b23);
        }
    }
}

// ================= bucketed CSR build =================

__global__ __launch_bounds__(256) void k_bhist_e(
    const int2* __restrict__ e, int* __restrict__ gcnt, int E, int nb)
{
    __shared__ int c[400];
    for (int i = threadIdx.x; i < nb; i += 256) c[i] = 0;
    __syncthreads();
    for (int idx = blockIdx.x*256 + threadIdx.x; idx < E; idx += gridDim.x*256)
        atomicAdd(&c[e[idx].y >> 8], 1);
    __syncthreads();
    for (int i = threadIdx.x; i < nb; i += 256) if (c[i]) atomicAdd(&gcnt[i], c[i]);
}

__global__ __launch_bounds__(256) void k_bhist_l(
    const int* __restrict__ lab, int* __restrict__ gcnt, int n, int nb)
{
    __shared__ int c[400];
    for (int i = threadIdx.x; i < nb; i += 256) c[i] = 0;
    __syncthreads();
    for (int idx = blockIdx.x*256 + threadIdx.x; idx < n; idx += gridDim.x*256)
        atomicAdd(&c[lab[idx] >> 8], 1);
    __syncthreads();
    for (int i = threadIdx.x; i < nb; i += 256) if (c[i]) atomicAdd(&gcnt[i], c[i]);
}

__global__ __launch_bounds__(512) void k_bscan3(
    const int* c0, int* b0, int* u0, int nb0, int t0,
    const int* c1, int* b1, int* u1, int nb1, int t1,
    const int* c2, int* b2, int* u2, int nb2, int t2)
{
    const int* cnt; int* base; int* cur; int nb; int tot;
    if (blockIdx.x == 0) { cnt=c0; base=b0; cur=u0; nb=nb0; tot=t0; }
    else if (blockIdx.x == 1) { cnt=c1; base=b1; cur=u1; nb=nb1; tot=t1; }
    else { cnt=c2; base=b2; cur=u2; nb=nb2; tot=t2; }
    __shared__ int sc[512];
    int t = threadIdx.x;
    int v = (t < nb) ? cnt[t] : 0;
    sc[t] = v; __syncthreads();
    for (int o = 1; o < 512; o <<= 1) {
        int a = (t >= o) ? sc[t-o] : 0;
        __syncthreads();
        sc[t] += a;
        __syncthreads();
    }
    if (t < nb) { int ex = sc[t] - v; base[t] = ex; cur[t] = ex; }
    if (t == nb) base[nb] = tot;
}

#define BKT 512
#define EPT 8
__global__ __launch_bounds__(BKT) void k_bucket_e(
    const int2* __restrict__ e, int* __restrict__ cur,
    int2* __restrict__ ebuf, int E, int nb)
{
    __shared__ int cnt[400];
    __shared__ int chunk[400];
    int t = threadIdx.x;
    int base = blockIdx.x * (BKT*EPT);
    for (int i = t; i < nb; i += BKT) cnt[i] = 0;
    __syncthreads();
    int2 ed[EPT]; int rk[EPT];
#pragma unroll
    for (int k = 0; k < EPT; ++k) {
        int idx = base + k*BKT + t;
        if (idx < E) { ed[k] = e[idx]; rk[k] = atomicAdd(&cnt[ed[k].y >> 8], 1); }
        else rk[k] = -1;
    }
    __syncthreads();
    for (int i = t; i < nb; i += BKT) { int c = cnt[i]; if (c) chunk[i] = atomicAdd(&cur[i], c); }
    __syncthreads();
#pragma unroll
    for (int k = 0; k < EPT; ++k)
        if (rk[k] >= 0) ebuf[chunk[ed[k].y >> 8] + rk[k]] = ed[k];
}

__global__ __launch_bounds__(BKT) void k_bucket_l(
    const int* __restrict__ lab, int* __restrict__ cur,
    int2* __restrict__ ebuf, int n, int nb)
{
    __shared__ int cnt[400];
    __shared__ int chunk[400];
    int t = threadIdx.x;
    int base = blockIdx.x * (BKT*EPT);
    for (int i = t; i < nb; i += BKT) cnt[i] = 0;
    __syncthreads();
    int2 ed[EPT]; int rk[EPT];
#pragma unroll
    for (int k = 0; k < EPT; ++k) {
        int idx = base + k*BKT + t;
        if (idx < n) { ed[k] = make_int2(idx, lab[idx]); rk[k] = atomicAdd(&cnt[ed[k].y >> 8], 1); }
        else rk[k] = -1;
    }
    __syncthreads();
    for (int i = t; i < nb; i += BKT) { int c = cnt[i]; if (c) chunk[i] = atomicAdd(&cur[i], c); }
    __syncthreads();
#pragma unroll
    for (int k = 0; k < EPT; ++k)
        if (rk[k] >= 0) ebuf[chunk[ed[k].y >> 8] + rk[k]] = ed[k];
}

__global__ __launch_bounds__(512) void k_final(
    const int2* __restrict__ ebuf, const int* __restrict__ base_,
    int* __restrict__ rs, int* __restrict__ srcs, int ndst, int etot, int nb)
{
    __shared__ int h[256];
    __shared__ int sc[256];
    int b = blockIdx.x, t = threadIdx.x;
    int base = base_[b];
    int cnt  = base_[b+1] - base;
    int d0 = b << 8;
    if (t < 256) h[t] = 0;
    __syncthreads();
    for (int i = t; i < cnt; i += 512) atomicAdd(&h[ebuf[base+i].y - d0], 1);
    __syncthreads();
    int v = (t < 256) ? h[t] : 0;
    if (t < 256) sc[t] = v;
    __syncthreads();
    for (int o = 1; o < 256; o <<= 1) {
        int a = (t < 256 && t >= o) ? sc[t-o] : 0;
        __syncthreads();
        if (t < 256) sc[t] += a;
        __syncthreads();
    }
    if (t < 256) {
        int gpos = base + sc[t] - v;
        if (d0 + t < ndst) rs[d0+t] = gpos;
        h[t] = gpos;
    }
    if (b == nb-1 && t == 0) rs[ndst] = etot;
    __syncthreads();
    for (int i = t; i < cnt; i += 512) {
        int2 ed = ebuf[base+i];
        int pos = atomicAdd(&h[ed.y - d0], 1);
        srcs[pos] = ed.x;
    }
}

// ================= VALU kernels =================

__global__ __launch_bounds__(256, 2) void k_feat_q(
    const float* __restrict__ feat, const float* __restrict__ pts,
    const float* __restrict__ ctr, const int* __restrict__ lab,
    const float* __restrict__ Wfe, const float* __restrict__ bfe,
    const float* __restrict__ Wh, const float* __restrict__ bh,
    const float* __restrict__ Wf, const float* __restrict__ bf,
    float* __restrict__ rel, float* __restrict__ x1, float* __restrict__ q, int n)
{
    int lane = threadIdx.x & 63;
    int wid  = blockIdx.x * (blockDim.x >> 6) + (threadIdx.x >> 6);
    int nw   = gridDim.x * (blockDim.x >> 6);
    float fe0 = Wfe[0*64+lane], fe1 = Wfe[1*64+lane], fe2 = Wfe[2*64+lane], fe3 = Wfe[3*64+lane];
    float fe4 = Wfe[4*64+lane], fe5 = Wfe[5*64+lane], fe6 = Wfe[6*64+lane];
    float bfe_l = bfe[lane];
    float w0 = Wf[0*64+lane], w1 = Wf[1*64+lane], w2 = Wf[2*64+lane];
    float bfl = bf[lane];
    float wh0 = Wh[lane*3+0], wh1 = Wh[lane*3+1], wh2 = Wh[lane*3+2];
    float bh0 = bh[0], bh1 = bh[1], bh2 = bh[2];
    for (int i0 = wid*2; i0 < n; i0 += nw*2) {
        int iA = __builtin_amdgcn_readfirstlane(i0);
        int iB = iA + 1;
        int lA = lab[iA], lB = lab[iB];
        float pA0 = pts[iA*3+0], pA1 = pts[iA*3+1], pA2 = pts[iA*3+2];
        float pB0 = pts[iB*3+0], pB1 = pts[iB*3+1], pB2 = pts[iB*3+2];
        float rA0 = pA0 - ctr[lA*3+0], rA1 = pA1 - ctr[lA*3+1], rA2 = pA2 - ctr[lA*3+2];
        float rB0 = pB0 - ctr[lB*3+0], rB1 = pB1 - ctr[lB*3+1], rB2 = pB2 - ctr[lB*3+2];
        if (lane == 0)      { rel[iA*3+0]=rA0; rel[iA*3+1]=rA1; rel[iA*3+2]=rA2; }
        else if (lane == 1) { rel[iB*3+0]=rB0; rel[iB*3+1]=rB1; rel[iB*3+2]=rB2; }
        float aA = bfe_l, aB = bfe_l;
        aA = fmaf(feat[iA*4+0], fe0, aA); aB = fmaf(feat[iB*4+0], fe0, aB);
        aA = fmaf(feat[iA*4+1], fe1, aA); aB = fmaf(feat[iB*4+1], fe1, aB);
        aA = fmaf(feat[iA*4+2], fe2, aA); aB = fmaf(feat[iB*4+2], fe2, aB);
        aA = fmaf(feat[iA*4+3], fe3, aA); aB = fmaf(feat[iB*4+3], fe3, aB);
        aA = fmaf(rA0, fe4, aA); aB = fmaf(rB0, fe4, aB);
        aA = fmaf(rA1, fe5, aA); aB = fmaf(rB1, fe5, aB);
        aA = fmaf(rA2, fe6, aA); aB = fmaf(rB2, fe6, aB);
        float xvA = fmaxf(aA, 0.f), xvB = fmaxf(aB, 0.f);
        x1[(size_t)iA*64+lane] = xvA;
        x1[(size_t)iB*64+lane] = xvB;
        float d0A = xvA*wh0, d1A = xvA*wh1, d2A = xvA*wh2;
        float d0B = xvB*wh0, d1B = xvB*wh1, d2B = xvB*wh2;
#pragma unroll
        for (int o = 32; o; o >>= 1) {
            d0A += __shfl_xor(d0A,o); d1A += __shfl_xor(d1A,o); d2A += __shfl_xor(d2A,o);
            d0B += __shfl_xor(d0B,o); d1B += __shfl_xor(d1B,o); d2B += __shfl_xor(d2B,o);
        }
        d0A = tanhf(d0A+bh0); d1A = tanhf(d1A+bh1); d2A = tanhf(d2A+bh2);
        d0B = tanhf(d0B+bh0); d1B = tanhf(d1B+bh1); d2B = tanhf(d2B+bh2);
        q[(size_t)iA*64+lane] = (d0A-pA0)*w0 + (d1A-pA1)*w1 + (d2A-pA2)*w2 + bfl;
        q[(size_t)iB*64+lane] = (d0B-pB0)*w0 + (d1B-pB1)*w1 + (d2B-pB2)*w2 + bfl;
    }
}

// CSR gather-max fused relu(max+q); 2 dests/wave, 8-deep each (16 outstanding).
__global__ __launch_bounds__(256) void k_seg_max_gnn(
    const int* __restrict__ rs, const int* __restrict__ srcs,
    const float* __restrict__ p, float* __restrict__ q, int n)
{
    int lane = threadIdx.x & 63;
    int wid  = blockIdx.x * (blockDim.x >> 6) + (threadIdx.x >> 6);
    int nw   = gridDim.x * (blockDim.x >> 6);
    for (int d0 = wid*2; d0 < n; d0 += nw*2) {
        int dA = __builtin_amdgcn_readfirstlane(d0);
        int begA = rs[dA], endA = rs[dA+1], endB = rs[dA+2];
        int ca = begA, cb = endA;
        float aA[8], aB[8];
#pragma unroll
        for (int u = 0; u < 8; ++u) { aA[u] = -1e30f; aB[u] = -1e30f; }
        while (ca+8 <= endA && cb+8 <= endB) {
            int sA[8], sB[8];
#pragma unroll
            for (int u = 0; u < 8; ++u) { sA[u] = srcs[ca+u]; sB[u] = srcs[cb+u]; }
#pragma unroll
            for (int u = 0; u < 8; ++u) {
                aA[u] = fmaxf(aA[u], p[(size_t)sA[u]*64+lane]);
                aB[u] = fmaxf(aB[u], p[(size_t)sB[u]*64+lane]);
            }
            ca += 8; cb += 8;
        }
        while (ca+4 <= endA) {
            int s0=srcs[ca], s1=srcs[ca+1], s2=srcs[ca+2], s3=srcs[ca+3];
            aA[0] = fmaxf(aA[0], p[(size_t)s0*64+lane]);
            aA[1] = fmaxf(aA[1], p[(size_t)s1*64+lane]);
            aA[2] = fmaxf(aA[2], p[(size_t)s2*64+lane]);
            aA[3] = fmaxf(aA[3], p[(size_t)s3*64+lane]);
            ca += 4;
        }
        while (cb+4 <= endB) {
            int t0=srcs[cb], t1=srcs[cb+1], t2=srcs[cb+2], t3=srcs[cb+3];
            aB[0] = fmaxf(aB[0], p[(size_t)t0*64+lane]);
            aB[1] = fmaxf(aB[1], p[(size_t)t1*64+lane]);
            aB[2] = fmaxf(aB[2], p[(size_t)t2*64+lane]);
            aB[3] = fmaxf(aB[3], p[(size_t)t3*64+lane]);
            cb += 4;
        }
        while (ca+2 <= endA) {
            int s0=srcs[ca], s1=srcs[ca+1];
            aA[0] = fmaxf(aA[0], p[(size_t)s0*64+lane]);
            aA[1] = fmaxf(aA[1], p[(size_t)s1*64+lane]);
            ca += 2;
        }
        while (cb+2 <= endB) {
            int t0=srcs[cb], t1=srcs[cb+1];
            aB[0] = fmaxf(aB[0], p[(size_t)t0*64+lane]);
            aB[1] = fmaxf(aB[1], p[(size_t)t1*64+lane]);
            cb += 2;
        }
        if (ca < endA) aA[0] = fmaxf(aA[0], p[(size_t)srcs[ca]*64+lane]);
        if (cb < endB) aB[0] = fmaxf(aB[0], p[(size_t)srcs[cb]*64+lane]);
        float accA = fmaxf(fmaxf(fmaxf(aA[0],aA[1]), fmaxf(aA[2],aA[3])),
                           fmaxf(fmaxf(aA[4],aA[5]), fmaxf(aA[6],aA[7])));
        float accB = fmaxf(fmaxf(fmaxf(aB[0],aB[1]), fmaxf(aB[2],aB[3])),
                           fmaxf(fmaxf(aB[4],aB[5]), fmaxf(aB[6],aB[7])));
        size_t oA = (size_t)dA*64 + lane, oB = oA + 64;
        q[oA] = fmaxf(accA + q[oA], 0.f);
        q[oB] = fmaxf(accB + q[oB], 0.f);
    }
}

__global__ __launch_bounds__(256, 2) void k_seglab_pre1(
    const int* __restrict__ rsL, const int* __restrict__ srcsL,
    const float* __restrict__ h, const float* __restrict__ pos,
    const float* __restrict__ Wh, const float* __restrict__ bh,
    const float* __restrict__ Wf, const float* __restrict__ bf,
    float* __restrict__ c, float* __restrict__ pa, float* __restrict__ qa, int m)
{
    int lane = threadIdx.x & 63;
    int wid  = blockIdx.x * (blockDim.x >> 6) + (threadIdx.x >> 6);
    int nw   = gridDim.x * (blockDim.x >> 6);
    REPD(WLOAD, wc, Wf + 3*64)
    float w0 = Wf[0*64+lane], w1 = Wf[1*64+lane], w2 = Wf[2*64+lane];
    float bfl = bf[lane];
    float wh0 = Wh[lane*3+0], wh1 = Wh[lane*3+1], wh2 = Wh[lane*3+2];
    float bh0 = bh[0], bh1 = bh[1], bh2 = bh[2];
    for (int d0 = wid*2; d0 < m; d0 += nw*2) {
        int dA = __builtin_amdgcn_readfirstlane(d0);
        int dB = dA + 1;
        int begA = rsL[dA], endA = rsL[dA+1], endB = rsL[dA+2];
        int ca = begA, cb = endA;
        float aA0=-1e30f, aA1=-1e30f, aB0=-1e30f, aB1=-1e30f;
        while (ca+2 <= endA && cb+2 <= endB) {
            int s0=srcsL[ca], s1=srcsL[ca+1], s2=srcsL[cb], s3=srcsL[cb+1];
            aA0 = fmaxf(aA0, h[(size_t)s0*64+lane]);
            aA1 = fmaxf(aA1, h[(size_t)s1*64+lane]);
            aB0 = fmaxf(aB0, h[(size_t)s2*64+lane]);
            aB1 = fmaxf(aB1, h[(size_t)s3*64+lane]);
            ca += 2; cb += 2;
        }
        while (ca+2 <= endA) {
            int s0=srcsL[ca], s1=srcsL[ca+1];
            aA0 = fmaxf(aA0, h[(size_t)s0*64+lane]);
            aA1 = fmaxf(aA1, h[(size_t)s1*64+lane]);
            ca += 2;
        }
        while (cb+2 <= endB) {
            int s2=srcsL[cb], s3=srcsL[cb+1];
            aB0 = fmaxf(aB0, h[(size_t)s2*64+lane]);
            aB1 = fmaxf(aB1, h[(size_t)s3*64+lane]);
            cb += 2;
        }
        if (ca < endA) aA0 = fmaxf(aA0, h[(size_t)srcsL[ca]*64+lane]);
        if (cb < endB) aB0 = fmaxf(aB0, h[(size_t)srcsL[cb]*64+lane]);
        float cvA = fmaxf(fmaxf(aA0,aA1), 0.f);
        float cvB = fmaxf(fmaxf(aB0,aB1), 0.f);
        c[(size_t)dA*64+lane] = cvA;
        c[(size_t)dB*64+lane] = cvB;
        float d0A = cvA*wh0, d1A = cvA*wh1, d2A = cvA*wh2;
        float d0B = cvB*wh0, d1B = cvB*wh1, d2B = cvB*wh2;
#pragma unroll
        for (int o = 32; o; o >>= 1) {
            d0A += __shfl_xor(d0A,o); d1A += __shfl_xor(d1A,o); d2A += __shfl_xor(d2A,o);
            d0B += __shfl_xor(d0B,o); d1B += __shfl_xor(d1B,o); d2B += __shfl_xor(d2B,o);
        }
        d0A = tanhf(d0A+bh0); d1A = tanhf(d1A+bh1); d2A = tanhf(d2A+bh2);
        d0B = tanhf(d0B+bh0); d1B = tanhf(d1B+bh1); d2B = tanhf(d2B+bh2);
        float pA0 = pos[dA*3+0], pA1 = pos[dA*3+1], pA2 = pos[dA*3+2];
        float pB0 = pos[dB*3+0], pB1 = pos[dB*3+1], pB2 = pos[dB*3+2];
        float s0A=0.f, s1A=0.f, s0B=0.f, s1B=0.f;
        REPP(WFMA, wc, cvA, s0A, s1A)
        REPP(WFMA, wc, cvB, s0B, s1B)
        pa[(size_t)dA*64+lane] = s0A+s1A + pA0*w0 + pA1*w1 + pA2*w2;
        pa[(size_t)dB*64+lane] = s0B+s1B + pB0*w0 + pB1*w1 + pB2*w2;
        qa[(size_t)dA*64+lane] = (d0A-pA0)*w0 + (d1A-pA1)*w1 + (d2A-pA2)*w2 + bfl;
        qa[(size_t)dB*64+lane] = (d0B-pB0)*w0 + (d1B-pB1)*w1 + (d2B-pB2)*w2 + bfl;
    }
}

__global__ __launch_bounds__(256, 2) void k_gnn_post(
    const float* __restrict__ agg, const float* __restrict__ Wg,
    const float* __restrict__ bg, const float* __restrict__ xres,
    float* __restrict__ out, int n)
{
    int lane = threadIdx.x & 63;
    int wid  = blockIdx.x * (blockDim.x >> 6) + (threadIdx.x >> 6);
    int nw   = gridDim.x * (blockDim.x >> 6);
    REPD(WLOAD, wg, Wg)
    float bgl = bg[lane];
    for (int i0 = wid*2; i0 < n; i0 += nw*2) {
        int iA = __builtin_amdgcn_readfirstlane(i0);
        size_t oA = (size_t)iA*64 + lane, oB = oA + 64;
        float avA = agg[oA], avB = agg[oB];
        float s0A=0.f, s1A=0.f, s0B=0.f, s1B=0.f;
        REPP(WFMA, wg, avA, s0A, s1A)
        REPP(WFMA, wg, avB, s0B, s1B)
        out[oA] = fmaxf(s0A+s1A + bgl, 0.f) + xres[oA];
        out[oB] = fmaxf(s0B+s1B + bgl, 0.f) + xres[oB];
    }
}

// ---------------- launch ----------------

extern "C" void kernel_launch(void* const* d_in, const int* in_sizes, int n_in,
                              void* d_out, int out_size, void* d_ws, size_t ws_size,
                              hipStream_t stream)
{
    const int N = 100000, M = 10000, E0 = 1600000, E1 = 320000;
    const int NB0 = (N + 255) / 256;
    const int NB1 = (M + 255) / 256;
    const int NBL = (M + 255) / 256;

    const float* feat = (const float*)d_in[0];
    const float* pts  = (const float*)d_in[1];
    const float* ctr  = (const float*)d_in[2];
    const int*   lab  = (const int*)d_in[3];
    const int2*  e0   = (const int2*)d_in[4];
    const int2*  e1   = (const int2*)d_in[5];
    const float* feW  = (const float*)d_in[6];
    const float* feb  = (const float*)d_in[7];
    const float* Wh   = (const float*)d_in[8];
    const float* bh   = (const float*)d_in[9];
    const float* Wf   = (const float*)d_in[10];
    const float* bf   = (const float*)d_in[11];
    const float* Wg   = (const float*)d_in[12];
    const float* bg   = (const float*)d_in[13];
    const float* m2lW = (const float*)d_in[14];
    const float* m2lb = (const float*)d_in[15];
    const float* l2mW = (const float*)d_in[16];
    const float* l2mb = (const float*)d_in[17];
    const float* cW1  = (const float*)d_in[18];
    const float* cb1  = (const float*)d_in[19];
    const float* cW2  = (const float*)d_in[20];
    const float* cb2  = (const float*)d_in[21];
    float* out = (float*)d_out;

    char* ws = (char*)d_ws;
    size_t off = 0;
    auto alloc = [&](size_t bytes) -> char* {
        char* r = ws + off; off += (bytes + 255) & ~(size_t)255; return r;
    };
    float* rel   = (float*)alloc((size_t)N*3*4);
    float* x1    = (float*)alloc((size_t)N*64*4);   // x1, later x5
    float* x2    = (float*)alloc((size_t)N*64*4);   // hosts ebufs pre-compute
    float* p     = (float*)alloc((size_t)N*64*4);   // p0/h/p2
    float* q     = (float*)alloc((size_t)N*64*4);   // q/agg
    float* c     = (float*)alloc((size_t)M*64*4);
    float* c4    = (float*)alloc((size_t)M*64*4);
    int* rs0     = (int*)alloc((size_t)(N+2)*4);
    int* srcs0   = (int*)alloc((size_t)E0*4);
    int* rs1     = (int*)alloc((size_t)(M+2)*4);
    int* srcs1   = (int*)alloc((size_t)E1*4);
    int* rsL     = (int*)alloc((size_t)(M+2)*4);
    int* srcsL   = (int*)alloc((size_t)N*4);
    int* cnt0    = (int*)alloc((size_t)NB0*4);
    int* cnt1    = (int*)alloc((size_t)NB1*4);
    int* cntL    = (int*)alloc((size_t)NBL*4);
    int* base0   = (int*)alloc((size_t)(NB0+1)*4);
    int* base1   = (int*)alloc((size_t)(NB1+1)*4);
    int* baseL   = (int*)alloc((size_t)(NBL+1)*4);
    int* cur0    = (int*)alloc((size_t)NB0*4);
    int* cur1    = (int*)alloc((size_t)NB1*4);
    int* curL    = (int*)alloc((size_t)NBL*4);
    unsigned short* pWf0  = (unsigned short*)alloc(8192*2);
    unsigned short* pWg0  = (unsigned short*)alloc(8192*2);
    unsigned short* pWm   = (unsigned short*)alloc(8192*2);
    unsigned short* pWl2m = (unsigned short*)alloc(8192*2);
    unsigned short* pWf2  = (unsigned short*)alloc(8192*2);
    unsigned short* pWg2  = (unsigned short*)alloc(8192*2);
    unsigned short* pW1   = (unsigned short*)alloc(8192*2);
    (void)ws_size; (void)in_sizes; (void)n_in; (void)out_size;

    int2* ebuf0 = (int2*)x2;
    int2* ebuf1 = ebuf0 + E0;
    int2* ebufL = ebuf1 + E1;

    dim3 blk(256);
    const int gridN = 2048, gridM = 640, gSeg = 3072;
    const int NT = N / 16;
    const int gG = (NT + 3) / 4;

    // ---- weight prepack ----
    k_packB7<<<7, blk, 0, stream>>>(
        Wf + 0*67*64 + 3*64, pWf0,
        Wg + 0*64*64,        pWg0,
        m2lW,                pWm,
        l2mW,                pWl2m,
        Wf + 2*67*64 + 3*64, pWf2,
        Wg + 2*64*64,        pWg2,
        cW1,                 pW1);

    // ---- CSR builds ----
    hipMemsetAsync(cnt0, 0, (size_t)NB0*4, stream);
    hipMemsetAsync(cnt1, 0, (size_t)NB1*4, stream);
    hipMemsetAsync(cntL, 0, (size_t)NBL*4, stream);
    k_bhist_e<<<1024, blk, 0, stream>>>(e0, cnt0, E0, NB0);
    k_bhist_e<<<512,  blk, 0, stream>>>(e1, cnt1, E1, NB1);
    k_bhist_l<<<512,  blk, 0, stream>>>(lab, cntL, N, NBL);
    k_bscan3<<<3, 512, 0, stream>>>(cnt0, base0, cur0, NB0, E0,
                                    cnt1, base1, cur1, NB1, E1,
                                    cntL, baseL, curL, NBL, N);
    k_bucket_e<<<(E0 + BKT*EPT - 1)/(BKT*EPT), BKT, 0, stream>>>(e0, cur0, ebuf0, E0, NB0);
    k_bucket_e<<<(E1 + BKT*EPT - 1)/(BKT*EPT), BKT, 0, stream>>>(e1, cur1, ebuf1, E1, NB1);
    k_bucket_l<<<(N  + BKT*EPT - 1)/(BKT*EPT), BKT, 0, stream>>>(lab, curL, ebufL, N, NBL);
    k_final<<<NB0, 512, 0, stream>>>(ebuf0, base0, rs0, srcs0, N, E0, NB0);
    k_final<<<NB1, 512, 0, stream>>>(ebuf1, base1, rs1, srcs1, M, E1, NB1);
    k_final<<<NBL, 512, 0, stream>>>(ebufL, baseL, rsL, srcsL, M, N, NBL);

    // ---- layer 0 ----
    k_feat_q<<<gridN, blk, 0, stream>>>(feat, pts, ctr, lab, feW, feb,
                                        Wh+0*64*3, bh+0*3, Wf+0*67*64, bf+0*64,
                                        rel, x1, q, N);
    k_gemm<2><<<gG, blk, 0, stream>>>(x1, pWf0, nullptr, nullptr, nullptr,
                                      pts, Wf+0*67*64, nullptr, p, NT);
    k_seg_max_gnn<<<gSeg, blk, 0, stream>>>(rs0, srcs0, p, q, N);
    k_post_m2l_g<<<gG, blk, 0, stream>>>(q, pWg0, bg+0*64, x1,
                                         pWm, m2lb, m2lW+64*64, rel,
                                         x2, p, NT);

    // ---- layer 1 (clusters, VALU) ----
    float* p1 = q;
    float* q1 = q + (size_t)M*64;
    k_seglab_pre1<<<gridM, blk, 0, stream>>>(rsL, srcsL, p, ctr,
                                             Wh+1*64*3, bh+1*3, Wf+1*67*64, bf+1*64,
                                             c, p1, q1, M);
    k_seg_max_gnn<<<640, blk, 0, stream>>>(rs1, srcs1, p1, q1, M);
    k_gnn_post<<<gridM, blk, 0, stream>>>(q1, Wg+1*64*64, bg+1*64, c, c4, M);

    // ---- l2m (+q fold) + layer 2 + classifier ----
    k_l2m_pre2_g<<<gG, blk, 0, stream>>>(c4, lab, pWl2m, l2mb, l2mW+64*64, rel,
                                         pWf2, Wf+2*67*64, pts,
                                         Wh+2*64*3, bh+2*3, bf+2*64,
                                         x1, p, q, NT);                     // x5 -> x1
    k_seg_max_gnn<<<gSeg, blk, 0, stream>>>(rs0, srcs0, p, q, N);
    k_gemm_final<<<gG, blk, 0, stream>>>(q, pWg2, bg+2*64, x1, x2,
                                         pW1, cb1, cW2, cb2, out, NT);
}

// Round 13
// 333.433 us; speedup vs baseline: 1.7905x; 1.1702x over previous
//
#include <hip/hip_runtime.h>

// ---------------- helpers ----------------

__device__ __forceinline__ float bcast(float v, int l) {
    return __int_as_float(__builtin_amdgcn_readlane(__float_as_int(v), l));
}

// 64 NAMED weight scalars (M-sized VALU kernels)
#define REPD(M,P,B) \
 M(0,P,B)  M(1,P,B)  M(2,P,B)  M(3,P,B)  M(4,P,B)  M(5,P,B)  M(6,P,B)  M(7,P,B) \
 M(8,P,B)  M(9,P,B)  M(10,P,B) M(11,P,B) M(12,P,B) M(13,P,B) M(14,P,B) M(15,P,B) \
 M(16,P,B) M(17,P,B) M(18,P,B) M(19,P,B) M(20,P,B) M(21,P,B) M(22,P,B) M(23,P,B) \
 M(24,P,B) M(25,P,B) M(26,P,B) M(27,P,B) M(28,P,B) M(29,P,B) M(30,P,B) M(31,P,B) \
 M(32,P,B) M(33,P,B) M(34,P,B) M(35,P,B) M(36,P,B) M(37,P,B) M(38,P,B) M(39,P,B) \
 M(40,P,B) M(41,P,B) M(42,P,B) M(43,P,B) M(44,P,B) M(45,P,B) M(46,P,B) M(47,P,B) \
 M(48,P,B) M(49,P,B) M(50,P,B) M(51,P,B) M(52,P,B) M(53,P,B) M(54,P,B) M(55,P,B) \
 M(56,P,B) M(57,P,B) M(58,P,B) M(59,P,B) M(60,P,B) M(61,P,B) M(62,P,B) M(63,P,B)

#define WLOAD(J,P,B) float P##J = (B)[(J)*64+lane];

#define REPP(M,P,X,S0,S1) \
 M(0,1,P,X,S0,S1)  M(2,3,P,X,S0,S1)  M(4,5,P,X,S0,S1)  M(6,7,P,X,S0,S1) \
 M(8,9,P,X,S0,S1)  M(10,11,P,X,S0,S1) M(12,13,P,X,S0,S1) M(14,15,P,X,S0,S1) \
 M(16,17,P,X,S0,S1) M(18,19,P,X,S0,S1) M(20,21,P,X,S0,S1) M(22,23,P,X,S0,S1) \
 M(24,25,P,X,S0,S1) M(26,27,P,X,S0,S1) M(28,29,P,X,S0,S1) M(30,31,P,X,S0,S1) \
 M(32,33,P,X,S0,S1) M(34,35,P,X,S0,S1) M(36,37,P,X,S0,S1) M(38,39,P,X,S0,S1) \
 M(40,41,P,X,S0,S1) M(42,43,P,X,S0,S1) M(44,45,P,X,S0,S1) M(46,47,P,X,S0,S1) \
 M(48,49,P,X,S0,S1) M(50,51,P,X,S0,S1) M(52,53,P,X,S0,S1) M(54,55,P,X,S0,S1) \
 M(56,57,P,X,S0,S1) M(58,59,P,X,S0,S1) M(60,61,P,X,S0,S1) M(62,63,P,X,S0,S1)

#define WFMA(J,K,P,X,S0,S1) \
 S0 = fmaf(bcast(X,J), P##J, S0); \
 S1 = fmaf(bcast(X,K), P##K, S1);

// ---------------- MFMA split-bf16 machinery ----------------

typedef short bf16x8 __attribute__((ext_vector_type(8)));
typedef float f32x4  __attribute__((ext_vector_type(4)));

__device__ __forceinline__ unsigned short f2bf_rne(float x) {
    unsigned u = __float_as_uint(x);
    unsigned r = u + 0x7FFFu + ((u >> 16) & 1u);
    return (unsigned short)(r >> 16);
}

__device__ __forceinline__ void a_frag(const float* __restrict__ row, int kt, int g4,
                                       bf16x8& ah, bf16x8& al)
{
    const float4 a0 = *(const float4*)(row + kt*32 + g4);
    const float4 a1 = *(const float4*)(row + kt*32 + 16 + g4);
    float v0 = a0.x, v1 = a0.y, v2 = a0.z, v3 = a0.w;
    float v4 = a1.x, v5 = a1.y, v6 = a1.z, v7 = a1.w;
#define CVT1(idx, val) { \
    unsigned short hh = f2bf_rne(val); \
    float lf = (val) - __uint_as_float((unsigned)hh << 16); \
    ah[idx] = (short)hh; al[idx] = (short)f2bf_rne(lf); }
    CVT1(0,v0) CVT1(1,v1) CVT1(2,v2) CVT1(3,v3)
    CVT1(4,v4) CVT1(5,v5) CVT1(6,v6) CVT1(7,v7)
#undef CVT1
}

// 3-MFMA split-bf16 64x64 matmul for one 16-row tile
__device__ __forceinline__ void mm64(const bf16x8& ah0, const bf16x8& al0,
                                     const bf16x8& ah1, const bf16x8& al1,
                                     const unsigned short* __restrict__ pW,
                                     int lane, f32x4 acc[4])
{
#pragma unroll
    for (int nt = 0; nt < 4; ++nt) {
        f32x4 a = {0.f, 0.f, 0.f, 0.f};
#pragma unroll
        for (int kt = 0; kt < 2; ++kt) {
            bf16x8 bh = *(const bf16x8*)(pW + (kt*4+nt)*1024 + lane*8);
            bf16x8 bl = *(const bf16x8*)(pW + (kt*4+nt)*1024 + 512 + lane*8);
            bf16x8 aH = kt ? ah1 : ah0;
            bf16x8 aL = kt ? al1 : al0;
            a = __builtin_amdgcn_mfma_f32_16x16x32_bf16(aH, bh, a, 0, 0, 0);
            a = __builtin_amdgcn_mfma_f32_16x16x32_bf16(aL, bh, a, 0, 0, 0);
            a = __builtin_amdgcn_mfma_f32_16x16x32_bf16(aH, bl, a, 0, 0, 0);
        }
        acc[nt] = a;
    }
}

// Pack 7 64x64 fp32 W into B-fragment order (bf16 hi/lo).
__global__ __launch_bounds__(256) void k_packB7(
    const float* W0, unsigned short* d0, const float* W1, unsigned short* d1,
    const float* W2, unsigned short* d2, const float* W3, unsigned short* d3,
    const float* W4, unsigned short* d4, const float* W5, unsigned short* d5,
    const float* W6, unsigned short* d6)
{
    const float* W; unsigned short* dst;
    switch (blockIdx.x) {
        case 0: W=W0; dst=d0; break;
        case 1: W=W1; dst=d1; break;
        case 2: W=W2; dst=d2; break;
        case 3: W=W3; dst=d3; break;
        case 4: W=W4; dst=d4; break;
        case 5: W=W5; dst=d5; break;
        default: W=W6; dst=d6; break;
    }
    int t = threadIdx.x;
    for (int slot = t; slot < 512; slot += 256) {
        int frag = slot >> 6;
        int lane = slot & 63;
        int kt = frag >> 2, nt = frag & 3;
        int g4 = (lane >> 4) * 4, n = nt*16 + (lane & 15);
        for (int j = 0; j < 8; ++j) {
            int k = kt*32 + (j>>2)*16 + g4 + (j&3);
            float x = W[k*64 + n];
            unsigned short hh = f2bf_rne(x);
            float lf = x - __uint_as_float((unsigned)hh << 16);
            dst[frag*1024 + 0*512 + lane*8 + j] = hh;
            dst[frag*1024 + 1*512 + lane*8 + j] = f2bf_rne(lf);
        }
    }
}

// ================= consolidated bucketed CSR build =================

__global__ __launch_bounds__(256) void k_zero3(
    int* c0, int n0, int* c1, int n1, int* c2, int n2)
{
    int t = threadIdx.x;
    for (int i = t; i < n0; i += 256) c0[i] = 0;
    for (int i = t; i < n1; i += 256) c1[i] = 0;
    for (int i = t; i < n2; i += 256) c2[i] = 0;
}

// grid = 1024 (e0) + 256 (e1) + 256 (lab)
__global__ __launch_bounds__(256) void k_bhist3(
    const int2* __restrict__ e0, int* cnt0, int E0, int nb0,
    const int2* __restrict__ e1, int* cnt1, int E1, int nb1,
    const int* __restrict__ lab, int* cntL, int NN, int nbL)
{
    const int2* e = nullptr; const int* lv = nullptr; int* gcnt; int total; int nb;
    int bloc, nblocks;
    int b = blockIdx.x;
    if (b < 1024)      { e = e0; gcnt = cnt0; total = E0; nb = nb0; bloc = b;        nblocks = 1024; }
    else if (b < 1280) { e = e1; gcnt = cnt1; total = E1; nb = nb1; bloc = b - 1024; nblocks = 256; }
    else               { lv = lab; gcnt = cntL; total = NN; nb = nbL; bloc = b - 1280; nblocks = 256; }
    __shared__ int c[400];
    for (int i = threadIdx.x; i < nb; i += 256) c[i] = 0;
    __syncthreads();
    for (int idx = bloc*256 + threadIdx.x; idx < total; idx += nblocks*256)
        atomicAdd(&c[(lv ? lv[idx] : e[idx].y) >> 8], 1);
    __syncthreads();
    for (int i = threadIdx.x; i < nb; i += 256) if (c[i]) atomicAdd(&gcnt[i], c[i]);
}

__global__ __launch_bounds__(512) void k_bscan3(
    const int* c0, int* b0, int* u0, int nb0, int t0,
    const int* c1, int* b1, int* u1, int nb1, int t1,
    const int* c2, int* b2, int* u2, int nb2, int t2)
{
    const int* cnt; int* base; int* cur; int nb; int tot;
    if (blockIdx.x == 0) { cnt=c0; base=b0; cur=u0; nb=nb0; tot=t0; }
    else if (blockIdx.x == 1) { cnt=c1; base=b1; cur=u1; nb=nb1; tot=t1; }
    else { cnt=c2; base=b2; cur=u2; nb=nb2; tot=t2; }
    __shared__ int sc[512];
    int t = threadIdx.x;
    int v = (t < nb) ? cnt[t] : 0;
    sc[t] = v; __syncthreads();
    for (int o = 1; o < 512; o <<= 1) {
        int a = (t >= o) ? sc[t-o] : 0;
        __syncthreads();
        sc[t] += a;
        __syncthreads();
    }
    if (t < nb) { int ex = sc[t] - v; base[t] = ex; cur[t] = ex; }
    if (t == nb) base[nb] = tot;
}

#define BKT 512
#define EPT 8
#define EPB (BKT*EPT)
// grid = GB0 + GB1 + GBL
__global__ __launch_bounds__(BKT) void k_bucket3(
    const int2* __restrict__ e0, int* cur0, int2* eb0, int E0, int nb0, int GB0,
    const int2* __restrict__ e1, int* cur1, int2* eb1, int E1, int nb1, int GB1,
    const int* __restrict__ lab, int* curL, int2* ebL, int NN, int nbL)
{
    const int2* e = nullptr; const int* lv = nullptr; int* cur; int2* ebuf;
    int total; int nb; int bloc;
    int b = blockIdx.x;
    if (b < GB0)            { e = e0; cur = cur0; ebuf = eb0; total = E0; nb = nb0; bloc = b; }
    else if (b < GB0 + GB1) { e = e1; cur = cur1; ebuf = eb1; total = E1; nb = nb1; bloc = b - GB0; }
    else                    { lv = lab; cur = curL; ebuf = ebL; total = NN; nb = nbL; bloc = b - GB0 - GB1; }
    __shared__ int cnt[400];
    __shared__ int chunk[400];
    int t = threadIdx.x;
    int base = bloc * EPB;
    for (int i = t; i < nb; i += BKT) cnt[i] = 0;
    __syncthreads();
    int2 ed[EPT]; int rk[EPT];
#pragma unroll
    for (int k = 0; k < EPT; ++k) {
        int idx = base + k*BKT + t;
        if (idx < total) {
            ed[k] = lv ? make_int2(idx, lv[idx]) : e[idx];
            rk[k] = atomicAdd(&cnt[ed[k].y >> 8], 1);
        } else rk[k] = -1;
    }
    __syncthreads();
    for (int i = t; i < nb; i += BKT) { int c = cnt[i]; if (c) chunk[i] = atomicAdd(&cur[i], c); }
    __syncthreads();
#pragma unroll
    for (int k = 0; k < EPT; ++k)
        if (rk[k] >= 0) ebuf[chunk[ed[k].y >> 8] + rk[k]] = ed[k];
}

// grid = NB0 + NB1 + NBL
__global__ __launch_bounds__(512) void k_final3(
    const int2* eb0, const int* base0, int* rs0, int* srcs0, int nd0, int et0, int NB0_,
    const int2* eb1, const int* base1, int* rs1, int* srcs1, int nd1, int et1, int NB1_,
    const int2* ebL, const int* baseL, int* rsL, int* srcsL, int ndL, int etL, int NBL_)
{
    const int2* ebuf; const int* base_; int* rs; int* srcs; int ndst; int etot; int nb; int bloc;
    int b = blockIdx.x;
    if (b < NB0_)              { ebuf=eb0; base_=base0; rs=rs0; srcs=srcs0; ndst=nd0; etot=et0; nb=NB0_; bloc=b; }
    else if (b < NB0_ + NB1_)  { ebuf=eb1; base_=base1; rs=rs1; srcs=srcs1; ndst=nd1; etot=et1; nb=NB1_; bloc=b-NB0_; }
    else                       { ebuf=ebL; base_=baseL; rs=rsL; srcs=srcsL; ndst=ndL; etot=etL; nb=NBL_; bloc=b-NB0_-NB1_; }
    __shared__ int h[256];
    __shared__ int sc[256];
    int t = threadIdx.x;
    int base = base_[bloc];
    int cnt  = base_[bloc+1] - base;
    int d0 = bloc << 8;
    if (t < 256) h[t] = 0;
    __syncthreads();
    for (int i = t; i < cnt; i += 512) atomicAdd(&h[ebuf[base+i].y - d0], 1);
    __syncthreads();
    int v = (t < 256) ? h[t] : 0;
    if (t < 256) sc[t] = v;
    __syncthreads();
    for (int o = 1; o < 256; o <<= 1) {
        int a = (t < 256 && t >= o) ? sc[t-o] : 0;
        __syncthreads();
        if (t < 256) sc[t] += a;
        __syncthreads();
    }
    if (t < 256) {
        int gpos = base + sc[t] - v;
        if (d0 + t < ndst) rs[d0+t] = gpos;
        h[t] = gpos;
    }
    if (bloc == nb-1 && t == 0) rs[ndst] = etot;
    __syncthreads();
    for (int i = t; i < cnt; i += 512) {
        int2 ed = ebuf[base+i];
        int pos = atomicAdd(&h[ed.y - d0], 1);
        srcs[pos] = ed.x;
    }
}

// ================= fused MFMA compute kernels =================

// Fused layer-0 front: rel; x1 = relu([feat,rel]@feW+feb); delta = tanh(x1@Wh+bh);
// p = x1@Wf[3:67] + pts.Wf[0:3]; q = (delta-pts).Wf[0:3] + bf.
__global__ __launch_bounds__(256) void k_feat_pre0_g(
    const float* __restrict__ feat, const float* __restrict__ pts,
    const float* __restrict__ ctr, const int* __restrict__ lab,
    const float* __restrict__ Wfe, const float* __restrict__ bfe,
    const float* __restrict__ Wh, const float* __restrict__ bh,
    const unsigned short* __restrict__ pWf0, const float* __restrict__ Wf0h,
    const float* __restrict__ bf0,
    float* __restrict__ rel, float* __restrict__ x1,
    float* __restrict__ p, float* __restrict__ q, int ntiles)
{
    __shared__ float xp[4][16*68];
    __shared__ float dd[4][64];
    int lane = threadIdx.x & 63;
    int w = threadIdx.x >> 6;
    int tile = blockIdx.x*4 + w;
    if (tile >= ntiles) return;
    int r0 = tile*16;
    int row = lane & 15;
    int cg  = lane >> 4;
    int r = r0 + row;
    int l = lab[r];
    float pr0 = pts[r*3+0], pr1 = pts[r*3+1], pr2 = pts[r*3+2];
    float rv0 = pr0 - ctr[l*3+0], rv1 = pr1 - ctr[l*3+1], rv2 = pr2 - ctr[l*3+2];
    if (cg == 0) { rel[r*3+0]=rv0; rel[r*3+1]=rv1; rel[r*3+2]=rv2; }
    float f0 = feat[r*4+0], f1 = feat[r*4+1], f2 = feat[r*4+2], f3 = feat[r*4+3];
#pragma unroll
    for (int k = 0; k < 16; ++k) {
        int c = cg*16 + k;
        float v = bfe[c];
        v = fmaf(f0, Wfe[0*64+c], v);
        v = fmaf(f1, Wfe[1*64+c], v);
        v = fmaf(f2, Wfe[2*64+c], v);
        v = fmaf(f3, Wfe[3*64+c], v);
        v = fmaf(rv0, Wfe[4*64+c], v);
        v = fmaf(rv1, Wfe[5*64+c], v);
        v = fmaf(rv2, Wfe[6*64+c], v);
        xp[w][row*68 + c] = fmaxf(v, 0.f);
    }
    {
        int j = cg < 3 ? cg : 2;
        float accd = 0.f;
#pragma unroll 16
        for (int k2 = 0; k2 < 64; ++k2)
            accd = fmaf(xp[w][row*68 + k2], Wh[k2*3 + j], accd);
        dd[w][row*4 + cg] = tanhf(accd + bh[j]);
    }
    int g4 = cg * 4;
    const float* lrow = &xp[w][row*68];
    bf16x8 ah0, al0, ah1, al1;
    a_frag(lrow, 0, g4, ah0, al0);
    a_frag(lrow, 1, g4, ah1, al1);
    f32x4 acc[4];
    mm64(ah0, al0, ah1, al1, pWf0, lane, acc);
    int rloc = cg*4;
#pragma unroll
    for (int nt = 0; nt < 4; ++nt) {
        int c = nt*16 + row;
        float w0t = Wf0h[0*64+c], w1t = Wf0h[1*64+c], w2t = Wf0h[2*64+c];
        float bfc = bf0[c];
#pragma unroll
        for (int reg = 0; reg < 4; ++reg) {
            int rr = r0 + rloc + reg;
            int rl = rloc + reg;
            float pp0 = pts[rr*3+0], pp1 = pts[rr*3+1], pp2 = pts[rr*3+2];
            float v = acc[nt][reg] + pp0*w0t + pp1*w1t + pp2*w2t;
            p[(size_t)rr*64 + c] = v;
            x1[(size_t)rr*64 + c] = xp[w][rl*68 + c];
            float d0 = dd[w][rl*4+0], d1 = dd[w][rl*4+1], d2 = dd[w][rl*4+2];
            q[(size_t)rr*64 + c] = (d0-pp0)*w0t + (d1-pp1)*w1t + (d2-pp2)*w2t + bfc;
        }
    }
}

// Fused: x2 = relu(agg@Wg+bg)+x1 (write), h = relu(x2@Wm + rel.Wmt + bm) (write)
__global__ __launch_bounds__(256) void k_post_m2l_g(
    const float* __restrict__ agg, const unsigned short* __restrict__ pWg,
    const float* __restrict__ bg, const float* __restrict__ x1,
    const unsigned short* __restrict__ pWm, const float* __restrict__ bm,
    const float* __restrict__ Wmt, const float* __restrict__ rel,
    float* __restrict__ x2, float* __restrict__ h, int ntiles)
{
    __shared__ float xp[4][16*68];
    int lane = threadIdx.x & 63;
    int w = threadIdx.x >> 6;
    int tile = blockIdx.x*4 + w;
    if (tile >= ntiles) return;
    int r0 = tile*16;
    int g4 = (lane >> 4) * 4;
    int rloc = (lane >> 4) * 4;
    const float* rowp = agg + (size_t)(r0 + (lane & 15)) * 64;
    bf16x8 ah0, al0, ah1, al1;
    a_frag(rowp, 0, g4, ah0, al0);
    a_frag(rowp, 1, g4, ah1, al1);
    f32x4 acc[4];
    mm64(ah0, al0, ah1, al1, pWg, lane, acc);
#pragma unroll
    for (int nt = 0; nt < 4; ++nt) {
        int c = nt*16 + (lane & 15);
        float bc = bg[c];
#pragma unroll
        for (int reg = 0; reg < 4; ++reg) {
            int r = r0 + rloc + reg;
            float v = fmaxf(acc[nt][reg] + bc, 0.f) + x1[(size_t)r*64 + c];
            x2[(size_t)r*64 + c] = v;
            xp[w][(rloc+reg)*68 + c] = v;
        }
    }
    const float* lrow = &xp[w][(lane & 15)*68];
    a_frag(lrow, 0, g4, ah0, al0);
    a_frag(lrow, 1, g4, ah1, al1);
    mm64(ah0, al0, ah1, al1, pWm, lane, acc);
#pragma unroll
    for (int nt = 0; nt < 4; ++nt) {
        int c = nt*16 + (lane & 15);
        float bc = bm[c];
        float w0t = Wmt[0*64+c], w1t = Wmt[1*64+c], w2t = Wmt[2*64+c];
#pragma unroll
        for (int reg = 0; reg < 4; ++reg) {
            int r = r0 + rloc + reg;
            float v = acc[nt][reg] + bc + rel[r*3+0]*w0t + rel[r*3+1]*w1t + rel[r*3+2]*w2t;
            h[(size_t)r*64 + c] = fmaxf(v, 0.f);
        }
    }
}

// Fused: x5 = relu(c4[lab]@Wl + rel.Wlt + bl); p = x5@Wf2 + pts.Wf2t;
//        q = (tanh(x5@Wh+bh) - pts).Wf2t + bf
__global__ __launch_bounds__(256) void k_l2m_pre2_g(
    const float* __restrict__ c4, const int* __restrict__ lab,
    const unsigned short* __restrict__ pWl, const float* __restrict__ bl,
    const float* __restrict__ Wlt, const float* __restrict__ rel,
    const unsigned short* __restrict__ pWf2, const float* __restrict__ Wf2t,
    const float* __restrict__ pts,
    const float* __restrict__ Wh, const float* __restrict__ bh,
    const float* __restrict__ bf,
    float* __restrict__ x5, float* __restrict__ p, float* __restrict__ q, int ntiles)
{
    __shared__ float xp[4][16*68];
    __shared__ float dd[4][64];
    int lane = threadIdx.x & 63;
    int w = threadIdx.x >> 6;
    int tile = blockIdx.x*4 + w;
    if (tile >= ntiles) return;
    int r0 = tile*16;
    int g4 = (lane >> 4) * 4;
    int rloc = (lane >> 4) * 4;
    int rA = r0 + (lane & 15);
    const float* rowp = c4 + (size_t)lab[rA] * 64;
    bf16x8 ah0, al0, ah1, al1;
    a_frag(rowp, 0, g4, ah0, al0);
    a_frag(rowp, 1, g4, ah1, al1);
    f32x4 acc[4];
    mm64(ah0, al0, ah1, al1, pWl, lane, acc);
#pragma unroll
    for (int nt = 0; nt < 4; ++nt) {
        int c = nt*16 + (lane & 15);
        float bc = bl[c];
        float w0t = Wlt[0*64+c], w1t = Wlt[1*64+c], w2t = Wlt[2*64+c];
#pragma unroll
        for (int reg = 0; reg < 4; ++reg) {
            int r = r0 + rloc + reg;
            float v = acc[nt][reg] + bc + rel[r*3+0]*w0t + rel[r*3+1]*w1t + rel[r*3+2]*w2t;
            v = fmaxf(v, 0.f);
            x5[(size_t)r*64 + c] = v;
            xp[w][(rloc+reg)*68 + c] = v;
        }
    }
    {
        int rowl = lane & 15;
        int jj = lane >> 4;
        int j = jj < 3 ? jj : 2;
        float accd = 0.f;
#pragma unroll 16
        for (int k = 0; k < 64; ++k)
            accd = fmaf(xp[w][rowl*68 + k], Wh[k*3 + j], accd);
        dd[w][rowl*4 + jj] = tanhf(accd + bh[j]);
    }
    const float* lrow = &xp[w][(lane & 15)*68];
    a_frag(lrow, 0, g4, ah0, al0);
    a_frag(lrow, 1, g4, ah1, al1);
    mm64(ah0, al0, ah1, al1, pWf2, lane, acc);
#pragma unroll
    for (int nt = 0; nt < 4; ++nt) {
        int c = nt*16 + (lane & 15);
        float w0t = Wf2t[0*64+c], w1t = Wf2t[1*64+c], w2t = Wf2t[2*64+c];
        float bfc = bf[c];
#pragma unroll
        for (int reg = 0; reg < 4; ++reg) {
            int r = r0 + rloc + reg;
            int rl = rloc + reg;
            float p0 = pts[r*3+0], p1 = pts[r*3+1], p2 = pts[r*3+2];
            float v = acc[nt][reg] + p0*w0t + p1*w1t + p2*w2t;
            p[(size_t)r*64 + c] = v;
            float d0 = dd[w][rl*4+0], d1 = dd[w][rl*4+1], d2 = dd[w][rl*4+2];
            q[(size_t)r*64 + c] = (d0-p0)*w0t + (d1-p1)*w1t + (d2-p2)*w2t + bfc;
        }
    }
}

// Fused final: fin = relu(agg@Wg2+bg2)+x5+x2; t = relu(fin@W1+b1); out = t@W2+b2
__global__ __launch_bounds__(256) void k_gemm_final(
    const float* __restrict__ agg, const unsigned short* __restrict__ pWg2,
    const float* __restrict__ bg2,
    const float* __restrict__ x5, const float* __restrict__ x2,
    const unsigned short* __restrict__ pW1, const float* __restrict__ b1,
    const float* __restrict__ W2, const float* __restrict__ b2,
    float* __restrict__ out, int ntiles)
{
    __shared__ float xp[4][16*68];
    int lane = threadIdx.x & 63;
    int w = threadIdx.x >> 6;
    int tile = blockIdx.x*4 + w;
    if (tile >= ntiles) return;
    int r0 = tile*16;
    int g4 = (lane >> 4) * 4;
    int rloc = (lane >> 4) * 4;
    const float* rowp = agg + (size_t)(r0 + (lane & 15)) * 64;
    bf16x8 ah0, al0, ah1, al1;
    a_frag(rowp, 0, g4, ah0, al0);
    a_frag(rowp, 1, g4, ah1, al1);
    f32x4 acc[4];
    mm64(ah0, al0, ah1, al1, pWg2, lane, acc);
#pragma unroll
    for (int nt = 0; nt < 4; ++nt) {
        int c = nt*16 + (lane & 15);
        float bc = bg2[c];
#pragma unroll
        for (int reg = 0; reg < 4; ++reg) {
            int r = r0 + rloc + reg;
            float v = fmaxf(acc[nt][reg] + bc, 0.f)
                    + x5[(size_t)r*64 + c] + x2[(size_t)r*64 + c];
            xp[w][(rloc+reg)*68 + c] = v;
        }
    }
    const float* lrow = &xp[w][(lane & 15)*68];
    a_frag(lrow, 0, g4, ah0, al0);
    a_frag(lrow, 1, g4, ah1, al1);
    mm64(ah0, al0, ah1, al1, pW1, lane, acc);
    float part0[4] = {0.f,0.f,0.f,0.f};
    float part1[4] = {0.f,0.f,0.f,0.f};
    float part2[4] = {0.f,0.f,0.f,0.f};
    float part3[4] = {0.f,0.f,0.f,0.f};
#pragma unroll
    for (int nt = 0; nt < 4; ++nt) {
        int c = nt*16 + (lane & 15);
        float bc = b1[c];
        float4 w2v = *(const float4*)(W2 + c*4);
#pragma unroll
        for (int reg = 0; reg < 4; ++reg) {
            float t = fmaxf(acc[nt][reg] + bc, 0.f);
            part0[reg] = fmaf(t, w2v.x, part0[reg]);
            part1[reg] = fmaf(t, w2v.y, part1[reg]);
            part2[reg] = fmaf(t, w2v.z, part2[reg]);
            part3[reg] = fmaf(t, w2v.w, part3[reg]);
        }
    }
#pragma unroll
    for (int m = 1; m < 16; m <<= 1) {
#pragma unroll
        for (int reg = 0; reg < 4; ++reg) {
            part0[reg] += __shfl_xor(part0[reg], m);
            part1[reg] += __shfl_xor(part1[reg], m);
            part2[reg] += __shfl_xor(part2[reg], m);
            part3[reg] += __shfl_xor(part3[reg], m);
        }
    }
    if ((lane & 15) == 0) {
        float b20 = b2[0], b21 = b2[1], b22 = b2[2], b23 = b2[3];
#pragma unroll
        for (int reg = 0; reg < 4; ++reg) {
            int r = r0 + rloc + reg;
            *(float4*)(out + (size_t)r*4) =
                make_float4(part0[reg]+b20, part1[reg]+b21, part2[reg]+b22, part3[reg]+b23);
        }
    }
}

// ================= gather/segmax + M-sized VALU kernels =================

// CSR gather-max fused relu(max+q); 2 dests/wave, 8-deep each.
__global__ __launch_bounds__(256) void k_seg_max_gnn(
    const int* __restrict__ rs, const int* __restrict__ srcs,
    const float* __restrict__ p, float* __restrict__ q, int n)
{
    int lane = threadIdx.x & 63;
    int wid  = blockIdx.x * (blockDim.x >> 6) + (threadIdx.x >> 6);
    int nw   = gridDim.x * (blockDim.x >> 6);
    for (int d0 = wid*2; d0 < n; d0 += nw*2) {
        int dA = __builtin_amdgcn_readfirstlane(d0);
        int begA = rs[dA], endA = rs[dA+1], endB = rs[dA+2];
        int ca = begA, cb = endA;
        float aA[8], aB[8];
#pragma unroll
        for (int u = 0; u < 8; ++u) { aA[u] = -1e30f; aB[u] = -1e30f; }
        while (ca+8 <= endA && cb+8 <= endB) {
            int sA[8], sB[8];
#pragma unroll
            for (int u = 0; u < 8; ++u) { sA[u] = srcs[ca+u]; sB[u] = srcs[cb+u]; }
#pragma unroll
            for (int u = 0; u < 8; ++u) {
                aA[u] = fmaxf(aA[u], p[(size_t)sA[u]*64+lane]);
                aB[u] = fmaxf(aB[u], p[(size_t)sB[u]*64+lane]);
            }
            ca += 8; cb += 8;
        }
        while (ca+4 <= endA) {
            int s0=srcs[ca], s1=srcs[ca+1], s2=srcs[ca+2], s3=srcs[ca+3];
            aA[0] = fmaxf(aA[0], p[(size_t)s0*64+lane]);
            aA[1] = fmaxf(aA[1], p[(size_t)s1*64+lane]);
            aA[2] = fmaxf(aA[2], p[(size_t)s2*64+lane]);
            aA[3] = fmaxf(aA[3], p[(size_t)s3*64+lane]);
            ca += 4;
        }
        while (cb+4 <= endB) {
            int t0=srcs[cb], t1=srcs[cb+1], t2=srcs[cb+2], t3=srcs[cb+3];
            aB[0] = fmaxf(aB[0], p[(size_t)t0*64+lane]);
            aB[1] = fmaxf(aB[1], p[(size_t)t1*64+lane]);
            aB[2] = fmaxf(aB[2], p[(size_t)t2*64+lane]);
            aB[3] = fmaxf(aB[3], p[(size_t)t3*64+lane]);
            cb += 4;
        }
        while (ca+2 <= endA) {
            int s0=srcs[ca], s1=srcs[ca+1];
            aA[0] = fmaxf(aA[0], p[(size_t)s0*64+lane]);
            aA[1] = fmaxf(aA[1], p[(size_t)s1*64+lane]);
            ca += 2;
        }
        while (cb+2 <= endB) {
            int t0=srcs[cb], t1=srcs[cb+1];
            aB[0] = fmaxf(aB[0], p[(size_t)t0*64+lane]);
            aB[1] = fmaxf(aB[1], p[(size_t)t1*64+lane]);
            cb += 2;
        }
        if (ca < endA) aA[0] = fmaxf(aA[0], p[(size_t)srcs[ca]*64+lane]);
        if (cb < endB) aB[0] = fmaxf(aB[0], p[(size_t)srcs[cb]*64+lane]);
        float accA = fmaxf(fmaxf(fmaxf(aA[0],aA[1]), fmaxf(aA[2],aA[3])),
                           fmaxf(fmaxf(aA[4],aA[5]), fmaxf(aA[6],aA[7])));
        float accB = fmaxf(fmaxf(fmaxf(aB[0],aB[1]), fmaxf(aB[2],aB[3])),
                           fmaxf(fmaxf(aB[4],aB[5]), fmaxf(aB[6],aB[7])));
        size_t oA = (size_t)dA*64 + lane, oB = oA + 64;
        q[oA] = fmaxf(accA + q[oA], 0.f);
        q[oB] = fmaxf(accB + q[oB], 0.f);
    }
}

__global__ __launch_bounds__(256, 2) void k_seglab_pre1(
    const int* __restrict__ rsL, const int* __restrict__ srcsL,
    const float* __restrict__ h, const float* __restrict__ pos,
    const float* __restrict__ Wh, const float* __restrict__ bh,
    const float* __restrict__ Wf, const float* __restrict__ bf,
    float* __restrict__ c, float* __restrict__ pa, float* __restrict__ qa, int m)
{
    int lane = threadIdx.x & 63;
    int wid  = blockIdx.x * (blockDim.x >> 6) + (threadIdx.x >> 6);
    int nw   = gridDim.x * (blockDim.x >> 6);
    REPD(WLOAD, wc, Wf + 3*64)
    float w0 = Wf[0*64+lane], w1 = Wf[1*64+lane], w2 = Wf[2*64+lane];
    float bfl = bf[lane];
    float wh0 = Wh[lane*3+0], wh1 = Wh[lane*3+1], wh2 = Wh[lane*3+2];
    float bh0 = bh[0], bh1 = bh[1], bh2 = bh[2];
    for (int d0 = wid*2; d0 < m; d0 += nw*2) {
        int dA = __builtin_amdgcn_readfirstlane(d0);
        int dB = dA + 1;
        int begA = rsL[dA], endA = rsL[dA+1], endB = rsL[dA+2];
        int ca = begA, cb = endA;
        float aA0=-1e30f, aA1=-1e30f, aB0=-1e30f, aB1=-1e30f;
        while (ca+2 <= endA && cb+2 <= endB) {
            int s0=srcsL[ca], s1=srcsL[ca+1], s2=srcsL[cb], s3=srcsL[cb+1];
            aA0 = fmaxf(aA0, h[(size_t)s0*64+lane]);
            aA1 = fmaxf(aA1, h[(size_t)s1*64+lane]);
            aB0 = fmaxf(aB0, h[(size_t)s2*64+lane]);
            aB1 = fmaxf(aB1, h[(size_t)s3*64+lane]);
            ca += 2; cb += 2;
        }
        while (ca+2 <= endA) {
            int s0=srcsL[ca], s1=srcsL[ca+1];
            aA0 = fmaxf(aA0, h[(size_t)s0*64+lane]);
            aA1 = fmaxf(aA1, h[(size_t)s1*64+lane]);
            ca += 2;
        }
        while (cb+2 <= endB) {
            int s2=srcsL[cb], s3=srcsL[cb+1];
            aB0 = fmaxf(aB0, h[(size_t)s2*64+lane]);
            aB1 = fmaxf(aB1, h[(size_t)s3*64+lane]);
            cb += 2;
        }
        if (ca < endA) aA0 = fmaxf(aA0, h[(size_t)srcsL[ca]*64+lane]);
        if (cb < endB) aB0 = fmaxf(aB0, h[(size_t)srcsL[cb]*64+lane]);
        float cvA = fmaxf(fmaxf(aA0,aA1), 0.f);
        float cvB = fmaxf(fmaxf(aB0,aB1), 0.f);
        c[(size_t)dA*64+lane] = cvA;
        c[(size_t)dB*64+lane] = cvB;
        float d0A = cvA*wh0, d1A = cvA*wh1, d2A = cvA*wh2;
        float d0B = cvB*wh0, d1B = cvB*wh1, d2B = cvB*wh2;
#pragma unroll
        for (int o = 32; o; o >>= 1) {
            d0A += __shfl_xor(d0A,o); d1A += __shfl_xor(d1A,o); d2A += __shfl_xor(d2A,o);
            d0B += __shfl_xor(d0B,o); d1B += __shfl_xor(d1B,o); d2B += __shfl_xor(d2B,o);
        }
        d0A = tanhf(d0A+bh0); d1A = tanhf(d1A+bh1); d2A = tanhf(d2A+bh2);
        d0B = tanhf(d0B+bh0); d1B = tanhf(d1B+bh1); d2B = tanhf(d2B+bh2);
        float pA0 = pos[dA*3+0], pA1 = pos[dA*3+1], pA2 = pos[dA*3+2];
        float pB0 = pos[dB*3+0], pB1 = pos[dB*3+1], pB2 = pos[dB*3+2];
        float s0A=0.f, s1A=0.f, s0B=0.f, s1B=0.f;
        REPP(WFMA, wc, cvA, s0A, s1A)
        REPP(WFMA, wc, cvB, s0B, s1B)
        pa[(size_t)dA*64+lane] = s0A+s1A + pA0*w0 + pA1*w1 + pA2*w2;
        pa[(size_t)dB*64+lane] = s0B+s1B + pB0*w0 + pB1*w1 + pB2*w2;
        qa[(size_t)dA*64+lane] = (d0A-pA0)*w0 + (d1A-pA1)*w1 + (d2A-pA2)*w2 + bfl;
        qa[(size_t)dB*64+lane] = (d0B-pB0)*w0 + (d1B-pB1)*w1 + (d2B-pB2)*w2 + bfl;
    }
}

__global__ __launch_bounds__(256, 2) void k_gnn_post(
    const float* __restrict__ agg, const float* __restrict__ Wg,
    const float* __restrict__ bg, const float* __restrict__ xres,
    float* __restrict__ out, int n)
{
    int lane = threadIdx.x & 63;
    int wid  = blockIdx.x * (blockDim.x >> 6) + (threadIdx.x >> 6);
    int nw   = gridDim.x * (blockDim.x >> 6);
    REPD(WLOAD, wg, Wg)
    float bgl = bg[lane];
    for (int i0 = wid*2; i0 < n; i0 += nw*2) {
        int iA = __builtin_amdgcn_readfirstlane(i0);
        size_t oA = (size_t)iA*64 + lane, oB = oA + 64;
        float avA = agg[oA], avB = agg[oB];
        float s0A=0.f, s1A=0.f, s0B=0.f, s1B=0.f;
        REPP(WFMA, wg, avA, s0A, s1A)
        REPP(WFMA, wg, avB, s0B, s1B)
        out[oA] = fmaxf(s0A+s1A + bgl, 0.f) + xres[oA];
        out[oB] = fmaxf(s0B+s1B + bgl, 0.f) + xres[oB];
    }
}

// ---------------- launch ----------------

extern "C" void kernel_launch(void* const* d_in, const int* in_sizes, int n_in,
                              void* d_out, int out_size, void* d_ws, size_t ws_size,
                              hipStream_t stream)
{
    const int N = 100000, M = 10000, E0 = 1600000, E1 = 320000;
    const int NB0 = (N + 255) / 256;   // 391
    const int NB1 = (M + 255) / 256;   // 40
    const int NBL = (M + 255) / 256;   // 40
    const int GB0 = (E0 + EPB - 1) / EPB;  // 391
    const int GB1 = (E1 + EPB - 1) / EPB;  // 79
    const int GBL = (N + EPB - 1) / EPB;   // 25

    const float* feat = (const float*)d_in[0];
    const float* pts  = (const float*)d_in[1];
    const float* ctr  = (const float*)d_in[2];
    const int*   lab  = (const int*)d_in[3];
    const int2*  e0   = (const int2*)d_in[4];
    const int2*  e1   = (const int2*)d_in[5];
    const float* feW  = (const float*)d_in[6];
    const float* feb  = (const float*)d_in[7];
    const float* Wh   = (const float*)d_in[8];
    const float* bh   = (const float*)d_in[9];
    const float* Wf   = (const float*)d_in[10];
    const float* bf   = (const float*)d_in[11];
    const float* Wg   = (const float*)d_in[12];
    const float* bg   = (const float*)d_in[13];
    const float* m2lW = (const float*)d_in[14];
    const float* m2lb = (const float*)d_in[15];
    const float* l2mW = (const float*)d_in[16];
    const float* l2mb = (const float*)d_in[17];
    const float* cW1  = (const float*)d_in[18];
    const float* cb1  = (const float*)d_in[19];
    const float* cW2  = (const float*)d_in[20];
    const float* cb2  = (const float*)d_in[21];
    float* out = (float*)d_out;

    char* ws = (char*)d_ws;
    size_t off = 0;
    auto alloc = [&](size_t bytes) -> char* {
        char* r = ws + off; off += (bytes + 255) & ~(size_t)255; return r;
    };
    float* rel   = (float*)alloc((size_t)N*3*4);
    float* x1    = (float*)alloc((size_t)N*64*4);   // x1, later x5
    float* x2    = (float*)alloc((size_t)N*64*4);   // hosts ebufs pre-compute
    float* p     = (float*)alloc((size_t)N*64*4);   // p0/h/p2
    float* q     = (float*)alloc((size_t)N*64*4);   // q/agg
    float* c     = (float*)alloc((size_t)M*64*4);
    float* c4    = (float*)alloc((size_t)M*64*4);
    int* rs0     = (int*)alloc((size_t)(N+2)*4);
    int* srcs0   = (int*)alloc((size_t)E0*4);
    int* rs1     = (int*)alloc((size_t)(M+2)*4);
    int* srcs1   = (int*)alloc((size_t)E1*4);
    int* rsL     = (int*)alloc((size_t)(M+2)*4);
    int* srcsL   = (int*)alloc((size_t)N*4);
    int* cnt0    = (int*)alloc((size_t)NB0*4);
    int* cnt1    = (int*)alloc((size_t)NB1*4);
    int* cntL    = (int*)alloc((size_t)NBL*4);
    int* base0   = (int*)alloc((size_t)(NB0+1)*4);
    int* base1   = (int*)alloc((size_t)(NB1+1)*4);
    int* baseL   = (int*)alloc((size_t)(NBL+1)*4);
    int* cur0    = (int*)alloc((size_t)NB0*4);
    int* cur1    = (int*)alloc((size_t)NB1*4);
    int* curL    = (int*)alloc((size_t)NBL*4);
    unsigned short* pWf0  = (unsigned short*)alloc(8192*2);
    unsigned short* pWg0  = (unsigned short*)alloc(8192*2);
    unsigned short* pWm   = (unsigned short*)alloc(8192*2);
    unsigned short* pWl2m = (unsigned short*)alloc(8192*2);
    unsigned short* pWf2  = (unsigned short*)alloc(8192*2);
    unsigned short* pWg2  = (unsigned short*)alloc(8192*2);
    unsigned short* pW1   = (unsigned short*)alloc(8192*2);
    (void)ws_size; (void)in_sizes; (void)n_in; (void)out_size;

    int2* ebuf0 = (int2*)x2;
    int2* ebuf1 = ebuf0 + E0;
    int2* ebufL = ebuf1 + E1;

    dim3 blk(256);
    const int gridM = 640, gSeg = 3072;
    const int NT = N / 16;
    const int gG = (NT + 3) / 4;

    // ---- weight prepack ----
    k_packB7<<<7, blk, 0, stream>>>(
        Wf + 0*67*64 + 3*64, pWf0,
        Wg + 0*64*64,        pWg0,
        m2lW,                pWm,
        l2mW,                pWl2m,
        Wf + 2*67*64 + 3*64, pWf2,
        Wg + 2*64*64,        pWg2,
        cW1,                 pW1);

    // ---- CSR builds (consolidated) ----
    k_zero3<<<1, blk, 0, stream>>>(cnt0, NB0, cnt1, NB1, cntL, NBL);
    k_bhist3<<<1536, blk, 0, stream>>>(e0, cnt0, E0, NB0,
                                       e1, cnt1, E1, NB1,
                                       lab, cntL, N, NBL);
    k_bscan3<<<3, 512, 0, stream>>>(cnt0, base0, cur0, NB0, E0,
                                    cnt1, base1, cur1, NB1, E1,
                                    cntL, baseL, curL, NBL, N);
    k_bucket3<<<GB0 + GB1 + GBL, BKT, 0, stream>>>(
        e0, cur0, ebuf0, E0, NB0, GB0,
        e1, cur1, ebuf1, E1, NB1, GB1,
        lab, curL, ebufL, N, NBL);
    k_final3<<<NB0 + NB1 + NBL, 512, 0, stream>>>(
        ebuf0, base0, rs0, srcs0, N, E0, NB0,
        ebuf1, base1, rs1, srcs1, M, E1, NB1,
        ebufL, baseL, rsL, srcsL, M, N, NBL);

    // ---- layer 0 (fully fused front) ----
    k_feat_pre0_g<<<gG, blk, 0, stream>>>(feat, pts, ctr, lab, feW, feb,
                                          Wh+0*64*3, bh+0*3,
                                          pWf0, Wf+0*67*64, bf+0*64,
                                          rel, x1, p, q, NT);
    k_seg_max_gnn<<<gSeg, blk, 0, stream>>>(rs0, srcs0, p, q, N);
    k_post_m2l_g<<<gG, blk, 0, stream>>>(q, pWg0, bg+0*64, x1,
                                         pWm, m2lb, m2lW+64*64, rel,
                                         x2, p, NT);

    // ---- layer 1 (clusters, VALU) ----
    float* p1 = q;
    float* q1 = q + (size_t)M*64;
    k_seglab_pre1<<<gridM, blk, 0, stream>>>(rsL, srcsL, p, ctr,
                                             Wh+1*64*3, bh+1*3, Wf+1*67*64, bf+1*64,
                                             c, p1, q1, M);
    k_seg_max_gnn<<<640, blk, 0, stream>>>(rs1, srcs1, p1, q1, M);
    k_gnn_post<<<gridM, blk, 0, stream>>>(q1, Wg+1*64*64, bg+1*64, c, c4, M);

    // ---- l2m (+q fold) + layer 2 + classifier ----
    k_l2m_pre2_g<<<gG, blk, 0, stream>>>(c4, lab, pWl2m, l2mb, l2mW+64*64, rel,
                                         pWf2, Wf+2*67*64, pts,
                                         Wh+2*64*3, bh+2*3, bf+2*64,
                                         x1, p, q, NT);                     // x5 -> x1
    k_seg_max_gnn<<<gSeg, blk, 0, stream>>>(rs0, srcs0, p, q, N);
    k_gemm_final<<<gG, blk, 0, stream>>>(q, pWg2, bg+2*64, x1, x2,
                                         pW1, cb1, cW2, cb2, out, NT);
}